// Round 1
// 555.611 us; speedup vs baseline: 1.2003x; 1.2003x over previous
//
#include <hip/hip_runtime.h>
#include <math.h>

#define LL 2048
#define DD 128
#define BB 4
#define CK 64
#define NCHUNK 32

typedef __bf16 bf16x8 __attribute__((ext_vector_type(8)));
typedef __bf16 bf16x4 __attribute__((ext_vector_type(4)));
typedef float floatx4 __attribute__((ext_vector_type(4)));

// ================= proj GEMM (bf16 MFMA): C(8192x128 x3) = x(8192x2048) @ w^T + b =========
__global__ __launch_bounds__(256) void proj_gemm_mfma(
    const float* __restrict__ x,
    const float* __restrict__ kw, const float* __restrict__ qw, const float* __restrict__ vw,
    const float* __restrict__ kb, const float* __restrict__ qb, const float* __restrict__ vb,
    float* __restrict__ k0, float* __restrict__ q0, float* __restrict__ v0)
{
    const int arr = blockIdx.y;
    const float* __restrict__ w   = arr == 0 ? kw : (arr == 1 ? qw : vw);
    const float* __restrict__ bia = arr == 0 ? kb : (arr == 1 ? qb : vb);
    float* __restrict__ out       = arr == 0 ? k0 : (arr == 1 ? q0 : v0);

    __shared__ __bf16 As[128][72];
    __shared__ __bf16 Bs[128][72];

    const int t    = threadIdx.x;
    const int wave = t >> 6, lane = t & 63;
    const int wm   = wave & 1, wn = wave >> 1;
    const int m    = lane & 15, quad = lane >> 4;
    const int row0 = blockIdx.x * 128;

    floatx4 acc[4][4] = {};

    for (int k0i = 0; k0i < 2048; k0i += 64) {
        #pragma unroll
        for (int c = 0; c < 4; c++) {
            int chunk = t + c * 256;
            int r = chunk >> 3, p = chunk & 7;
            const float4* src = (const float4*)&x[(size_t)(row0 + r) * 2048 + k0i + p * 8];
            float4 f0 = src[0], f1 = src[1];
            bf16x8 v8;
            v8[0] = (__bf16)f0.x; v8[1] = (__bf16)f0.y; v8[2] = (__bf16)f0.z; v8[3] = (__bf16)f0.w;
            v8[4] = (__bf16)f1.x; v8[5] = (__bf16)f1.y; v8[6] = (__bf16)f1.z; v8[7] = (__bf16)f1.w;
            *(bf16x8*)&As[r][p * 8] = v8;
        }
        #pragma unroll
        for (int c = 0; c < 4; c++) {
            int chunk = t + c * 256;
            int r = chunk >> 3, p = chunk & 7;
            const float4* src = (const float4*)&w[(size_t)r * 2048 + k0i + p * 8];
            float4 f0 = src[0], f1 = src[1];
            bf16x8 v8;
            v8[0] = (__bf16)f0.x; v8[1] = (__bf16)f0.y; v8[2] = (__bf16)f0.z; v8[3] = (__bf16)f0.w;
            v8[4] = (__bf16)f1.x; v8[5] = (__bf16)f1.y; v8[6] = (__bf16)f1.z; v8[7] = (__bf16)f1.w;
            *(bf16x8*)&Bs[r][p * 8] = v8;
        }
        __syncthreads();
        #pragma unroll
        for (int ks = 0; ks < 2; ks++) {
            bf16x8 af[4], bfr[4];
            #pragma unroll
            for (int i = 0; i < 4; i++)
                af[i] = *(const bf16x8*)&As[wm * 64 + i * 16 + m][ks * 32 + quad * 8];
            #pragma unroll
            for (int j = 0; j < 4; j++)
                bfr[j] = *(const bf16x8*)&Bs[wn * 64 + j * 16 + m][ks * 32 + quad * 8];
            #pragma unroll
            for (int i = 0; i < 4; i++)
                #pragma unroll
                for (int j = 0; j < 4; j++)
                    acc[i][j] = __builtin_amdgcn_mfma_f32_16x16x32_bf16(af[i], bfr[j], acc[i][j], 0, 0, 0);
        }
        __syncthreads();
    }
    #pragma unroll
    for (int i = 0; i < 4; i++) {
        int grow = row0 + wm * 64 + i * 16 + quad * 4;
        #pragma unroll
        for (int j = 0; j < 4; j++) {
            int col = wn * 64 + j * 16 + m;
            float bv = bia[col];
            #pragma unroll
            for (int r = 0; r < 4; r++)
                out[(size_t)(grow + r) * 128 + col] = acc[i][j][r] + bv;
        }
    }
}

// ================= out GEMM (bf16 MFMA): out(8192x2048) = nm(8192x128) @ ow^T + ob ========
__global__ __launch_bounds__(256) void out_gemm_mfma(
    const float* __restrict__ A, const float* __restrict__ w,
    const float* __restrict__ bias, float* __restrict__ out)
{
    __shared__ __bf16 As[128][72];
    __shared__ __bf16 Bs[128][72];

    const int t    = threadIdx.x;
    const int wave = t >> 6, lane = t & 63;
    const int wm   = wave & 1, wn = wave >> 1;
    const int m    = lane & 15, quad = lane >> 4;
    const int row0 = blockIdx.x * 128;
    const int col0 = blockIdx.y * 128;

    floatx4 acc[4][4] = {};

    for (int k0i = 0; k0i < 128; k0i += 64) {
        #pragma unroll
        for (int c = 0; c < 4; c++) {
            int chunk = t + c * 256;
            int r = chunk >> 3, p = chunk & 7;
            const float4* src = (const float4*)&A[(size_t)(row0 + r) * 128 + k0i + p * 8];
            float4 f0 = src[0], f1 = src[1];
            bf16x8 v8;
            v8[0] = (__bf16)f0.x; v8[1] = (__bf16)f0.y; v8[2] = (__bf16)f0.z; v8[3] = (__bf16)f0.w;
            v8[4] = (__bf16)f1.x; v8[5] = (__bf16)f1.y; v8[6] = (__bf16)f1.z; v8[7] = (__bf16)f1.w;
            *(bf16x8*)&As[r][p * 8] = v8;
        }
        #pragma unroll
        for (int c = 0; c < 4; c++) {
            int chunk = t + c * 256;
            int r = chunk >> 3, p = chunk & 7;
            const float4* src = (const float4*)&w[(size_t)(col0 + r) * 128 + k0i + p * 8];
            float4 f0 = src[0], f1 = src[1];
            bf16x8 v8;
            v8[0] = (__bf16)f0.x; v8[1] = (__bf16)f0.y; v8[2] = (__bf16)f0.z; v8[3] = (__bf16)f0.w;
            v8[4] = (__bf16)f1.x; v8[5] = (__bf16)f1.y; v8[6] = (__bf16)f1.z; v8[7] = (__bf16)f1.w;
            *(bf16x8*)&Bs[r][p * 8] = v8;
        }
        __syncthreads();
        #pragma unroll
        for (int ks = 0; ks < 2; ks++) {
            bf16x8 af[4], bfr[4];
            #pragma unroll
            for (int i = 0; i < 4; i++)
                af[i] = *(const bf16x8*)&As[wm * 64 + i * 16 + m][ks * 32 + quad * 8];
            #pragma unroll
            for (int j = 0; j < 4; j++)
                bfr[j] = *(const bf16x8*)&Bs[wn * 64 + j * 16 + m][ks * 32 + quad * 8];
            #pragma unroll
            for (int i = 0; i < 4; i++)
                #pragma unroll
                for (int j = 0; j < 4; j++)
                    acc[i][j] = __builtin_amdgcn_mfma_f32_16x16x32_bf16(af[i], bfr[j], acc[i][j], 0, 0, 0);
        }
        __syncthreads();
    }
    #pragma unroll
    for (int i = 0; i < 4; i++) {
        int grow = row0 + wm * 64 + i * 16 + quad * 4;
        #pragma unroll
        for (int j = 0; j < 4; j++) {
            int col = col0 + wn * 64 + j * 16 + m;
            float bv = bias[col];
            #pragma unroll
            for (int r = 0; r < 4; r++)
                out[(size_t)(grow + r) * 2048 + col] = acc[i][j][r] + bv;
        }
    }
}

// ================= beta = sigmoid(x @ beta_w^T + beta_b) ================
__global__ __launch_bounds__(256) void beta_kernel(
    const float* __restrict__ x, const float* __restrict__ bw,
    const float* __restrict__ bb, float* __restrict__ beta)
{
    const int row = blockIdx.x;
    const float* xr = x + (size_t)row * 2048;
    float s = 0.f;
    for (int j = threadIdx.x; j < 2048; j += 256) s = fmaf(xr[j], bw[j], s);
    #pragma unroll
    for (int m = 1; m < 64; m <<= 1) s += __shfl_xor(s, m, 64);
    __shared__ float red[4];
    if ((threadIdx.x & 63) == 0) red[threadIdx.x >> 6] = s;
    __syncthreads();
    if (threadIdx.x == 0) {
        float tot = red[0] + red[1] + red[2] + red[3] + bb[0];
        beta[row] = 1.f / (1.f + expf(-tot));
    }
}

// ================= 3-tap conv along s (kw=1 column of 3x3) + bias + SiLU ================
__global__ __launch_bounds__(256) void conv_silu(
    const float* __restrict__ k0, const float* __restrict__ q0, const float* __restrict__ v0,
    const float* __restrict__ kw, const float* __restrict__ qw, const float* __restrict__ vw,
    const float* __restrict__ kb, const float* __restrict__ qb, const float* __restrict__ vb,
    float* __restrict__ kc, float* __restrict__ qc, float* __restrict__ vc)
{
    const int st  = blockIdx.x;
    const int og  = blockIdx.y;
    const int arr = blockIdx.z >> 2;
    const int b   = blockIdx.z & 3;
    const float* __restrict__ in = (arr == 0 ? k0 : arr == 1 ? q0 : v0) + (size_t)b * DD * LL;
    const float* __restrict__ w  = arr == 0 ? kw : arr == 1 ? qw : vw;
    const float* __restrict__ bi = arr == 0 ? kb : arr == 1 ? qb : vb;
    float* __restrict__ out      = (arr == 0 ? kc : arr == 1 ? qc : vc) + (size_t)b * DD * LL;

    __shared__ float wl[16 * 128 * 3];
    __shared__ float ls[258];
    const int t = threadIdx.x;
    for (int e = t; e < 16 * 128 * 3; e += 256) {
        int oo = e / 384, rem = e % 384;
        int i = rem / 3, kh = rem % 3;
        wl[e] = w[(size_t)(((og * 16 + oo) * 128 + i) * 3 + kh) * 3 + 1];
    }
    __syncthreads();

    const int s = st * 256 + t;
    float acc[16];
    #pragma unroll
    for (int oo = 0; oo < 16; oo++) acc[oo] = 0.f;

    for (int i = 0; i < 128; i++) {
        int sl = st * 256 - 1 + t;
        ls[t] = (sl >= 0 && sl < LL) ? in[(size_t)i * LL + sl] : 0.f;
        if (t < 2) {
            int s2 = st * 256 + 255 + t;
            ls[256 + t] = (s2 < LL) ? in[(size_t)i * LL + s2] : 0.f;
        }
        __syncthreads();
        float xm = ls[t], x0 = ls[t + 1], xp = ls[t + 2];
        #pragma unroll
        for (int oo = 0; oo < 16; oo++) {
            const float* wp = &wl[(oo * 128 + i) * 3];
            acc[oo] = fmaf(wp[0], xm, acc[oo]);
            acc[oo] = fmaf(wp[1], x0, acc[oo]);
            acc[oo] = fmaf(wp[2], xp, acc[oo]);
        }
        __syncthreads();
    }
    #pragma unroll
    for (int oo = 0; oo < 16; oo++) {
        int o = og * 16 + oo;
        float v = acc[oo] + bi[o];
        out[(size_t)o * LL + s] = v / (1.f + expf(-v));
    }
}

// ================= 1/max(||row||_2, 1e-12) over s for k,q ================
__global__ __launch_bounds__(256) void l2norm_reduce(
    const float* __restrict__ kc, const float* __restrict__ qc, float* __restrict__ invn)
{
    const int row = blockIdx.x;
    const int arr = blockIdx.y;
    const float* src = (arr ? qc : kc) + (size_t)row * LL;
    float s = 0.f;
    for (int j = threadIdx.x; j < LL; j += 256) { float v = src[j]; s = fmaf(v, v, s); }
    #pragma unroll
    for (int m = 1; m < 64; m <<= 1) s += __shfl_xor(s, m, 64);
    __shared__ float red[4];
    if ((threadIdx.x & 63) == 0) red[threadIdx.x >> 6] = s;
    __syncthreads();
    if (threadIdx.x == 0) {
        float n = sqrtf(red[0] + red[1] + red[2] + red[3]);
        invn[arr * 512 + row] = 1.f / fmaxf(n, 1e-12f);
    }
}

// ================= transpose (B,D,L)->(B,L,D), scaling k,q by invn ================
__global__ __launch_bounds__(256) void pack_transpose(
    const float* __restrict__ kc, const float* __restrict__ qc, const float* __restrict__ vc,
    const float* __restrict__ invn,
    float* __restrict__ kT, float* __restrict__ qT, float* __restrict__ vT)
{
    const int arr = blockIdx.z >> 2;
    const int b   = blockIdx.z & 3;
    const float* src = (arr == 0 ? kc : arr == 1 ? qc : vc) + (size_t)b * DD * LL;
    float* dst       = (arr == 0 ? kT : arr == 1 ? qT : vT) + (size_t)b * LL * DD;
    __shared__ float tile[32][33];
    const int s0 = blockIdx.x * 32, d0 = blockIdx.y * 32;
    const int c = threadIdx.x & 31, r = threadIdx.x >> 5;
    #pragma unroll
    for (int p = 0; p < 4; p++) {
        int d = d0 + r + p * 8;
        tile[r + p * 8][c] = src[(size_t)d * LL + s0 + c];
    }
    __syncthreads();
    #pragma unroll
    for (int p = 0; p < 4; p++) {
        int s = s0 + r + p * 8;
        int d = d0 + c;
        float sc = (arr < 2) ? invn[arr * 512 + b * 128 + d] : 1.f;
        dst[(size_t)s * DD + d] = tile[c][r + p * 8] * sc;
    }
}

// ============================================================================
// Chunked delta rule (WY / UT transform), C = 64, exact reformulation:
//   u_t = beta_t (v_t - S_{t-1} k_t);  S_t = S_{t-1} + u_t k_t^T;  o_t = S_t q_t
// Per chunk:  (I + A) U = beta (V - K S0^T),  A = strict_tril(diag(beta) K K^T)
//   U = U0 - W S0^T  with  W = (I+A)^{-1} beta K,  U0 = (I+A)^{-1} beta V
//   S_next = S0 (I - H) + G,   H = W^T K,  G = U0^T K
//   O = P S0^T + Y,            P = Q - L W,  Y = L U0,  L = tril(Q K^T, incl diag)
// S held fp32 in MFMA accumulators across the 32-chunk serial chain; bf16 only
// in multiplicands (one-shot rounding, no compounding).
// ============================================================================

// --------- PRE1 (parallel over 128 (b,c)): A, L, and triangular solve -> W, U0
__global__ __launch_bounds__(256) void chunk_pre1(
    const float* __restrict__ kTg, const float* __restrict__ qTg, const float* __restrict__ vTg,
    const float* __restrict__ beta,
    __bf16* __restrict__ Lb, __bf16* __restrict__ Wb, __bf16* __restrict__ Ub)
{
    const int c = blockIdx.x, b = blockIdx.y;
    const int gc = b * NCHUNK + c;
    const int t0 = c * CK;
    const float* kbase = kTg + ((size_t)b * LL + t0) * DD;
    const float* qbase = qTg + ((size_t)b * LL + t0) * DD;
    const float* vbase = vTg + ((size_t)b * LL + t0) * DD;

    __shared__ __bf16 Ks[CK][136];
    __shared__ __bf16 Qs[CK][136];
    __shared__ float  Af[CK][65];
    __shared__ float  WU[CK][257];
    __shared__ float  betas[CK];

    const int t = threadIdx.x;
    #pragma unroll
    for (int p = 0; p < 8; p++) {
        int idx = t + p * 256;          // 2048 float4 chunks = 64 x 128
        int r = idx >> 5, c4 = idx & 31;
        float4 f = *(const float4*)&kbase[(size_t)r * DD + c4 * 4];
        bf16x4 v; v[0] = (__bf16)f.x; v[1] = (__bf16)f.y; v[2] = (__bf16)f.z; v[3] = (__bf16)f.w;
        *(bf16x4*)&Ks[r][c4 * 4] = v;
        float4 g = *(const float4*)&qbase[(size_t)r * DD + c4 * 4];
        bf16x4 u; u[0] = (__bf16)g.x; u[1] = (__bf16)g.y; u[2] = (__bf16)g.z; u[3] = (__bf16)g.w;
        *(bf16x4*)&Qs[r][c4 * 4] = u;
    }
    if (t < CK) betas[t] = beta[(size_t)b * LL + t0 + t];
    __syncthreads();

    const int wave = t >> 6, lane = t & 63;
    const int wm = wave & 1, wn = wave >> 1;
    const int m = lane & 15, quad = lane >> 4;

    floatx4 accM[2][2] = {}, accL[2][2] = {};
    #pragma unroll
    for (int ks = 0; ks < 4; ks++) {
        bf16x8 ak[2], aq[2], bk[2];
        #pragma unroll
        for (int i = 0; i < 2; i++) {
            ak[i] = *(const bf16x8*)&Ks[wm * 32 + i * 16 + m][ks * 32 + quad * 8];
            aq[i] = *(const bf16x8*)&Qs[wm * 32 + i * 16 + m][ks * 32 + quad * 8];
            bk[i] = *(const bf16x8*)&Ks[wn * 32 + i * 16 + m][ks * 32 + quad * 8];
        }
        #pragma unroll
        for (int i = 0; i < 2; i++)
            #pragma unroll
            for (int j = 0; j < 2; j++) {
                accM[i][j] = __builtin_amdgcn_mfma_f32_16x16x32_bf16(ak[i], bk[j], accM[i][j], 0, 0, 0);
                accL[i][j] = __builtin_amdgcn_mfma_f32_16x16x32_bf16(aq[i], bk[j], accL[i][j], 0, 0, 0);
            }
    }
    #pragma unroll
    for (int i = 0; i < 2; i++)
        #pragma unroll
        for (int j = 0; j < 2; j++)
            #pragma unroll
            for (int r = 0; r < 4; r++) {
                int row = wm * 32 + i * 16 + quad * 4 + r;
                int col = wn * 32 + j * 16 + m;
                Af[row][col] = (col < row) ? betas[row] * accM[i][j][r] : 0.f;
                Lb[((size_t)gc * CK + row) * CK + col] =
                    (col <= row) ? (__bf16)accL[i][j][r] : (__bf16)0.f;
            }
    __syncthreads();

    // forward substitution: (I+A)[W|U0] = beta [K|V]; each thread owns one column
    const int col = t;
    const float* rbase = (col < DD) ? kbase : vbase;
    const int cm = col & (DD - 1);
    float cur = rbase[cm];
    for (int tt = 0; tt < CK; tt++) {
        float nxt = (tt < CK - 1) ? rbase[(size_t)(tt + 1) * DD + cm] : 0.f;
        float acc = betas[tt] * cur;
        for (int s = 0; s < tt; s++)
            acc -= Af[tt][s] * WU[s][col];
        WU[tt][col] = acc;
        __bf16 bv = (__bf16)acc;
        if (col < DD) Wb[((size_t)gc * CK + tt) * DD + col] = bv;
        else          Ub[((size_t)gc * CK + tt) * DD + cm]  = bv;
        cur = nxt;
    }
}

// --------- PRE2 (parallel): H, G, P, Y from W, U0, L, K, Q
__global__ __launch_bounds__(256) void chunk_pre2(
    const float* __restrict__ kTg, const float* __restrict__ qTg,
    const __bf16* __restrict__ Lb, const __bf16* __restrict__ Wb, const __bf16* __restrict__ Ub,
    __bf16* __restrict__ HTb, __bf16* __restrict__ Gb,
    __bf16* __restrict__ Pb, __bf16* __restrict__ Yb)
{
    const int c = blockIdx.x, b = blockIdx.y;
    const int gc = b * NCHUNK + c;
    const int t0 = c * CK;

    __shared__ __bf16 Kt[DD][72];   // K^T : Kt[j][t]
    __shared__ __bf16 Wt[DD][72];   // W^T : Wt[i][t]
    __shared__ __bf16 Ut[DD][72];   // U0^T: Ut[i][t]
    __shared__ __bf16 Ls[CK][72];   // L[t][s]

    const int t = threadIdx.x;
    #pragma unroll
    for (int p = 0; p < 8; p++) {
        int idx = t + p * 256;        // 2048 chunks of 4 over 64x128
        int tt = idx >> 5, j4 = idx & 31;
        float4 f = *(const float4*)&kTg[((size_t)b * LL + t0 + tt) * DD + j4 * 4];
        Kt[j4 * 4 + 0][tt] = (__bf16)f.x; Kt[j4 * 4 + 1][tt] = (__bf16)f.y;
        Kt[j4 * 4 + 2][tt] = (__bf16)f.z; Kt[j4 * 4 + 3][tt] = (__bf16)f.w;
        bf16x4 w = *(const bf16x4*)&Wb[((size_t)gc * CK + tt) * DD + j4 * 4];
        bf16x4 u = *(const bf16x4*)&Ub[((size_t)gc * CK + tt) * DD + j4 * 4];
        #pragma unroll
        for (int e = 0; e < 4; e++) { Wt[j4 * 4 + e][tt] = w[e]; Ut[j4 * 4 + e][tt] = u[e]; }
    }
    #pragma unroll
    for (int p = 0; p < 4; p++) {
        int idx = t + p * 256;        // 1024 chunks of 4 over 64x64
        int tt = idx >> 4, s4 = idx & 15;
        *(bf16x4*)&Ls[tt][s4 * 4] = *(const bf16x4*)&Lb[((size_t)gc * CK + tt) * CK + s4 * 4];
    }
    __syncthreads();

    const int wave = t >> 6, lane = t & 63;
    const int wm = wave & 1, wn = wave >> 1;
    const int m = lane & 15, quad = lane >> 4;

    // H^T (negated): C[j][i] = -sum_t Kt[j][t] Wt[i][t]  (128x128, red 64)
    {
        floatx4 acc[4][4] = {};
        #pragma unroll
        for (int ks = 0; ks < 2; ks++) {
            bf16x8 a[4], bb[4];
            #pragma unroll
            for (int i = 0; i < 4; i++) {
                a[i]  = *(const bf16x8*)&Kt[wm * 64 + i * 16 + m][ks * 32 + quad * 8];
                bb[i] = *(const bf16x8*)&Wt[wn * 64 + i * 16 + m][ks * 32 + quad * 8];
            }
            #pragma unroll
            for (int i = 0; i < 4; i++)
                #pragma unroll
                for (int j = 0; j < 4; j++)
                    acc[i][j] = __builtin_amdgcn_mfma_f32_16x16x32_bf16(a[i], bb[j], acc[i][j], 0, 0, 0);
        }
        #pragma unroll
        for (int i = 0; i < 4; i++)
            #pragma unroll
            for (int j = 0; j < 4; j++)
                #pragma unroll
                for (int r = 0; r < 4; r++) {
                    int row = wm * 64 + i * 16 + quad * 4 + r;
                    int cx  = wn * 64 + j * 16 + m;
                    HTb[((size_t)gc * DD + row) * DD + cx] = (__bf16)(-acc[i][j][r]);
                }
    }
    // G: C[i][j] = sum_t Ut[i][t] Kt[j][t]
    {
        floatx4 acc[4][4] = {};
        #pragma unroll
        for (int ks = 0; ks < 2; ks++) {
            bf16x8 a[4], bb[4];
            #pragma unroll
            for (int i = 0; i < 4; i++) {
                a[i]  = *(const bf16x8*)&Ut[wm * 64 + i * 16 + m][ks * 32 + quad * 8];
                bb[i] = *(const bf16x8*)&Kt[wn * 64 + i * 16 + m][ks * 32 + quad * 8];
            }
            #pragma unroll
            for (int i = 0; i < 4; i++)
                #pragma unroll
                for (int j = 0; j < 4; j++)
                    acc[i][j] = __builtin_amdgcn_mfma_f32_16x16x32_bf16(a[i], bb[j], acc[i][j], 0, 0, 0);
        }
        #pragma unroll
        for (int i = 0; i < 4; i++)
            #pragma unroll
            for (int j = 0; j < 4; j++)
                #pragma unroll
                for (int r = 0; r < 4; r++) {
                    int row = wm * 64 + i * 16 + quad * 4 + r;
                    int cx  = wn * 64 + j * 16 + m;
                    Gb[((size_t)gc * DD + row) * DD + cx] = (__bf16)acc[i][j][r];
                }
    }
    // P = Q - L W : C[t][i] = sum_s Ls[t][s] Wt[i][s]  (64x128, red 64)
    {
        floatx4 acc[2][4] = {};
        #pragma unroll
        for (int ks = 0; ks < 2; ks++) {
            bf16x8 a[2], bb[4];
            #pragma unroll
            for (int i = 0; i < 2; i++)
                a[i] = *(const bf16x8*)&Ls[wm * 32 + i * 16 + m][ks * 32 + quad * 8];
            #pragma unroll
            for (int j = 0; j < 4; j++)
                bb[j] = *(const bf16x8*)&Wt[wn * 64 + j * 16 + m][ks * 32 + quad * 8];
            #pragma unroll
            for (int i = 0; i < 2; i++)
                #pragma unroll
                for (int j = 0; j < 4; j++)
                    acc[i][j] = __builtin_amdgcn_mfma_f32_16x16x32_bf16(a[i], bb[j], acc[i][j], 0, 0, 0);
        }
        #pragma unroll
        for (int i = 0; i < 2; i++)
            #pragma unroll
            for (int j = 0; j < 4; j++)
                #pragma unroll
                for (int r = 0; r < 4; r++) {
                    int row = wm * 32 + i * 16 + quad * 4 + r;
                    int cx  = wn * 64 + j * 16 + m;
                    float qv = qTg[((size_t)b * LL + t0 + row) * DD + cx];
                    Pb[((size_t)gc * CK + row) * DD + cx] = (__bf16)(qv - acc[i][j][r]);
                }
    }
    // Y = L U0 : C[t][i] = sum_s Ls[t][s] Ut[i][s]
    {
        floatx4 acc[2][4] = {};
        #pragma unroll
        for (int ks = 0; ks < 2; ks++) {
            bf16x8 a[2], bb[4];
            #pragma unroll
            for (int i = 0; i < 2; i++)
                a[i] = *(const bf16x8*)&Ls[wm * 32 + i * 16 + m][ks * 32 + quad * 8];
            #pragma unroll
            for (int j = 0; j < 4; j++)
                bb[j] = *(const bf16x8*)&Ut[wn * 64 + j * 16 + m][ks * 32 + quad * 8];
            #pragma unroll
            for (int i = 0; i < 2; i++)
                #pragma unroll
                for (int j = 0; j < 4; j++)
                    acc[i][j] = __builtin_amdgcn_mfma_f32_16x16x32_bf16(a[i], bb[j], acc[i][j], 0, 0, 0);
        }
        #pragma unroll
        for (int i = 0; i < 2; i++)
            #pragma unroll
            for (int j = 0; j < 4; j++)
                #pragma unroll
                for (int r = 0; r < 4; r++) {
                    int row = wm * 32 + i * 16 + quad * 4 + r;
                    int cx  = wn * 64 + j * 16 + m;
                    Yb[((size_t)gc * CK + row) * DD + cx] = (__bf16)acc[i][j][r];
                }
    }
}

// --------- serial chain: S <- S (I - H) + G per chunk; snapshot S0 each chunk
__global__ __launch_bounds__(1024) void delta_serial(
    const __bf16* __restrict__ HTb, const __bf16* __restrict__ Gb, __bf16* __restrict__ S0b)
{
    const int b = blockIdx.x;
    __shared__ __bf16 Ss[DD][136];
    __shared__ __bf16 Hs[DD][136];
    const int t = threadIdx.x;
    const int wave = t >> 6, lane = t & 63;
    const int wi = wave >> 2, wj = wave & 3;
    const int m = lane & 15, quad = lane >> 4;

    floatx4 acc[2][2] = {};   // fp32 S across the whole chain

    for (int c = 0; c < NCHUNK; c++) {
        const size_t gco = (size_t)(b * NCHUNK + c) * DD * DD;
        // 1. Ss = bf16(S0)
        #pragma unroll
        for (int i = 0; i < 2; i++)
            #pragma unroll
            for (int j = 0; j < 2; j++) {
                int row = wi * 32 + i * 16 + quad * 4;
                int cx  = wj * 32 + j * 16 + m;
                #pragma unroll
                for (int r = 0; r < 4; r++)
                    Ss[row + r][cx] = (__bf16)acc[i][j][r];
            }
        __syncthreads();
        // 2. snapshot S0 to global; load -H^T into Hs; add G into acc (fp32)
        #pragma unroll
        for (int p = 0; p < 4; p++) {
            int idx = t + p * 1024;          // 4096 chunks of 4 over 128x128
            int row = idx >> 5, c4 = idx & 31;
            *(bf16x4*)&S0b[gco + (size_t)row * DD + c4 * 4] = *(const bf16x4*)&Ss[row][c4 * 4];
            *(bf16x4*)&Hs[row][c4 * 4] = *(const bf16x4*)&HTb[gco + (size_t)row * DD + c4 * 4];
        }
        #pragma unroll
        for (int i = 0; i < 2; i++)
            #pragma unroll
            for (int j = 0; j < 2; j++) {
                int row = wi * 32 + i * 16 + quad * 4;
                int cx  = wj * 32 + j * 16 + m;
                #pragma unroll
                for (int r = 0; r < 4; r++)
                    acc[i][j][r] += (float)Gb[gco + (size_t)(row + r) * DD + cx];
            }
        __syncthreads();
        // 3. acc += S0 * (-H): A = Ss rows i, B = Hs rows j (both m-contig)
        #pragma unroll
        for (int ks = 0; ks < 4; ks++) {
            bf16x8 a[2], bb[2];
            #pragma unroll
            for (int i = 0; i < 2; i++) {
                a[i]  = *(const bf16x8*)&Ss[wi * 32 + i * 16 + m][ks * 32 + quad * 8];
                bb[i] = *(const bf16x8*)&Hs[wj * 32 + i * 16 + m][ks * 32 + quad * 8];
            }
            #pragma unroll
            for (int i = 0; i < 2; i++)
                #pragma unroll
                for (int j = 0; j < 2; j++)
                    acc[i][j] = __builtin_amdgcn_mfma_f32_16x16x32_bf16(a[i], bb[j], acc[i][j], 0, 0, 0);
        }
        __syncthreads();
    }
}

// --------- O = P S0^T + Y per chunk (parallel) -> dl (fp32, (B,L,D))
__global__ __launch_bounds__(256) void chunk_out(
    const __bf16* __restrict__ Pb, const __bf16* __restrict__ Yb, const __bf16* __restrict__ S0b,
    float* __restrict__ dl)
{
    const int c = blockIdx.x, b = blockIdx.y;
    const int gc = b * NCHUNK + c;
    const int t0 = c * CK;
    __shared__ __bf16 Ps[CK][136];
    __shared__ __bf16 Sb[DD][136];
    const int t = threadIdx.x;
    #pragma unroll
    for (int p = 0; p < 8; p++) {
        int idx = t + p * 256;           // 2048 chunks of 4 over 64x128
        int row = idx >> 5, c4 = idx & 31;
        *(bf16x4*)&Ps[row][c4 * 4] = *(const bf16x4*)&Pb[((size_t)gc * CK + row) * DD + c4 * 4];
    }
    #pragma unroll
    for (int p = 0; p < 16; p++) {
        int idx = t + p * 256;           // 4096 chunks of 4 over 128x128
        int row = idx >> 5, c4 = idx & 31;
        *(bf16x4*)&Sb[row][c4 * 4] = *(const bf16x4*)&S0b[((size_t)gc * DD + row) * DD + c4 * 4];
    }
    __syncthreads();

    const int wave = t >> 6, lane = t & 63;
    const int wm = wave & 1, wn = wave >> 1;
    const int m = lane & 15, quad = lane >> 4;

    floatx4 acc[2][4] = {};
    #pragma unroll
    for (int ks = 0; ks < 4; ks++) {
        bf16x8 a[2], bb[4];
        #pragma unroll
        for (int i = 0; i < 2; i++)
            a[i] = *(const bf16x8*)&Ps[wm * 32 + i * 16 + m][ks * 32 + quad * 8];
        #pragma unroll
        for (int j = 0; j < 4; j++)
            bb[j] = *(const bf16x8*)&Sb[wn * 64 + j * 16 + m][ks * 32 + quad * 8];
        #pragma unroll
        for (int i = 0; i < 2; i++)
            #pragma unroll
            for (int j = 0; j < 4; j++)
                acc[i][j] = __builtin_amdgcn_mfma_f32_16x16x32_bf16(a[i], bb[j], acc[i][j], 0, 0, 0);
    }
    #pragma unroll
    for (int i = 0; i < 2; i++)
        #pragma unroll
        for (int j = 0; j < 4; j++)
            #pragma unroll
            for (int r = 0; r < 4; r++) {
                int row = wm * 32 + i * 16 + quad * 4 + r;
                int cx  = wn * 64 + j * 16 + m;
                float y = (float)Yb[((size_t)gc * CK + row) * DD + cx];
                dl[((size_t)b * LL + t0 + row) * DD + cx] = acc[i][j][r] + y;
            }
}

// ================= RMSNorm over D (in-place capable) ================
__global__ __launch_bounds__(128) void rms_norm(
    const float* __restrict__ dl, const float* __restrict__ rms_w, float* __restrict__ normed)
{
    const int row = blockIdx.x;
    const int t = threadIdx.x;
    float v = dl[(size_t)row * DD + t];
    float s = v * v;
    #pragma unroll
    for (int m = 1; m < 64; m <<= 1) s += __shfl_xor(s, m, 64);
    __shared__ float r2[2];
    if ((t & 63) == 0) r2[t >> 6] = s;
    __syncthreads();
    float ms = (r2[0] + r2[1]) * (1.f / 128.f);
    normed[(size_t)row * DD + t] = v * rsqrtf(ms + 1.1920928955078125e-07f) * rms_w[t];
}

extern "C" void kernel_launch(void* const* d_in, const int* in_sizes, int n_in,
                              void* d_out, int out_size, void* d_ws, size_t ws_size,
                              hipStream_t stream) {
    const float* x    = (const float*)d_in[0];
    const float* kpw  = (const float*)d_in[1];
    const float* kpb  = (const float*)d_in[2];
    const float* qpw  = (const float*)d_in[3];
    const float* qpb  = (const float*)d_in[4];
    const float* vpw  = (const float*)d_in[5];
    const float* vpb  = (const float*)d_in[6];
    const float* kcw  = (const float*)d_in[7];
    const float* kcb  = (const float*)d_in[8];
    const float* qcw  = (const float*)d_in[9];
    const float* qcb  = (const float*)d_in[10];
    const float* vcw  = (const float*)d_in[11];
    const float* vcb  = (const float*)d_in[12];
    const float* bw   = (const float*)d_in[13];
    const float* bb   = (const float*)d_in[14];
    const float* rw   = (const float*)d_in[15];
    const float* ow   = (const float*)d_in[16];
    const float* obi  = (const float*)d_in[17];
    float* out = (float*)d_out;

    float* ws = (float*)d_ws;
    const size_t NB1 = (size_t)BB * DD * LL;   // 1,048,576 floats = 4 MB
    // slot map (each slot NB1 floats = 4 MB):
    //  0: kT   1: qT   2: vT -> Gb(bf16)   3: kc -> Lb+Wb(bf16) -> S0b(bf16)
    //  4: qc -> Ub(bf16)   5: vc -> HTb(bf16)   6: dl (fp32, in-place rms)
    //  7: Pb+Yb(bf16)   8: beta + invn
    float* kT = ws;
    float* qT = ws + NB1;
    float* vT = ws + 2 * NB1;
    float* kc = ws + 3 * NB1;
    float* qc = ws + 4 * NB1;
    float* vc = ws + 5 * NB1;
    float* dl = ws + 6 * NB1;
    float* beta = ws + 8 * NB1;
    float* invn = beta + (size_t)BB * LL;

    __bf16* Lb  = (__bf16*)(ws + 3 * NB1);                 // 128*64*64
    __bf16* Wb  = Lb + (size_t)128 * 64 * 64;              // 128*64*128
    __bf16* Ub  = (__bf16*)(ws + 4 * NB1);                 // 128*64*128
    __bf16* HTb = (__bf16*)(ws + 5 * NB1);                 // 128*128*128
    __bf16* Gb  = (__bf16*)(ws + 2 * NB1);                 // 128*128*128
    __bf16* Pb  = (__bf16*)(ws + 7 * NB1);                 // 128*64*128
    __bf16* Yb  = Pb + (size_t)128 * 64 * 128;             // 128*64*128
    __bf16* S0b = (__bf16*)(ws + 3 * NB1);                 // 128*128*128 (reuse after PRE2)

    proj_gemm_mfma<<<dim3(64, 3), 256, 0, stream>>>(x, kpw, qpw, vpw, kpb, qpb, vpb, kT, qT, vT);
    beta_kernel<<<dim3(BB * LL), 256, 0, stream>>>(x, bw, bb, beta);
    conv_silu<<<dim3(8, 8, 12), 256, 0, stream>>>(kT, qT, vT, kcw, qcw, vcw, kcb, qcb, vcb, kc, qc, vc);
    l2norm_reduce<<<dim3(512, 2), 256, 0, stream>>>(kc, qc, invn);
    pack_transpose<<<dim3(64, 4, 12), 256, 0, stream>>>(kc, qc, vc, invn, kT, qT, vT);
    chunk_pre1<<<dim3(NCHUNK, BB), 256, 0, stream>>>(kT, qT, vT, beta, Lb, Wb, Ub);
    chunk_pre2<<<dim3(NCHUNK, BB), 256, 0, stream>>>(kT, qT, Lb, Wb, Ub, HTb, Gb, Pb, Yb);
    delta_serial<<<dim3(BB), 1024, 0, stream>>>(HTb, Gb, S0b);
    chunk_out<<<dim3(NCHUNK, BB), 256, 0, stream>>>(Pb, Yb, S0b, dl);
    rms_norm<<<dim3(BB * LL), 128, 0, stream>>>(dl, rw, dl);
    out_gemm_mfma<<<dim3(64, 16), 256, 0, stream>>>(dl, ow, obi, out);
}

// Round 2
// 432.680 us; speedup vs baseline: 1.5414x; 1.2841x over previous
//
#include <hip/hip_runtime.h>
#include <math.h>

#define LL 2048
#define DD 128
#define BB 4
#define CK 64
#define NCHUNK 32

typedef __bf16 bf16x8 __attribute__((ext_vector_type(8)));
typedef __bf16 bf16x4 __attribute__((ext_vector_type(4)));
typedef float floatx4 __attribute__((ext_vector_type(4)));

// ================= proj GEMM (bf16 MFMA): C(8192x128 x3) = x(8192x2048) @ w^T + b =========
__global__ __launch_bounds__(256) void proj_gemm_mfma(
    const float* __restrict__ x,
    const float* __restrict__ kw, const float* __restrict__ qw, const float* __restrict__ vw,
    const float* __restrict__ kb, const float* __restrict__ qb, const float* __restrict__ vb,
    float* __restrict__ k0, float* __restrict__ q0, float* __restrict__ v0)
{
    const int arr = blockIdx.y;
    const float* __restrict__ w   = arr == 0 ? kw : (arr == 1 ? qw : vw);
    const float* __restrict__ bia = arr == 0 ? kb : (arr == 1 ? qb : vb);
    float* __restrict__ out       = arr == 0 ? k0 : (arr == 1 ? q0 : v0);

    __shared__ __bf16 As[128][72];
    __shared__ __bf16 Bs[128][72];

    const int t    = threadIdx.x;
    const int wave = t >> 6, lane = t & 63;
    const int wm   = wave & 1, wn = wave >> 1;
    const int m    = lane & 15, quad = lane >> 4;
    const int row0 = blockIdx.x * 128;

    floatx4 acc[4][4] = {};

    for (int k0i = 0; k0i < 2048; k0i += 64) {
        #pragma unroll
        for (int c = 0; c < 4; c++) {
            int chunk = t + c * 256;
            int r = chunk >> 3, p = chunk & 7;
            const float4* src = (const float4*)&x[(size_t)(row0 + r) * 2048 + k0i + p * 8];
            float4 f0 = src[0], f1 = src[1];
            bf16x8 v8;
            v8[0] = (__bf16)f0.x; v8[1] = (__bf16)f0.y; v8[2] = (__bf16)f0.z; v8[3] = (__bf16)f0.w;
            v8[4] = (__bf16)f1.x; v8[5] = (__bf16)f1.y; v8[6] = (__bf16)f1.z; v8[7] = (__bf16)f1.w;
            *(bf16x8*)&As[r][p * 8] = v8;
        }
        #pragma unroll
        for (int c = 0; c < 4; c++) {
            int chunk = t + c * 256;
            int r = chunk >> 3, p = chunk & 7;
            const float4* src = (const float4*)&w[(size_t)r * 2048 + k0i + p * 8];
            float4 f0 = src[0], f1 = src[1];
            bf16x8 v8;
            v8[0] = (__bf16)f0.x; v8[1] = (__bf16)f0.y; v8[2] = (__bf16)f0.z; v8[3] = (__bf16)f0.w;
            v8[4] = (__bf16)f1.x; v8[5] = (__bf16)f1.y; v8[6] = (__bf16)f1.z; v8[7] = (__bf16)f1.w;
            *(bf16x8*)&Bs[r][p * 8] = v8;
        }
        __syncthreads();
        #pragma unroll
        for (int ks = 0; ks < 2; ks++) {
            bf16x8 af[4], bfr[4];
            #pragma unroll
            for (int i = 0; i < 4; i++)
                af[i] = *(const bf16x8*)&As[wm * 64 + i * 16 + m][ks * 32 + quad * 8];
            #pragma unroll
            for (int j = 0; j < 4; j++)
                bfr[j] = *(const bf16x8*)&Bs[wn * 64 + j * 16 + m][ks * 32 + quad * 8];
            #pragma unroll
            for (int i = 0; i < 4; i++)
                #pragma unroll
                for (int j = 0; j < 4; j++)
                    acc[i][j] = __builtin_amdgcn_mfma_f32_16x16x32_bf16(af[i], bfr[j], acc[i][j], 0, 0, 0);
        }
        __syncthreads();
    }
    #pragma unroll
    for (int i = 0; i < 4; i++) {
        int grow = row0 + wm * 64 + i * 16 + quad * 4;
        #pragma unroll
        for (int j = 0; j < 4; j++) {
            int col = wn * 64 + j * 16 + m;
            float bv = bia[col];
            #pragma unroll
            for (int r = 0; r < 4; r++)
                out[(size_t)(grow + r) * 128 + col] = acc[i][j][r] + bv;
        }
    }
}

// ================= out GEMM (bf16 MFMA): out(8192x2048) = nm(8192x128) @ ow^T + ob ========
__global__ __launch_bounds__(256) void out_gemm_mfma(
    const float* __restrict__ A, const float* __restrict__ w,
    const float* __restrict__ bias, float* __restrict__ out)
{
    __shared__ __bf16 As[128][72];
    __shared__ __bf16 Bs[128][72];

    const int t    = threadIdx.x;
    const int wave = t >> 6, lane = t & 63;
    const int wm   = wave & 1, wn = wave >> 1;
    const int m    = lane & 15, quad = lane >> 4;
    const int row0 = blockIdx.x * 128;
    const int col0 = blockIdx.y * 128;

    floatx4 acc[4][4] = {};

    for (int k0i = 0; k0i < 128; k0i += 64) {
        #pragma unroll
        for (int c = 0; c < 4; c++) {
            int chunk = t + c * 256;
            int r = chunk >> 3, p = chunk & 7;
            const float4* src = (const float4*)&A[(size_t)(row0 + r) * 128 + k0i + p * 8];
            float4 f0 = src[0], f1 = src[1];
            bf16x8 v8;
            v8[0] = (__bf16)f0.x; v8[1] = (__bf16)f0.y; v8[2] = (__bf16)f0.z; v8[3] = (__bf16)f0.w;
            v8[4] = (__bf16)f1.x; v8[5] = (__bf16)f1.y; v8[6] = (__bf16)f1.z; v8[7] = (__bf16)f1.w;
            *(bf16x8*)&As[r][p * 8] = v8;
        }
        #pragma unroll
        for (int c = 0; c < 4; c++) {
            int chunk = t + c * 256;
            int r = chunk >> 3, p = chunk & 7;
            const float4* src = (const float4*)&w[(size_t)(col0 + r) * 128 + k0i + p * 8];
            float4 f0 = src[0], f1 = src[1];
            bf16x8 v8;
            v8[0] = (__bf16)f0.x; v8[1] = (__bf16)f0.y; v8[2] = (__bf16)f0.z; v8[3] = (__bf16)f0.w;
            v8[4] = (__bf16)f1.x; v8[5] = (__bf16)f1.y; v8[6] = (__bf16)f1.z; v8[7] = (__bf16)f1.w;
            *(bf16x8*)&Bs[r][p * 8] = v8;
        }
        __syncthreads();
        #pragma unroll
        for (int ks = 0; ks < 2; ks++) {
            bf16x8 af[4], bfr[4];
            #pragma unroll
            for (int i = 0; i < 4; i++)
                af[i] = *(const bf16x8*)&As[wm * 64 + i * 16 + m][ks * 32 + quad * 8];
            #pragma unroll
            for (int j = 0; j < 4; j++)
                bfr[j] = *(const bf16x8*)&Bs[wn * 64 + j * 16 + m][ks * 32 + quad * 8];
            #pragma unroll
            for (int i = 0; i < 4; i++)
                #pragma unroll
                for (int j = 0; j < 4; j++)
                    acc[i][j] = __builtin_amdgcn_mfma_f32_16x16x32_bf16(af[i], bfr[j], acc[i][j], 0, 0, 0);
        }
        __syncthreads();
    }
    #pragma unroll
    for (int i = 0; i < 4; i++) {
        int grow = row0 + wm * 64 + i * 16 + quad * 4;
        #pragma unroll
        for (int j = 0; j < 4; j++) {
            int col = col0 + wn * 64 + j * 16 + m;
            float bv = bias[col];
            #pragma unroll
            for (int r = 0; r < 4; r++)
                out[(size_t)(grow + r) * 2048 + col] = acc[i][j][r] + bv;
        }
    }
}

// ================= beta = sigmoid(x @ beta_w^T + beta_b) ================
__global__ __launch_bounds__(256) void beta_kernel(
    const float* __restrict__ x, const float* __restrict__ bw,
    const float* __restrict__ bb, float* __restrict__ beta)
{
    const int row = blockIdx.x;
    const float* xr = x + (size_t)row * 2048;
    float s = 0.f;
    for (int j = threadIdx.x; j < 2048; j += 256) s = fmaf(xr[j], bw[j], s);
    #pragma unroll
    for (int m = 1; m < 64; m <<= 1) s += __shfl_xor(s, m, 64);
    __shared__ float red[4];
    if ((threadIdx.x & 63) == 0) red[threadIdx.x >> 6] = s;
    __syncthreads();
    if (threadIdx.x == 0) {
        float tot = red[0] + red[1] + red[2] + red[3] + bb[0];
        beta[row] = 1.f / (1.f + expf(-tot));
    }
}

// ================= pack conv weights (kw=1 column) to bf16 [arr][dt][o][i]; zero sumsq ====
__global__ __launch_bounds__(256) void wpack_zero(
    const float* __restrict__ kw, const float* __restrict__ qw, const float* __restrict__ vw,
    __bf16* __restrict__ wpk, float* __restrict__ sumsq)
{
    const int t = threadIdx.x;
    if (blockIdx.x == 0) {
        #pragma unroll
        for (int e = 0; e < 4; e++) sumsq[t * 4 + e] = 0.f;   // 1024 floats
    }
    int base = (blockIdx.x * 256 + t) * 4;                    // over 3*3*128*128 = 147456
    int arr = base / 49152, rem = base % 49152;
    const float* __restrict__ w = arr == 0 ? kw : arr == 1 ? qw : vw;
    int dt = rem / 16384, rem2 = rem % 16384;
    int o = rem2 >> 7, i0 = rem2 & 127;
    #pragma unroll
    for (int e = 0; e < 4; e++) {
        int i = i0 + e;
        wpk[base + e] = (__bf16)w[(size_t)((o * 128 + i) * 3 + dt) * 3 + 1];
    }
}

// ================= conv as MFMA GEMM: y(s,o) = sum_dt shift(X^T,dt) @ Wdt^T, +bias, SiLU ==
// Output directly in (L,D) layout (replaces conv_silu + pack_transpose).
// Also accumulates per-column sum(y^2) for k,q (replaces l2norm_reduce).
// Xs: in-LDS transpose of X (i,s)->(s,i), row stride 136 bf16 (16B-aligned rows),
// XOR swizzle ((row&7)<<4) on the i index to tame read bank conflicts.
__global__ __launch_bounds__(256) void conv_mfma(
    const float* __restrict__ k0, const float* __restrict__ q0, const float* __restrict__ v0,
    const __bf16* __restrict__ wpk,
    const float* __restrict__ kb, const float* __restrict__ qb, const float* __restrict__ vb,
    float* __restrict__ kcT, float* __restrict__ qcT, float* __restrict__ vcT,
    float* __restrict__ sumsq)
{
    const int sb  = blockIdx.x;            // 32 blocks of 64 s-rows
    const int arr = blockIdx.y >> 2;
    const int b   = blockIdx.y & 3;
    const float* __restrict__ in = (arr == 0 ? k0 : arr == 1 ? q0 : v0) + (size_t)b * DD * LL;
    const float* __restrict__ bi = arr == 0 ? kb : arr == 1 ? qb : vb;
    float* __restrict__ out      = (arr == 0 ? kcT : arr == 1 ? qcT : vcT) + (size_t)b * LL * DD;
    const __bf16* __restrict__ wp = wpk + (size_t)arr * 3 * DD * DD;

    __shared__ __bf16 Xs[66 * 136];        // rows 0..65 <-> s0-1 .. s0+64
    __shared__ float colsum[128];

    const int t = threadIdx.x;
    const int s0 = sb * 64;
    if (t < 128) colsum[t] = 0.f;

    // main rows 1..64 (s = s0..s0+63): coalesced scalar loads (lanes vary s)
    #pragma unroll
    for (int p = 0; p < 32; p++) {
        int idx = t + p * 256;
        int sr = idx & 63, i = idx >> 6;
        float v = in[(size_t)i * LL + s0 + sr];
        int row = sr + 1;
        Xs[row * 136 + (i ^ ((row & 7) << 4))] = (__bf16)v;
    }
    // halo rows 0 and 65 (s = s0-1, s0+64), zero-padded at edges
    {
        int e = t >> 7, i = t & 127;
        int row = e * 65;
        int s = s0 - 1 + e * 65;
        float v = (s >= 0 && s < LL) ? in[(size_t)i * LL + s] : 0.f;
        Xs[row * 136 + (i ^ ((row & 7) << 4))] = (__bf16)v;
    }
    __syncthreads();

    const int wave = t >> 6, lane = t & 63;
    const int wm = wave & 1, wn = wave >> 1;   // wave: 32 s x 64 o
    const int m = lane & 15, quad = lane >> 4;

    floatx4 acc[2][4] = {};
    #pragma unroll
    for (int dt = 0; dt < 3; dt++) {
        bf16x8 bfr[4][4];
        #pragma unroll
        for (int ks = 0; ks < 4; ks++)
            #pragma unroll
            for (int j = 0; j < 4; j++)
                bfr[ks][j] = *(const bf16x8*)&wp[(size_t)(dt * DD + wn * 64 + j * 16 + m) * DD + ks * 32 + quad * 8];
        #pragma unroll
        for (int ks = 0; ks < 4; ks++) {
            bf16x8 af[2];
            #pragma unroll
            for (int ii = 0; ii < 2; ii++) {
                int row = wm * 32 + ii * 16 + m + dt;
                af[ii] = *(const bf16x8*)&Xs[row * 136 + ((ks * 32 + quad * 8) ^ ((row & 7) << 4))];
            }
            #pragma unroll
            for (int ii = 0; ii < 2; ii++)
                #pragma unroll
                for (int j = 0; j < 4; j++)
                    acc[ii][j] = __builtin_amdgcn_mfma_f32_16x16x32_bf16(af[ii], bfr[ks][j], acc[ii][j], 0, 0, 0);
        }
    }

    // epilogue: bias + SiLU, store (s,o); per-column y^2 partials for l2norm (k,q)
    float part[4] = {0.f, 0.f, 0.f, 0.f};
    #pragma unroll
    for (int ii = 0; ii < 2; ii++)
        #pragma unroll
        for (int j = 0; j < 4; j++) {
            int col = wn * 64 + j * 16 + m;
            float bv = bi[col];
            #pragma unroll
            for (int r = 0; r < 4; r++) {
                int srow = s0 + wm * 32 + ii * 16 + quad * 4 + r;
                float v = acc[ii][j][r] + bv;
                float y = v / (1.f + expf(-v));
                out[(size_t)srow * DD + col] = y;
                part[j] = fmaf(y, y, part[j]);
            }
        }
    if (arr < 2) {
        #pragma unroll
        for (int j = 0; j < 4; j++)
            atomicAdd(&colsum[wn * 64 + j * 16 + m], part[j]);
        __syncthreads();
        if (t < 128) atomicAdd(&sumsq[arr * 512 + b * 128 + t], colsum[t]);
    }
}

// ============================================================================
// Chunked delta rule (WY / UT transform), C = 64 — see R0 derivation.
// k,q are l2-normalized on the fly: scale = rsqrt(max(sumsq,1e-24)).
// ============================================================================

// --------- PRE1 (parallel over 128 (b,c)): A, L, and triangular solve -> W, U0
__global__ __launch_bounds__(256) void chunk_pre1(
    const float* __restrict__ kTg, const float* __restrict__ qTg, const float* __restrict__ vTg,
    const float* __restrict__ beta, const float* __restrict__ sumsq,
    __bf16* __restrict__ Lb, __bf16* __restrict__ Wb, __bf16* __restrict__ Ub)
{
    const int c = blockIdx.x, b = blockIdx.y;
    const int gc = b * NCHUNK + c;
    const int t0 = c * CK;
    const float* kbase = kTg + ((size_t)b * LL + t0) * DD;
    const float* qbase = qTg + ((size_t)b * LL + t0) * DD;
    const float* vbase = vTg + ((size_t)b * LL + t0) * DD;

    __shared__ __bf16 Ks[CK][136];
    __shared__ __bf16 Qs[CK][136];
    __shared__ float  Af[CK][65];
    __shared__ float  WU[CK][257];
    __shared__ float  betas[CK];

    const int t = threadIdx.x;
    #pragma unroll
    for (int p = 0; p < 8; p++) {
        int idx = t + p * 256;          // 2048 float4 chunks = 64 x 128
        int r = idx >> 5, c4 = idx & 31;
        float4 sk = *(const float4*)&sumsq[b * 128 + c4 * 4];
        float4 sq = *(const float4*)&sumsq[512 + b * 128 + c4 * 4];
        float ik0 = rsqrtf(fmaxf(sk.x, 1e-24f)), ik1 = rsqrtf(fmaxf(sk.y, 1e-24f));
        float ik2 = rsqrtf(fmaxf(sk.z, 1e-24f)), ik3 = rsqrtf(fmaxf(sk.w, 1e-24f));
        float iq0 = rsqrtf(fmaxf(sq.x, 1e-24f)), iq1 = rsqrtf(fmaxf(sq.y, 1e-24f));
        float iq2 = rsqrtf(fmaxf(sq.z, 1e-24f)), iq3 = rsqrtf(fmaxf(sq.w, 1e-24f));
        float4 f = *(const float4*)&kbase[(size_t)r * DD + c4 * 4];
        bf16x4 v; v[0] = (__bf16)(f.x * ik0); v[1] = (__bf16)(f.y * ik1);
        v[2] = (__bf16)(f.z * ik2); v[3] = (__bf16)(f.w * ik3);
        *(bf16x4*)&Ks[r][c4 * 4] = v;
        float4 g = *(const float4*)&qbase[(size_t)r * DD + c4 * 4];
        bf16x4 u; u[0] = (__bf16)(g.x * iq0); u[1] = (__bf16)(g.y * iq1);
        u[2] = (__bf16)(g.z * iq2); u[3] = (__bf16)(g.w * iq3);
        *(bf16x4*)&Qs[r][c4 * 4] = u;
    }
    if (t < CK) betas[t] = beta[(size_t)b * LL + t0 + t];
    __syncthreads();

    const int wave = t >> 6, lane = t & 63;
    const int wm = wave & 1, wn = wave >> 1;
    const int m = lane & 15, quad = lane >> 4;

    floatx4 accM[2][2] = {}, accL[2][2] = {};
    #pragma unroll
    for (int ks = 0; ks < 4; ks++) {
        bf16x8 ak[2], aq[2], bk[2];
        #pragma unroll
        for (int i = 0; i < 2; i++) {
            ak[i] = *(const bf16x8*)&Ks[wm * 32 + i * 16 + m][ks * 32 + quad * 8];
            aq[i] = *(const bf16x8*)&Qs[wm * 32 + i * 16 + m][ks * 32 + quad * 8];
            bk[i] = *(const bf16x8*)&Ks[wn * 32 + i * 16 + m][ks * 32 + quad * 8];
        }
        #pragma unroll
        for (int i = 0; i < 2; i++)
            #pragma unroll
            for (int j = 0; j < 2; j++) {
                accM[i][j] = __builtin_amdgcn_mfma_f32_16x16x32_bf16(ak[i], bk[j], accM[i][j], 0, 0, 0);
                accL[i][j] = __builtin_amdgcn_mfma_f32_16x16x32_bf16(aq[i], bk[j], accL[i][j], 0, 0, 0);
            }
    }
    #pragma unroll
    for (int i = 0; i < 2; i++)
        #pragma unroll
        for (int j = 0; j < 2; j++)
            #pragma unroll
            for (int r = 0; r < 4; r++) {
                int row = wm * 32 + i * 16 + quad * 4 + r;
                int col = wn * 32 + j * 16 + m;
                Af[row][col] = (col < row) ? betas[row] * accM[i][j][r] : 0.f;
                Lb[((size_t)gc * CK + row) * CK + col] =
                    (col <= row) ? (__bf16)accL[i][j][r] : (__bf16)0.f;
            }
    __syncthreads();

    // forward substitution: (I+A)[W|U0] = beta [K_norm|V]; each thread owns one column
    const int col = t;
    const float* rbase = (col < DD) ? kbase : vbase;
    const int cm = col & (DD - 1);
    const float scale = (col < DD) ? rsqrtf(fmaxf(sumsq[b * 128 + cm], 1e-24f)) : 1.f;
    float cur = rbase[cm] * scale;
    for (int tt = 0; tt < CK; tt++) {
        float nxt = (tt < CK - 1) ? rbase[(size_t)(tt + 1) * DD + cm] * scale : 0.f;
        float acc = betas[tt] * cur;
        for (int s = 0; s < tt; s++)
            acc -= Af[tt][s] * WU[s][col];
        WU[tt][col] = acc;
        __bf16 bv = (__bf16)acc;
        if (col < DD) Wb[((size_t)gc * CK + tt) * DD + col] = bv;
        else          Ub[((size_t)gc * CK + tt) * DD + cm]  = bv;
        cur = nxt;
    }
}

// --------- PRE2 (parallel): H, G, P, Y from W, U0, L, K, Q
__global__ __launch_bounds__(256) void chunk_pre2(
    const float* __restrict__ kTg, const float* __restrict__ qTg,
    const float* __restrict__ sumsq,
    const __bf16* __restrict__ Lb, const __bf16* __restrict__ Wb, const __bf16* __restrict__ Ub,
    __bf16* __restrict__ HTb, __bf16* __restrict__ Gb,
    __bf16* __restrict__ Pb, __bf16* __restrict__ Yb)
{
    const int c = blockIdx.x, b = blockIdx.y;
    const int gc = b * NCHUNK + c;
    const int t0 = c * CK;

    __shared__ __bf16 Kt[DD][72];   // K^T : Kt[j][t]
    __shared__ __bf16 Wt[DD][72];   // W^T : Wt[i][t]
    __shared__ __bf16 Ut[DD][72];   // U0^T: Ut[i][t]
    __shared__ __bf16 Ls[CK][72];   // L[t][s]

    const int t = threadIdx.x;
    #pragma unroll
    for (int p = 0; p < 8; p++) {
        int idx = t + p * 256;        // 2048 chunks of 4 over 64x128
        int tt = idx >> 5, j4 = idx & 31;
        float4 sk = *(const float4*)&sumsq[b * 128 + j4 * 4];
        float4 f = *(const float4*)&kTg[((size_t)b * LL + t0 + tt) * DD + j4 * 4];
        Kt[j4 * 4 + 0][tt] = (__bf16)(f.x * rsqrtf(fmaxf(sk.x, 1e-24f)));
        Kt[j4 * 4 + 1][tt] = (__bf16)(f.y * rsqrtf(fmaxf(sk.y, 1e-24f)));
        Kt[j4 * 4 + 2][tt] = (__bf16)(f.z * rsqrtf(fmaxf(sk.z, 1e-24f)));
        Kt[j4 * 4 + 3][tt] = (__bf16)(f.w * rsqrtf(fmaxf(sk.w, 1e-24f)));
        bf16x4 w = *(const bf16x4*)&Wb[((size_t)gc * CK + tt) * DD + j4 * 4];
        bf16x4 u = *(const bf16x4*)&Ub[((size_t)gc * CK + tt) * DD + j4 * 4];
        #pragma unroll
        for (int e = 0; e < 4; e++) { Wt[j4 * 4 + e][tt] = w[e]; Ut[j4 * 4 + e][tt] = u[e]; }
    }
    #pragma unroll
    for (int p = 0; p < 4; p++) {
        int idx = t + p * 256;        // 1024 chunks of 4 over 64x64
        int tt = idx >> 4, s4 = idx & 15;
        *(bf16x4*)&Ls[tt][s4 * 4] = *(const bf16x4*)&Lb[((size_t)gc * CK + tt) * CK + s4 * 4];
    }
    __syncthreads();

    const int wave = t >> 6, lane = t & 63;
    const int wm = wave & 1, wn = wave >> 1;
    const int m = lane & 15, quad = lane >> 4;

    // H^T (negated): C[j][i] = -sum_t Kt[j][t] Wt[i][t]  (128x128, red 64)
    {
        floatx4 acc[4][4] = {};
        #pragma unroll
        for (int ks = 0; ks < 2; ks++) {
            bf16x8 a[4], bb[4];
            #pragma unroll
            for (int i = 0; i < 4; i++) {
                a[i]  = *(const bf16x8*)&Kt[wm * 64 + i * 16 + m][ks * 32 + quad * 8];
                bb[i] = *(const bf16x8*)&Wt[wn * 64 + i * 16 + m][ks * 32 + quad * 8];
            }
            #pragma unroll
            for (int i = 0; i < 4; i++)
                #pragma unroll
                for (int j = 0; j < 4; j++)
                    acc[i][j] = __builtin_amdgcn_mfma_f32_16x16x32_bf16(a[i], bb[j], acc[i][j], 0, 0, 0);
        }
        #pragma unroll
        for (int i = 0; i < 4; i++)
            #pragma unroll
            for (int j = 0; j < 4; j++)
                #pragma unroll
                for (int r = 0; r < 4; r++) {
                    int row = wm * 64 + i * 16 + quad * 4 + r;
                    int cx  = wn * 64 + j * 16 + m;
                    HTb[((size_t)gc * DD + row) * DD + cx] = (__bf16)(-acc[i][j][r]);
                }
    }
    // G: C[i][j] = sum_t Ut[i][t] Kt[j][t]
    {
        floatx4 acc[4][4] = {};
        #pragma unroll
        for (int ks = 0; ks < 2; ks++) {
            bf16x8 a[4], bb[4];
            #pragma unroll
            for (int i = 0; i < 4; i++) {
                a[i]  = *(const bf16x8*)&Ut[wm * 64 + i * 16 + m][ks * 32 + quad * 8];
                bb[i] = *(const bf16x8*)&Kt[wn * 64 + i * 16 + m][ks * 32 + quad * 8];
            }
            #pragma unroll
            for (int i = 0; i < 4; i++)
                #pragma unroll
                for (int j = 0; j < 4; j++)
                    acc[i][j] = __builtin_amdgcn_mfma_f32_16x16x32_bf16(a[i], bb[j], acc[i][j], 0, 0, 0);
        }
        #pragma unroll
        for (int i = 0; i < 4; i++)
            #pragma unroll
            for (int j = 0; j < 4; j++)
                #pragma unroll
                for (int r = 0; r < 4; r++) {
                    int row = wm * 64 + i * 16 + quad * 4 + r;
                    int cx  = wn * 64 + j * 16 + m;
                    Gb[((size_t)gc * DD + row) * DD + cx] = (__bf16)acc[i][j][r];
                }
    }
    // P = Q - L W : C[t][i] = sum_s Ls[t][s] Wt[i][s]  (64x128, red 64)
    {
        floatx4 acc[2][4] = {};
        #pragma unroll
        for (int ks = 0; ks < 2; ks++) {
            bf16x8 a[2], bb[4];
            #pragma unroll
            for (int i = 0; i < 2; i++)
                a[i] = *(const bf16x8*)&Ls[wm * 32 + i * 16 + m][ks * 32 + quad * 8];
            #pragma unroll
            for (int j = 0; j < 4; j++)
                bb[j] = *(const bf16x8*)&Wt[wn * 64 + j * 16 + m][ks * 32 + quad * 8];
            #pragma unroll
            for (int i = 0; i < 2; i++)
                #pragma unroll
                for (int j = 0; j < 4; j++)
                    acc[i][j] = __builtin_amdgcn_mfma_f32_16x16x32_bf16(a[i], bb[j], acc[i][j], 0, 0, 0);
        }
        #pragma unroll
        for (int i = 0; i < 2; i++)
            #pragma unroll
            for (int j = 0; j < 4; j++)
                #pragma unroll
                for (int r = 0; r < 4; r++) {
                    int row = wm * 32 + i * 16 + quad * 4 + r;
                    int cx  = wn * 64 + j * 16 + m;
                    float iq = rsqrtf(fmaxf(sumsq[512 + b * 128 + cx], 1e-24f));
                    float qv = qTg[((size_t)b * LL + t0 + row) * DD + cx] * iq;
                    Pb[((size_t)gc * CK + row) * DD + cx] = (__bf16)(qv - acc[i][j][r]);
                }
    }
    // Y = L U0 : C[t][i] = sum_s Ls[t][s] Ut[i][s]
    {
        floatx4 acc[2][4] = {};
        #pragma unroll
        for (int ks = 0; ks < 2; ks++) {
            bf16x8 a[2], bb[4];
            #pragma unroll
            for (int i = 0; i < 2; i++)
                a[i] = *(const bf16x8*)&Ls[wm * 32 + i * 16 + m][ks * 32 + quad * 8];
            #pragma unroll
            for (int j = 0; j < 4; j++)
                bb[j] = *(const bf16x8*)&Ut[wn * 64 + j * 16 + m][ks * 32 + quad * 8];
            #pragma unroll
            for (int i = 0; i < 2; i++)
                #pragma unroll
                for (int j = 0; j < 4; j++)
                    acc[i][j] = __builtin_amdgcn_mfma_f32_16x16x32_bf16(a[i], bb[j], acc[i][j], 0, 0, 0);
        }
        #pragma unroll
        for (int i = 0; i < 2; i++)
            #pragma unroll
            for (int j = 0; j < 4; j++)
                #pragma unroll
                for (int r = 0; r < 4; r++) {
                    int row = wm * 32 + i * 16 + quad * 4 + r;
                    int cx  = wn * 64 + j * 16 + m;
                    Yb[((size_t)gc * CK + row) * DD + cx] = (__bf16)acc[i][j][r];
                }
    }
}

// --------- serial chain: S <- S (I - H) + G per chunk; snapshot S0 each chunk
__global__ __launch_bounds__(1024) void delta_serial(
    const __bf16* __restrict__ HTb, const __bf16* __restrict__ Gb, __bf16* __restrict__ S0b)
{
    const int b = blockIdx.x;
    __shared__ __bf16 Ss[DD][136];
    __shared__ __bf16 Hs[DD][136];
    const int t = threadIdx.x;
    const int wave = t >> 6, lane = t & 63;
    const int wi = wave >> 2, wj = wave & 3;
    const int m = lane & 15, quad = lane >> 4;

    floatx4 acc[2][2] = {};   // fp32 S across the whole chain

    for (int c = 0; c < NCHUNK; c++) {
        const size_t gco = (size_t)(b * NCHUNK + c) * DD * DD;
        #pragma unroll
        for (int i = 0; i < 2; i++)
            #pragma unroll
            for (int j = 0; j < 2; j++) {
                int row = wi * 32 + i * 16 + quad * 4;
                int cx  = wj * 32 + j * 16 + m;
                #pragma unroll
                for (int r = 0; r < 4; r++)
                    Ss[row + r][cx] = (__bf16)acc[i][j][r];
            }
        __syncthreads();
        #pragma unroll
        for (int p = 0; p < 4; p++) {
            int idx = t + p * 1024;          // 4096 chunks of 4 over 128x128
            int row = idx >> 5, c4 = idx & 31;
            *(bf16x4*)&S0b[gco + (size_t)row * DD + c4 * 4] = *(const bf16x4*)&Ss[row][c4 * 4];
            *(bf16x4*)&Hs[row][c4 * 4] = *(const bf16x4*)&HTb[gco + (size_t)row * DD + c4 * 4];
        }
        #pragma unroll
        for (int i = 0; i < 2; i++)
            #pragma unroll
            for (int j = 0; j < 2; j++) {
                int row = wi * 32 + i * 16 + quad * 4;
                int cx  = wj * 32 + j * 16 + m;
                #pragma unroll
                for (int r = 0; r < 4; r++)
                    acc[i][j][r] += (float)Gb[gco + (size_t)(row + r) * DD + cx];
            }
        __syncthreads();
        #pragma unroll
        for (int ks = 0; ks < 4; ks++) {
            bf16x8 a[2], bb[2];
            #pragma unroll
            for (int i = 0; i < 2; i++) {
                a[i]  = *(const bf16x8*)&Ss[wi * 32 + i * 16 + m][ks * 32 + quad * 8];
                bb[i] = *(const bf16x8*)&Hs[wj * 32 + i * 16 + m][ks * 32 + quad * 8];
            }
            #pragma unroll
            for (int i = 0; i < 2; i++)
                #pragma unroll
                for (int j = 0; j < 2; j++)
                    acc[i][j] = __builtin_amdgcn_mfma_f32_16x16x32_bf16(a[i], bb[j], acc[i][j], 0, 0, 0);
        }
        __syncthreads();
    }
}

// --------- O = P S0^T + Y per chunk (parallel) -> dl (fp32, (B,L,D))
__global__ __launch_bounds__(256) void chunk_out(
    const __bf16* __restrict__ Pb, const __bf16* __restrict__ Yb, const __bf16* __restrict__ S0b,
    float* __restrict__ dl)
{
    const int c = blockIdx.x, b = blockIdx.y;
    const int gc = b * NCHUNK + c;
    const int t0 = c * CK;
    __shared__ __bf16 Ps[CK][136];
    __shared__ __bf16 Sb[DD][136];
    const int t = threadIdx.x;
    #pragma unroll
    for (int p = 0; p < 8; p++) {
        int idx = t + p * 256;
        int row = idx >> 5, c4 = idx & 31;
        *(bf16x4*)&Ps[row][c4 * 4] = *(const bf16x4*)&Pb[((size_t)gc * CK + row) * DD + c4 * 4];
    }
    #pragma unroll
    for (int p = 0; p < 16; p++) {
        int idx = t + p * 256;
        int row = idx >> 5, c4 = idx & 31;
        *(bf16x4*)&Sb[row][c4 * 4] = *(const bf16x4*)&S0b[((size_t)gc * DD + row) * DD + c4 * 4];
    }
    __syncthreads();

    const int wave = t >> 6, lane = t & 63;
    const int wm = wave & 1, wn = wave >> 1;
    const int m = lane & 15, quad = lane >> 4;

    floatx4 acc[2][4] = {};
    #pragma unroll
    for (int ks = 0; ks < 4; ks++) {
        bf16x8 a[2], bb[4];
        #pragma unroll
        for (int i = 0; i < 2; i++)
            a[i] = *(const bf16x8*)&Ps[wm * 32 + i * 16 + m][ks * 32 + quad * 8];
        #pragma unroll
        for (int j = 0; j < 4; j++)
            bb[j] = *(const bf16x8*)&Sb[wn * 64 + j * 16 + m][ks * 32 + quad * 8];
        #pragma unroll
        for (int i = 0; i < 2; i++)
            #pragma unroll
            for (int j = 0; j < 4; j++)
                acc[i][j] = __builtin_amdgcn_mfma_f32_16x16x32_bf16(a[i], bb[j], acc[i][j], 0, 0, 0);
    }
    #pragma unroll
    for (int i = 0; i < 2; i++)
        #pragma unroll
        for (int j = 0; j < 4; j++)
            #pragma unroll
            for (int r = 0; r < 4; r++) {
                int row = wm * 32 + i * 16 + quad * 4 + r;
                int cx  = wn * 64 + j * 16 + m;
                float y = (float)Yb[((size_t)gc * CK + row) * DD + cx];
                dl[((size_t)b * LL + t0 + row) * DD + cx] = acc[i][j][r] + y;
            }
}

// ================= RMSNorm over D (in-place capable) ================
__global__ __launch_bounds__(128) void rms_norm(
    const float* __restrict__ dl, const float* __restrict__ rms_w, float* __restrict__ normed)
{
    const int row = blockIdx.x;
    const int t = threadIdx.x;
    float v = dl[(size_t)row * DD + t];
    float s = v * v;
    #pragma unroll
    for (int m = 1; m < 64; m <<= 1) s += __shfl_xor(s, m, 64);
    __shared__ float r2[2];
    if ((t & 63) == 0) r2[t >> 6] = s;
    __syncthreads();
    float ms = (r2[0] + r2[1]) * (1.f / 128.f);
    normed[(size_t)row * DD + t] = v * rsqrtf(ms + 1.1920928955078125e-07f) * rms_w[t];
}

extern "C" void kernel_launch(void* const* d_in, const int* in_sizes, int n_in,
                              void* d_out, int out_size, void* d_ws, size_t ws_size,
                              hipStream_t stream) {
    const float* x    = (const float*)d_in[0];
    const float* kpw  = (const float*)d_in[1];
    const float* kpb  = (const float*)d_in[2];
    const float* qpw  = (const float*)d_in[3];
    const float* qpb  = (const float*)d_in[4];
    const float* vpw  = (const float*)d_in[5];
    const float* vpb  = (const float*)d_in[6];
    const float* kcw  = (const float*)d_in[7];
    const float* kcb  = (const float*)d_in[8];
    const float* qcw  = (const float*)d_in[9];
    const float* qcb  = (const float*)d_in[10];
    const float* vcw  = (const float*)d_in[11];
    const float* vcb  = (const float*)d_in[12];
    const float* bw   = (const float*)d_in[13];
    const float* bb   = (const float*)d_in[14];
    const float* rw   = (const float*)d_in[15];
    const float* ow   = (const float*)d_in[16];
    const float* obi  = (const float*)d_in[17];
    float* out = (float*)d_out;

    float* ws = (float*)d_ws;
    const size_t NB1 = (size_t)BB * DD * LL;   // 1,048,576 floats = 4 MB
    // slot map (each slot NB1 floats = 4 MB):
    //  0: k0 (proj, (i,s)) -> Lb+Wb(bf16, 3MB) -> S0b(bf16, 4MB)
    //  1: q0 -> Ub(bf16, 2MB)
    //  2: v0 -> HTb(bf16, 4MB)
    //  3: kcT (L,D fp32)   4: qcT   5: vcT -> Gb(bf16, 4MB)
    //  6: dl (fp32, in-place rms)   7: Pb+Yb(bf16, 4MB)
    //  8: beta (32KB) + sumsq (4KB) + wpk (288KB bf16)
    float* k0  = ws;
    float* q0  = ws + NB1;
    float* v0  = ws + 2 * NB1;
    float* kcT = ws + 3 * NB1;
    float* qcT = ws + 4 * NB1;
    float* vcT = ws + 5 * NB1;
    float* dl  = ws + 6 * NB1;
    float* beta  = ws + 8 * NB1;
    float* sumsq = beta + (size_t)BB * LL;
    __bf16* wpk  = (__bf16*)(sumsq + 1024);

    __bf16* Lb  = (__bf16*)k0;                 // 128*64*64  = 1 MB
    __bf16* Wb  = Lb + (size_t)128 * 64 * 64;  // 128*64*128 = 2 MB
    __bf16* Ub  = (__bf16*)q0;                 // 2 MB
    __bf16* HTb = (__bf16*)v0;                 // 4 MB
    __bf16* Gb  = (__bf16*)vcT;                // 4 MB
    __bf16* Pb  = (__bf16*)(ws + 7 * NB1);     // 2 MB
    __bf16* Yb  = Pb + (size_t)128 * 64 * 128; // 2 MB
    __bf16* S0b = (__bf16*)k0;                 // 4 MB (after pre2)

    proj_gemm_mfma<<<dim3(64, 3), 256, 0, stream>>>(x, kpw, qpw, vpw, kpb, qpb, vpb, k0, q0, v0);
    beta_kernel<<<dim3(BB * LL), 256, 0, stream>>>(x, bw, bb, beta);
    wpack_zero<<<dim3(144), 256, 0, stream>>>(kcw, qcw, vcw, wpk, sumsq);
    conv_mfma<<<dim3(32, 12), 256, 0, stream>>>(k0, q0, v0, wpk, kcb, qcb, vcb, kcT, qcT, vcT, sumsq);
    chunk_pre1<<<dim3(NCHUNK, BB), 256, 0, stream>>>(kcT, qcT, vcT, beta, sumsq, Lb, Wb, Ub);
    chunk_pre2<<<dim3(NCHUNK, BB), 256, 0, stream>>>(kcT, qcT, sumsq, Lb, Wb, Ub, HTb, Gb, Pb, Yb);
    delta_serial<<<dim3(BB), 1024, 0, stream>>>(HTb, Gb, S0b);
    chunk_out<<<dim3(NCHUNK, BB), 256, 0, stream>>>(Pb, Yb, S0b, dl);
    rms_norm<<<dim3(BB * LL), 128, 0, stream>>>(dl, rw, dl);
    out_gemm_mfma<<<dim3(64, 16), 256, 0, stream>>>(dl, ow, obi, out);
}

// Round 3
// 364.597 us; speedup vs baseline: 1.8292x; 1.1867x over previous
//
#include <hip/hip_runtime.h>
#include <math.h>

#define LL 2048
#define DD 128
#define BB 4
#define CK 64
#define NCHUNK 32

typedef __bf16 bf16x8 __attribute__((ext_vector_type(8)));
typedef __bf16 bf16x4 __attribute__((ext_vector_type(4)));
typedef float floatx4 __attribute__((ext_vector_type(4)));

// ================= proj GEMM (bf16 MFMA): C(8192x128 x3) = x(8192x2048) @ w^T + b =========
__global__ __launch_bounds__(256) void proj_gemm_mfma(
    const float* __restrict__ x,
    const float* __restrict__ kw, const float* __restrict__ qw, const float* __restrict__ vw,
    const float* __restrict__ kb, const float* __restrict__ qb, const float* __restrict__ vb,
    float* __restrict__ k0, float* __restrict__ q0, float* __restrict__ v0)
{
    const int arr = blockIdx.y;
    const float* __restrict__ w   = arr == 0 ? kw : (arr == 1 ? qw : vw);
    const float* __restrict__ bia = arr == 0 ? kb : (arr == 1 ? qb : vb);
    float* __restrict__ out       = arr == 0 ? k0 : (arr == 1 ? q0 : v0);

    __shared__ __bf16 As[128][72];
    __shared__ __bf16 Bs[128][72];

    const int t    = threadIdx.x;
    const int wave = t >> 6, lane = t & 63;
    const int wm   = wave & 1, wn = wave >> 1;
    const int m    = lane & 15, quad = lane >> 4;
    const int row0 = blockIdx.x * 128;

    floatx4 acc[4][4] = {};

    for (int k0i = 0; k0i < 2048; k0i += 64) {
        #pragma unroll
        for (int c = 0; c < 4; c++) {
            int chunk = t + c * 256;
            int r = chunk >> 3, p = chunk & 7;
            const float4* src = (const float4*)&x[(size_t)(row0 + r) * 2048 + k0i + p * 8];
            float4 f0 = src[0], f1 = src[1];
            bf16x8 v8;
            v8[0] = (__bf16)f0.x; v8[1] = (__bf16)f0.y; v8[2] = (__bf16)f0.z; v8[3] = (__bf16)f0.w;
            v8[4] = (__bf16)f1.x; v8[5] = (__bf16)f1.y; v8[6] = (__bf16)f1.z; v8[7] = (__bf16)f1.w;
            *(bf16x8*)&As[r][p * 8] = v8;
        }
        #pragma unroll
        for (int c = 0; c < 4; c++) {
            int chunk = t + c * 256;
            int r = chunk >> 3, p = chunk & 7;
            const float4* src = (const float4*)&w[(size_t)r * 2048 + k0i + p * 8];
            float4 f0 = src[0], f1 = src[1];
            bf16x8 v8;
            v8[0] = (__bf16)f0.x; v8[1] = (__bf16)f0.y; v8[2] = (__bf16)f0.z; v8[3] = (__bf16)f0.w;
            v8[4] = (__bf16)f1.x; v8[5] = (__bf16)f1.y; v8[6] = (__bf16)f1.z; v8[7] = (__bf16)f1.w;
            *(bf16x8*)&Bs[r][p * 8] = v8;
        }
        __syncthreads();
        #pragma unroll
        for (int ks = 0; ks < 2; ks++) {
            bf16x8 af[4], bfr[4];
            #pragma unroll
            for (int i = 0; i < 4; i++)
                af[i] = *(const bf16x8*)&As[wm * 64 + i * 16 + m][ks * 32 + quad * 8];
            #pragma unroll
            for (int j = 0; j < 4; j++)
                bfr[j] = *(const bf16x8*)&Bs[wn * 64 + j * 16 + m][ks * 32 + quad * 8];
            #pragma unroll
            for (int i = 0; i < 4; i++)
                #pragma unroll
                for (int j = 0; j < 4; j++)
                    acc[i][j] = __builtin_amdgcn_mfma_f32_16x16x32_bf16(af[i], bfr[j], acc[i][j], 0, 0, 0);
        }
        __syncthreads();
    }
    #pragma unroll
    for (int i = 0; i < 4; i++) {
        int grow = row0 + wm * 64 + i * 16 + quad * 4;
        #pragma unroll
        for (int j = 0; j < 4; j++) {
            int col = wn * 64 + j * 16 + m;
            float bv = bia[col];
            #pragma unroll
            for (int r = 0; r < 4; r++)
                out[(size_t)(grow + r) * 128 + col] = acc[i][j][r] + bv;
        }
    }
}

// ================= out GEMM (bf16 MFMA): out(8192x2048) = nmb(8192x128 bf16) @ ow^T + ob ==
__global__ __launch_bounds__(256) void out_gemm_mfma(
    const __bf16* __restrict__ A, const float* __restrict__ w,
    const float* __restrict__ bias, float* __restrict__ out)
{
    __shared__ __bf16 As[128][72];
    __shared__ __bf16 Bs[128][72];

    const int t    = threadIdx.x;
    const int wave = t >> 6, lane = t & 63;
    const int wm   = wave & 1, wn = wave >> 1;
    const int m    = lane & 15, quad = lane >> 4;
    const int row0 = blockIdx.x * 128;
    const int col0 = blockIdx.y * 128;

    floatx4 acc[4][4] = {};

    for (int k0i = 0; k0i < 128; k0i += 64) {
        #pragma unroll
        for (int c = 0; c < 4; c++) {
            int chunk = t + c * 256;
            int r = chunk >> 3, p = chunk & 7;
            *(bf16x8*)&As[r][p * 8] = *(const bf16x8*)&A[(size_t)(row0 + r) * 128 + k0i + p * 8];
        }
        #pragma unroll
        for (int c = 0; c < 4; c++) {
            int chunk = t + c * 256;
            int r = chunk >> 3, p = chunk & 7;
            const float4* src = (const float4*)&w[(size_t)(col0 + r) * 128 + k0i + p * 8];
            float4 f0 = src[0], f1 = src[1];
            bf16x8 v8;
            v8[0] = (__bf16)f0.x; v8[1] = (__bf16)f0.y; v8[2] = (__bf16)f0.z; v8[3] = (__bf16)f0.w;
            v8[4] = (__bf16)f1.x; v8[5] = (__bf16)f1.y; v8[6] = (__bf16)f1.z; v8[7] = (__bf16)f1.w;
            *(bf16x8*)&Bs[r][p * 8] = v8;
        }
        __syncthreads();
        #pragma unroll
        for (int ks = 0; ks < 2; ks++) {
            bf16x8 af[4], bfr[4];
            #pragma unroll
            for (int i = 0; i < 4; i++)
                af[i] = *(const bf16x8*)&As[wm * 64 + i * 16 + m][ks * 32 + quad * 8];
            #pragma unroll
            for (int j = 0; j < 4; j++)
                bfr[j] = *(const bf16x8*)&Bs[wn * 64 + j * 16 + m][ks * 32 + quad * 8];
            #pragma unroll
            for (int i = 0; i < 4; i++)
                #pragma unroll
                for (int j = 0; j < 4; j++)
                    acc[i][j] = __builtin_amdgcn_mfma_f32_16x16x32_bf16(af[i], bfr[j], acc[i][j], 0, 0, 0);
        }
        __syncthreads();
    }
    #pragma unroll
    for (int i = 0; i < 4; i++) {
        int grow = row0 + wm * 64 + i * 16 + quad * 4;
        #pragma unroll
        for (int j = 0; j < 4; j++) {
            int col = col0 + wn * 64 + j * 16 + m;
            float bv = bias[col];
            #pragma unroll
            for (int r = 0; r < 4; r++)
                out[(size_t)(grow + r) * 2048 + col] = acc[i][j][r] + bv;
        }
    }
}

// ================= beta = sigmoid(x @ beta_w^T + beta_b) ================
__global__ __launch_bounds__(256) void beta_kernel(
    const float* __restrict__ x, const float* __restrict__ bw,
    const float* __restrict__ bb, float* __restrict__ beta)
{
    const int row = blockIdx.x;
    const float* xr = x + (size_t)row * 2048;
    float s = 0.f;
    for (int j = threadIdx.x; j < 2048; j += 256) s = fmaf(xr[j], bw[j], s);
    #pragma unroll
    for (int m = 1; m < 64; m <<= 1) s += __shfl_xor(s, m, 64);
    __shared__ float red[4];
    if ((threadIdx.x & 63) == 0) red[threadIdx.x >> 6] = s;
    __syncthreads();
    if (threadIdx.x == 0) {
        float tot = red[0] + red[1] + red[2] + red[3] + bb[0];
        beta[row] = 1.f / (1.f + expf(-tot));
    }
}

// ================= pack conv weights (kw=1 column) to bf16 [arr][dt][o][i]; zero sumsq ====
__global__ __launch_bounds__(256) void wpack_zero(
    const float* __restrict__ kw, const float* __restrict__ qw, const float* __restrict__ vw,
    __bf16* __restrict__ wpk, float* __restrict__ sumsq)
{
    const int t = threadIdx.x;
    if (blockIdx.x == 0) {
        #pragma unroll
        for (int e = 0; e < 4; e++) sumsq[t * 4 + e] = 0.f;
    }
    int base = (blockIdx.x * 256 + t) * 4;
    int arr = base / 49152, rem = base % 49152;
    const float* __restrict__ w = arr == 0 ? kw : arr == 1 ? qw : vw;
    int dt = rem / 16384, rem2 = rem % 16384;
    int o = rem2 >> 7, i0 = rem2 & 127;
    #pragma unroll
    for (int e = 0; e < 4; e++) {
        int i = i0 + e;
        wpk[base + e] = (__bf16)w[(size_t)((o * 128 + i) * 3 + dt) * 3 + 1];
    }
}

// ================= conv as MFMA GEMM + bias + SiLU + fused l2norm partials ================
__global__ __launch_bounds__(256) void conv_mfma(
    const float* __restrict__ k0, const float* __restrict__ q0, const float* __restrict__ v0,
    const __bf16* __restrict__ wpk,
    const float* __restrict__ kb, const float* __restrict__ qb, const float* __restrict__ vb,
    float* __restrict__ kcT, float* __restrict__ qcT, float* __restrict__ vcT,
    float* __restrict__ sumsq)
{
    const int sb  = blockIdx.x;
    const int arr = blockIdx.y >> 2;
    const int b   = blockIdx.y & 3;
    const float* __restrict__ in = (arr == 0 ? k0 : arr == 1 ? q0 : v0) + (size_t)b * DD * LL;
    const float* __restrict__ bi = arr == 0 ? kb : arr == 1 ? qb : vb;
    float* __restrict__ out      = (arr == 0 ? kcT : arr == 1 ? qcT : vcT) + (size_t)b * LL * DD;
    const __bf16* __restrict__ wp = wpk + (size_t)arr * 3 * DD * DD;

    __shared__ __bf16 Xs[66 * 136];
    __shared__ float colsum[128];

    const int t = threadIdx.x;
    const int s0 = sb * 64;
    if (t < 128) colsum[t] = 0.f;

    #pragma unroll
    for (int p = 0; p < 32; p++) {
        int idx = t + p * 256;
        int sr = idx & 63, i = idx >> 6;
        float v = in[(size_t)i * LL + s0 + sr];
        int row = sr + 1;
        Xs[row * 136 + (i ^ ((row & 7) << 4))] = (__bf16)v;
    }
    {
        int e = t >> 7, i = t & 127;
        int row = e * 65;
        int s = s0 - 1 + e * 65;
        float v = (s >= 0 && s < LL) ? in[(size_t)i * LL + s] : 0.f;
        Xs[row * 136 + (i ^ ((row & 7) << 4))] = (__bf16)v;
    }
    __syncthreads();

    const int wave = t >> 6, lane = t & 63;
    const int wm = wave & 1, wn = wave >> 1;
    const int m = lane & 15, quad = lane >> 4;

    floatx4 acc[2][4] = {};
    #pragma unroll
    for (int dt = 0; dt < 3; dt++) {
        bf16x8 bfr[4][4];
        #pragma unroll
        for (int ks = 0; ks < 4; ks++)
            #pragma unroll
            for (int j = 0; j < 4; j++)
                bfr[ks][j] = *(const bf16x8*)&wp[(size_t)(dt * DD + wn * 64 + j * 16 + m) * DD + ks * 32 + quad * 8];
        #pragma unroll
        for (int ks = 0; ks < 4; ks++) {
            bf16x8 af[2];
            #pragma unroll
            for (int ii = 0; ii < 2; ii++) {
                int row = wm * 32 + ii * 16 + m + dt;
                af[ii] = *(const bf16x8*)&Xs[row * 136 + ((ks * 32 + quad * 8) ^ ((row & 7) << 4))];
            }
            #pragma unroll
            for (int ii = 0; ii < 2; ii++)
                #pragma unroll
                for (int j = 0; j < 4; j++)
                    acc[ii][j] = __builtin_amdgcn_mfma_f32_16x16x32_bf16(af[ii], bfr[ks][j], acc[ii][j], 0, 0, 0);
        }
    }

    float part[4] = {0.f, 0.f, 0.f, 0.f};
    #pragma unroll
    for (int ii = 0; ii < 2; ii++)
        #pragma unroll
        for (int j = 0; j < 4; j++) {
            int col = wn * 64 + j * 16 + m;
            float bv = bi[col];
            #pragma unroll
            for (int r = 0; r < 4; r++) {
                int srow = s0 + wm * 32 + ii * 16 + quad * 4 + r;
                float v = acc[ii][j][r] + bv;
                float y = v / (1.f + expf(-v));
                out[(size_t)srow * DD + col] = y;
                part[j] = fmaf(y, y, part[j]);
            }
        }
    if (arr < 2) {
        #pragma unroll
        for (int j = 0; j < 4; j++)
            atomicAdd(&colsum[wn * 64 + j * 16 + m], part[j]);
        __syncthreads();
        if (t < 128) atomicAdd(&sumsq[arr * 512 + b * 128 + t], colsum[t]);
    }
}

// ============================================================================
// Chunked delta rule (WY / UT transform), C = 64 — see R0 derivation.
// ============================================================================

// --------- PRE1 (parallel over 128 (b,c)): A, L, and triangular solve -> W, U0
__global__ __launch_bounds__(256) void chunk_pre1(
    const float* __restrict__ kTg, const float* __restrict__ qTg, const float* __restrict__ vTg,
    const float* __restrict__ beta, const float* __restrict__ sumsq,
    __bf16* __restrict__ Lb, __bf16* __restrict__ Wb, __bf16* __restrict__ Ub)
{
    const int c = blockIdx.x, b = blockIdx.y;
    const int gc = b * NCHUNK + c;
    const int t0 = c * CK;
    const float* kbase = kTg + ((size_t)b * LL + t0) * DD;
    const float* qbase = qTg + ((size_t)b * LL + t0) * DD;
    const float* vbase = vTg + ((size_t)b * LL + t0) * DD;

    __shared__ __bf16 Ks[CK][136];
    __shared__ __bf16 Qs[CK][136];
    __shared__ float  Af[CK][65];
    __shared__ float  WU[CK][257];
    __shared__ float  betas[CK];

    const int t = threadIdx.x;
    #pragma unroll
    for (int p = 0; p < 8; p++) {
        int idx = t + p * 256;
        int r = idx >> 5, c4 = idx & 31;
        float4 sk = *(const float4*)&sumsq[b * 128 + c4 * 4];
        float4 sq = *(const float4*)&sumsq[512 + b * 128 + c4 * 4];
        float ik0 = rsqrtf(fmaxf(sk.x, 1e-24f)), ik1 = rsqrtf(fmaxf(sk.y, 1e-24f));
        float ik2 = rsqrtf(fmaxf(sk.z, 1e-24f)), ik3 = rsqrtf(fmaxf(sk.w, 1e-24f));
        float iq0 = rsqrtf(fmaxf(sq.x, 1e-24f)), iq1 = rsqrtf(fmaxf(sq.y, 1e-24f));
        float iq2 = rsqrtf(fmaxf(sq.z, 1e-24f)), iq3 = rsqrtf(fmaxf(sq.w, 1e-24f));
        float4 f = *(const float4*)&kbase[(size_t)r * DD + c4 * 4];
        bf16x4 v; v[0] = (__bf16)(f.x * ik0); v[1] = (__bf16)(f.y * ik1);
        v[2] = (__bf16)(f.z * ik2); v[3] = (__bf16)(f.w * ik3);
        *(bf16x4*)&Ks[r][c4 * 4] = v;
        float4 g = *(const float4*)&qbase[(size_t)r * DD + c4 * 4];
        bf16x4 u; u[0] = (__bf16)(g.x * iq0); u[1] = (__bf16)(g.y * iq1);
        u[2] = (__bf16)(g.z * iq2); u[3] = (__bf16)(g.w * iq3);
        *(bf16x4*)&Qs[r][c4 * 4] = u;
    }
    if (t < CK) betas[t] = beta[(size_t)b * LL + t0 + t];
    __syncthreads();

    const int wave = t >> 6, lane = t & 63;
    const int wm = wave & 1, wn = wave >> 1;
    const int m = lane & 15, quad = lane >> 4;

    floatx4 accM[2][2] = {}, accL[2][2] = {};
    #pragma unroll
    for (int ks = 0; ks < 4; ks++) {
        bf16x8 ak[2], aq[2], bk[2];
        #pragma unroll
        for (int i = 0; i < 2; i++) {
            ak[i] = *(const bf16x8*)&Ks[wm * 32 + i * 16 + m][ks * 32 + quad * 8];
            aq[i] = *(const bf16x8*)&Qs[wm * 32 + i * 16 + m][ks * 32 + quad * 8];
            bk[i] = *(const bf16x8*)&Ks[wn * 32 + i * 16 + m][ks * 32 + quad * 8];
        }
        #pragma unroll
        for (int i = 0; i < 2; i++)
            #pragma unroll
            for (int j = 0; j < 2; j++) {
                accM[i][j] = __builtin_amdgcn_mfma_f32_16x16x32_bf16(ak[i], bk[j], accM[i][j], 0, 0, 0);
                accL[i][j] = __builtin_amdgcn_mfma_f32_16x16x32_bf16(aq[i], bk[j], accL[i][j], 0, 0, 0);
            }
    }
    #pragma unroll
    for (int i = 0; i < 2; i++)
        #pragma unroll
        for (int j = 0; j < 2; j++)
            #pragma unroll
            for (int r = 0; r < 4; r++) {
                int row = wm * 32 + i * 16 + quad * 4 + r;
                int col = wn * 32 + j * 16 + m;
                Af[row][col] = (col < row) ? betas[row] * accM[i][j][r] : 0.f;
                Lb[((size_t)gc * CK + row) * CK + col] =
                    (col <= row) ? (__bf16)accL[i][j][r] : (__bf16)0.f;
            }
    __syncthreads();

    const int col = t;
    const float* rbase = (col < DD) ? kbase : vbase;
    const int cm = col & (DD - 1);
    const float scale = (col < DD) ? rsqrtf(fmaxf(sumsq[b * 128 + cm], 1e-24f)) : 1.f;
    float cur = rbase[cm] * scale;
    for (int tt = 0; tt < CK; tt++) {
        float nxt = (tt < CK - 1) ? rbase[(size_t)(tt + 1) * DD + cm] * scale : 0.f;
        float acc = betas[tt] * cur;
        for (int s = 0; s < tt; s++)
            acc -= Af[tt][s] * WU[s][col];
        WU[tt][col] = acc;
        __bf16 bv = (__bf16)acc;
        if (col < DD) Wb[((size_t)gc * CK + tt) * DD + col] = bv;
        else          Ub[((size_t)gc * CK + tt) * DD + cm]  = bv;
        cur = nxt;
    }
}

// --------- PRE2 (parallel): H, G, P, Y from W, U0, L, K, Q
__global__ __launch_bounds__(256) void chunk_pre2(
    const float* __restrict__ kTg, const float* __restrict__ qTg,
    const float* __restrict__ sumsq,
    const __bf16* __restrict__ Lb, const __bf16* __restrict__ Wb, const __bf16* __restrict__ Ub,
    __bf16* __restrict__ HTb, __bf16* __restrict__ Gb,
    __bf16* __restrict__ Pb, __bf16* __restrict__ Yb)
{
    const int c = blockIdx.x, b = blockIdx.y;
    const int gc = b * NCHUNK + c;
    const int t0 = c * CK;

    __shared__ __bf16 Kt[DD][72];
    __shared__ __bf16 Wt[DD][72];
    __shared__ __bf16 Ut[DD][72];
    __shared__ __bf16 Ls[CK][72];

    const int t = threadIdx.x;
    #pragma unroll
    for (int p = 0; p < 8; p++) {
        int idx = t + p * 256;
        int tt = idx >> 5, j4 = idx & 31;
        float4 sk = *(const float4*)&sumsq[b * 128 + j4 * 4];
        float4 f = *(const float4*)&kTg[((size_t)b * LL + t0 + tt) * DD + j4 * 4];
        Kt[j4 * 4 + 0][tt] = (__bf16)(f.x * rsqrtf(fmaxf(sk.x, 1e-24f)));
        Kt[j4 * 4 + 1][tt] = (__bf16)(f.y * rsqrtf(fmaxf(sk.y, 1e-24f)));
        Kt[j4 * 4 + 2][tt] = (__bf16)(f.z * rsqrtf(fmaxf(sk.z, 1e-24f)));
        Kt[j4 * 4 + 3][tt] = (__bf16)(f.w * rsqrtf(fmaxf(sk.w, 1e-24f)));
        bf16x4 w = *(const bf16x4*)&Wb[((size_t)gc * CK + tt) * DD + j4 * 4];
        bf16x4 u = *(const bf16x4*)&Ub[((size_t)gc * CK + tt) * DD + j4 * 4];
        #pragma unroll
        for (int e = 0; e < 4; e++) { Wt[j4 * 4 + e][tt] = w[e]; Ut[j4 * 4 + e][tt] = u[e]; }
    }
    #pragma unroll
    for (int p = 0; p < 4; p++) {
        int idx = t + p * 256;
        int tt = idx >> 4, s4 = idx & 15;
        *(bf16x4*)&Ls[tt][s4 * 4] = *(const bf16x4*)&Lb[((size_t)gc * CK + tt) * CK + s4 * 4];
    }
    __syncthreads();

    const int wave = t >> 6, lane = t & 63;
    const int wm = wave & 1, wn = wave >> 1;
    const int m = lane & 15, quad = lane >> 4;

    // H^T (negated): C[j][i] = -sum_t Kt[j][t] Wt[i][t]
    {
        floatx4 acc[4][4] = {};
        #pragma unroll
        for (int ks = 0; ks < 2; ks++) {
            bf16x8 a[4], bb[4];
            #pragma unroll
            for (int i = 0; i < 4; i++) {
                a[i]  = *(const bf16x8*)&Kt[wm * 64 + i * 16 + m][ks * 32 + quad * 8];
                bb[i] = *(const bf16x8*)&Wt[wn * 64 + i * 16 + m][ks * 32 + quad * 8];
            }
            #pragma unroll
            for (int i = 0; i < 4; i++)
                #pragma unroll
                for (int j = 0; j < 4; j++)
                    acc[i][j] = __builtin_amdgcn_mfma_f32_16x16x32_bf16(a[i], bb[j], acc[i][j], 0, 0, 0);
        }
        #pragma unroll
        for (int i = 0; i < 4; i++)
            #pragma unroll
            for (int j = 0; j < 4; j++)
                #pragma unroll
                for (int r = 0; r < 4; r++) {
                    int row = wm * 64 + i * 16 + quad * 4 + r;
                    int cx  = wn * 64 + j * 16 + m;
                    HTb[((size_t)gc * DD + row) * DD + cx] = (__bf16)(-acc[i][j][r]);
                }
    }
    // G: C[i][j] = sum_t Ut[i][t] Kt[j][t]
    {
        floatx4 acc[4][4] = {};
        #pragma unroll
        for (int ks = 0; ks < 2; ks++) {
            bf16x8 a[4], bb[4];
            #pragma unroll
            for (int i = 0; i < 4; i++) {
                a[i]  = *(const bf16x8*)&Ut[wm * 64 + i * 16 + m][ks * 32 + quad * 8];
                bb[i] = *(const bf16x8*)&Kt[wn * 64 + i * 16 + m][ks * 32 + quad * 8];
            }
            #pragma unroll
            for (int i = 0; i < 4; i++)
                #pragma unroll
                for (int j = 0; j < 4; j++)
                    acc[i][j] = __builtin_amdgcn_mfma_f32_16x16x32_bf16(a[i], bb[j], acc[i][j], 0, 0, 0);
        }
        #pragma unroll
        for (int i = 0; i < 4; i++)
            #pragma unroll
            for (int j = 0; j < 4; j++)
                #pragma unroll
                for (int r = 0; r < 4; r++) {
                    int row = wm * 64 + i * 16 + quad * 4 + r;
                    int cx  = wn * 64 + j * 16 + m;
                    Gb[((size_t)gc * DD + row) * DD + cx] = (__bf16)acc[i][j][r];
                }
    }
    // P = Q - L W
    {
        floatx4 acc[2][4] = {};
        #pragma unroll
        for (int ks = 0; ks < 2; ks++) {
            bf16x8 a[2], bb[4];
            #pragma unroll
            for (int i = 0; i < 2; i++)
                a[i] = *(const bf16x8*)&Ls[wm * 32 + i * 16 + m][ks * 32 + quad * 8];
            #pragma unroll
            for (int j = 0; j < 4; j++)
                bb[j] = *(const bf16x8*)&Wt[wn * 64 + j * 16 + m][ks * 32 + quad * 8];
            #pragma unroll
            for (int i = 0; i < 2; i++)
                #pragma unroll
                for (int j = 0; j < 4; j++)
                    acc[i][j] = __builtin_amdgcn_mfma_f32_16x16x32_bf16(a[i], bb[j], acc[i][j], 0, 0, 0);
        }
        #pragma unroll
        for (int i = 0; i < 2; i++)
            #pragma unroll
            for (int j = 0; j < 4; j++)
                #pragma unroll
                for (int r = 0; r < 4; r++) {
                    int row = wm * 32 + i * 16 + quad * 4 + r;
                    int cx  = wn * 64 + j * 16 + m;
                    float iq = rsqrtf(fmaxf(sumsq[512 + b * 128 + cx], 1e-24f));
                    float qv = qTg[((size_t)b * LL + t0 + row) * DD + cx] * iq;
                    Pb[((size_t)gc * CK + row) * DD + cx] = (__bf16)(qv - acc[i][j][r]);
                }
    }
    // Y = L U0
    {
        floatx4 acc[2][4] = {};
        #pragma unroll
        for (int ks = 0; ks < 2; ks++) {
            bf16x8 a[2], bb[4];
            #pragma unroll
            for (int i = 0; i < 2; i++)
                a[i] = *(const bf16x8*)&Ls[wm * 32 + i * 16 + m][ks * 32 + quad * 8];
            #pragma unroll
            for (int j = 0; j < 4; j++)
                bb[j] = *(const bf16x8*)&Ut[wn * 64 + j * 16 + m][ks * 32 + quad * 8];
            #pragma unroll
            for (int i = 0; i < 2; i++)
                #pragma unroll
                for (int j = 0; j < 4; j++)
                    acc[i][j] = __builtin_amdgcn_mfma_f32_16x16x32_bf16(a[i], bb[j], acc[i][j], 0, 0, 0);
        }
        #pragma unroll
        for (int i = 0; i < 2; i++)
            #pragma unroll
            for (int j = 0; j < 4; j++)
                #pragma unroll
                for (int r = 0; r < 4; r++) {
                    int row = wm * 32 + i * 16 + quad * 4 + r;
                    int cx  = wn * 64 + j * 16 + m;
                    Yb[((size_t)gc * CK + row) * DD + cx] = (__bf16)acc[i][j][r];
                }
    }
}

// --------- serial chain: S <- S (I - H) + G; 16 blocks (4b x 4 rowgroups of 32 rows)
// H fragments double-buffered in REGISTERS (direct global->VGPR, prefetched 1 chunk
// ahead); G prefetched in registers; only S round-trips LDS (layout shuffle for MFMA).
__global__ __launch_bounds__(256) void delta_serial(
    const __bf16* __restrict__ HTb, const __bf16* __restrict__ Gb, __bf16* __restrict__ S0b)
{
    const int b  = blockIdx.x >> 2;
    const int rg = blockIdx.x & 3;          // row group: rows rg*32 .. rg*32+31
    __shared__ __bf16 Ss[32][136];
    const int t = threadIdx.x;
    const int wj = t >> 6;                  // wave = output col group (32 cols)
    const int lane = t & 63;
    const int m = lane & 15, quad = lane >> 4;

    floatx4 acc[2][2] = {};                 // rows i*16+quad*4+r (local), cols wj*32+j*16+m
    bf16x8 hA[8], hB[8];                    // H fragments, double-buffered: [ks*2+j]
    __bf16 gpre[16];

    // prefetch chunk 0 H-fragments + G
    {
        const size_t g0 = (size_t)(b * NCHUNK) * DD * DD;
        #pragma unroll
        for (int ks = 0; ks < 4; ks++)
            #pragma unroll
            for (int j = 0; j < 2; j++) {
                int hr = wj * 32 + j * 16 + m;                 // fragment row = output col
                hA[ks * 2 + j] = *(const bf16x8*)&HTb[g0 + (size_t)hr * DD + ks * 32 + quad * 8];
            }
        #pragma unroll
        for (int i = 0; i < 2; i++)
            #pragma unroll
            for (int j = 0; j < 2; j++)
                #pragma unroll
                for (int r = 0; r < 4; r++) {
                    int row = rg * 32 + i * 16 + quad * 4 + r;
                    int cx  = wj * 32 + j * 16 + m;
                    gpre[(i * 2 + j) * 4 + r] = Gb[g0 + (size_t)row * DD + cx];
                }
    }

    for (int c = 0; c < NCHUNK; c++) {
        const size_t gco = (size_t)(b * NCHUNK + c) * DD * DD;
        const size_t gcn = gco + (size_t)DD * DD;
        const bool even = (c & 1) == 0;
        // issue next-chunk H prefetch into the other buffer
        if (c + 1 < NCHUNK) {
            #pragma unroll
            for (int ks = 0; ks < 4; ks++)
                #pragma unroll
                for (int j = 0; j < 2; j++) {
                    int hr = wj * 32 + j * 16 + m;
                    bf16x8 v = *(const bf16x8*)&HTb[gcn + (size_t)hr * DD + ks * 32 + quad * 8];
                    if (even) hB[ks * 2 + j] = v; else hA[ks * 2 + j] = v;
                }
        }
        // Ss = bf16(S)
        #pragma unroll
        for (int i = 0; i < 2; i++)
            #pragma unroll
            for (int j = 0; j < 2; j++) {
                int row = i * 16 + quad * 4;
                int cx  = wj * 32 + j * 16 + m;
                #pragma unroll
                for (int r = 0; r < 4; r++)
                    Ss[row + r][cx] = (__bf16)acc[i][j][r];
            }
        __syncthreads();
        // snapshot S0 (this block's 32 rows)
        #pragma unroll
        for (int p = 0; p < 4; p++) {
            int idx = t + p * 256;
            int row = idx >> 5, c4 = idx & 31;
            *(bf16x4*)&S0b[gco + (size_t)(rg * 32 + row) * DD + c4 * 4] =
                *(const bf16x4*)&Ss[row][c4 * 4];
        }
        // acc += G
        #pragma unroll
        for (int i = 0; i < 2; i++)
            #pragma unroll
            for (int j = 0; j < 2; j++)
                #pragma unroll
                for (int r = 0; r < 4; r++)
                    acc[i][j][r] += (float)gpre[(i * 2 + j) * 4 + r];
        // issue next-chunk G prefetch
        if (c + 1 < NCHUNK) {
            #pragma unroll
            for (int i = 0; i < 2; i++)
                #pragma unroll
                for (int j = 0; j < 2; j++)
                    #pragma unroll
                    for (int r = 0; r < 4; r++) {
                        int row = rg * 32 + i * 16 + quad * 4 + r;
                        int cx  = wj * 32 + j * 16 + m;
                        gpre[(i * 2 + j) * 4 + r] = Gb[gcn + (size_t)row * DD + cx];
                    }
        }
        // MFMA: acc += Ss * (-H)
        #pragma unroll
        for (int ks = 0; ks < 4; ks++) {
            bf16x8 a[2];
            #pragma unroll
            for (int i = 0; i < 2; i++)
                a[i] = *(const bf16x8*)&Ss[i * 16 + m][ks * 32 + quad * 8];
            #pragma unroll
            for (int i = 0; i < 2; i++)
                #pragma unroll
                for (int j = 0; j < 2; j++) {
                    bf16x8 hb = even ? hA[ks * 2 + j] : hB[ks * 2 + j];
                    acc[i][j] = __builtin_amdgcn_mfma_f32_16x16x32_bf16(a[i], hb, acc[i][j], 0, 0, 0);
                }
        }
        __syncthreads();
    }
}

// --------- O = P S0^T + Y, fused RMSNorm over D -> nmb (bf16, (B,L,D))
__global__ __launch_bounds__(256) void chunk_out(
    const __bf16* __restrict__ Pb, const __bf16* __restrict__ Yb, const __bf16* __restrict__ S0b,
    const float* __restrict__ rms_w, __bf16* __restrict__ nmb)
{
    const int c = blockIdx.x, b = blockIdx.y;
    const int gc = b * NCHUNK + c;
    const int t0 = c * CK;
    __shared__ __bf16 Ps[CK][136];
    __shared__ __bf16 Sb[DD][136];
    __shared__ float red[2][2][2][4][4];   // [wn][wm][i][quad][r]
    const int t = threadIdx.x;
    #pragma unroll
    for (int p = 0; p < 8; p++) {
        int idx = t + p * 256;
        int row = idx >> 5, c4 = idx & 31;
        *(bf16x4*)&Ps[row][c4 * 4] = *(const bf16x4*)&Pb[((size_t)gc * CK + row) * DD + c4 * 4];
    }
    #pragma unroll
    for (int p = 0; p < 16; p++) {
        int idx = t + p * 256;
        int row = idx >> 5, c4 = idx & 31;
        *(bf16x4*)&Sb[row][c4 * 4] = *(const bf16x4*)&S0b[((size_t)gc * DD + row) * DD + c4 * 4];
    }
    __syncthreads();

    const int wave = t >> 6, lane = t & 63;
    const int wm = wave & 1, wn = wave >> 1;
    const int m = lane & 15, quad = lane >> 4;

    floatx4 acc[2][4] = {};
    #pragma unroll
    for (int ks = 0; ks < 4; ks++) {
        bf16x8 a[2], bb[4];
        #pragma unroll
        for (int i = 0; i < 2; i++)
            a[i] = *(const bf16x8*)&Ps[wm * 32 + i * 16 + m][ks * 32 + quad * 8];
        #pragma unroll
        for (int j = 0; j < 4; j++)
            bb[j] = *(const bf16x8*)&Sb[wn * 64 + j * 16 + m][ks * 32 + quad * 8];
        #pragma unroll
        for (int i = 0; i < 2; i++)
            #pragma unroll
            for (int j = 0; j < 4; j++)
                acc[i][j] = __builtin_amdgcn_mfma_f32_16x16x32_bf16(a[i], bb[j], acc[i][j], 0, 0, 0);
    }

    float v[2][4][4];
    float ss[2][4] = {};
    #pragma unroll
    for (int i = 0; i < 2; i++)
        #pragma unroll
        for (int j = 0; j < 4; j++)
            #pragma unroll
            for (int r = 0; r < 4; r++) {
                int row = wm * 32 + i * 16 + quad * 4 + r;
                int cx  = wn * 64 + j * 16 + m;
                float y = (float)Yb[((size_t)gc * CK + row) * DD + cx];
                float vv = acc[i][j][r] + y;
                v[i][j][r] = vv;
                ss[i][r] = fmaf(vv, vv, ss[i][r]);
            }
    #pragma unroll
    for (int mask = 1; mask < 16; mask <<= 1)
        #pragma unroll
        for (int i = 0; i < 2; i++)
            #pragma unroll
            for (int r = 0; r < 4; r++)
                ss[i][r] += __shfl_xor(ss[i][r], mask, 64);
    if (m == 0)
        #pragma unroll
        for (int i = 0; i < 2; i++)
            #pragma unroll
            for (int r = 0; r < 4; r++)
                red[wn][wm][i][quad][r] = ss[i][r];
    __syncthreads();
    #pragma unroll
    for (int i = 0; i < 2; i++)
        #pragma unroll
        for (int r = 0; r < 4; r++) {
            float tot = red[0][wm][i][quad][r] + red[1][wm][i][quad][r];
            float inv = rsqrtf(tot * (1.f / 128.f) + 1.1920928955078125e-07f);
            int row = wm * 32 + i * 16 + quad * 4 + r;
            #pragma unroll
            for (int j = 0; j < 4; j++) {
                int cx = wn * 64 + j * 16 + m;
                nmb[((size_t)b * LL + t0 + row) * DD + cx] = (__bf16)(v[i][j][r] * inv * rms_w[cx]);
            }
        }
}

extern "C" void kernel_launch(void* const* d_in, const int* in_sizes, int n_in,
                              void* d_out, int out_size, void* d_ws, size_t ws_size,
                              hipStream_t stream) {
    const float* x    = (const float*)d_in[0];
    const float* kpw  = (const float*)d_in[1];
    const float* kpb  = (const float*)d_in[2];
    const float* qpw  = (const float*)d_in[3];
    const float* qpb  = (const float*)d_in[4];
    const float* vpw  = (const float*)d_in[5];
    const float* vpb  = (const float*)d_in[6];
    const float* kcw  = (const float*)d_in[7];
    const float* kcb  = (const float*)d_in[8];
    const float* qcw  = (const float*)d_in[9];
    const float* qcb  = (const float*)d_in[10];
    const float* vcw  = (const float*)d_in[11];
    const float* vcb  = (const float*)d_in[12];
    const float* bw   = (const float*)d_in[13];
    const float* bb   = (const float*)d_in[14];
    const float* rw   = (const float*)d_in[15];
    const float* ow   = (const float*)d_in[16];
    const float* obi  = (const float*)d_in[17];
    float* out = (float*)d_out;

    float* ws = (float*)d_ws;
    const size_t NB1 = (size_t)BB * DD * LL;   // 1,048,576 floats = 4 MB
    // slot map:
    //  0: k0 -> Lb+Wb(bf16) -> S0b(bf16)   1: q0 -> Ub(bf16)   2: v0 -> HTb(bf16)
    //  3: kcT   4: qcT   5: vcT -> Gb(bf16)
    //  6: nmb (bf16 normed, 2MB)   7: Pb+Yb(bf16)   8: beta + sumsq + wpk
    float* k0  = ws;
    float* q0  = ws + NB1;
    float* v0  = ws + 2 * NB1;
    float* kcT = ws + 3 * NB1;
    float* qcT = ws + 4 * NB1;
    float* vcT = ws + 5 * NB1;
    float* beta  = ws + 8 * NB1;
    float* sumsq = beta + (size_t)BB * LL;
    __bf16* wpk  = (__bf16*)(sumsq + 1024);

    __bf16* Lb  = (__bf16*)k0;
    __bf16* Wb  = Lb + (size_t)128 * 64 * 64;
    __bf16* Ub  = (__bf16*)q0;
    __bf16* HTb = (__bf16*)v0;
    __bf16* Gb  = (__bf16*)vcT;
    __bf16* Pb  = (__bf16*)(ws + 7 * NB1);
    __bf16* Yb  = Pb + (size_t)128 * 64 * 128;
    __bf16* S0b = (__bf16*)k0;
    __bf16* nmb = (__bf16*)(ws + 6 * NB1);

    proj_gemm_mfma<<<dim3(64, 3), 256, 0, stream>>>(x, kpw, qpw, vpw, kpb, qpb, vpb, k0, q0, v0);
    beta_kernel<<<dim3(BB * LL), 256, 0, stream>>>(x, bw, bb, beta);
    wpack_zero<<<dim3(144), 256, 0, stream>>>(kcw, qcw, vcw, wpk, sumsq);
    conv_mfma<<<dim3(32, 12), 256, 0, stream>>>(k0, q0, v0, wpk, kcb, qcb, vcb, kcT, qcT, vcT, sumsq);
    chunk_pre1<<<dim3(NCHUNK, BB), 256, 0, stream>>>(kcT, qcT, vcT, beta, sumsq, Lb, Wb, Ub);
    chunk_pre2<<<dim3(NCHUNK, BB), 256, 0, stream>>>(kcT, qcT, sumsq, Lb, Wb, Ub, HTb, Gb, Pb, Yb);
    delta_serial<<<dim3(BB * 4), 256, 0, stream>>>(HTb, Gb, S0b);
    chunk_out<<<dim3(NCHUNK, BB), 256, 0, stream>>>(Pb, Yb, S0b, rw, nmb);
    out_gemm_mfma<<<dim3(64, 16), 256, 0, stream>>>(nmb, ow, obi, out);
}

// Round 5
// 349.764 us; speedup vs baseline: 1.9068x; 1.0424x over previous
//
#include <hip/hip_runtime.h>
#include <math.h>

#define LL 2048
#define DD 128
#define BB 4
#define CK 64
#define NCHUNK 32

typedef __bf16 bf16x8 __attribute__((ext_vector_type(8)));
typedef __bf16 bf16x4 __attribute__((ext_vector_type(4)));
typedef float floatx4 __attribute__((ext_vector_type(4)));

// async global->LDS, 16B per lane. LDS dest must be wave-uniform base + lane*16.
__device__ __forceinline__ void gload_lds16(const void* g, void* l) {
    __builtin_amdgcn_global_load_lds(
        (const __attribute__((address_space(1))) unsigned int*)g,
        (__attribute__((address_space(3))) unsigned int*)l, 16, 0, 0);
}

// ================= proj GEMM (bf16 MFMA, global_load_lds, dbuf) =================
// C(8192x128 x3) = xb(8192x2048 bf16) @ wcat[arr]^T + b.  Tile 64x128, K-step 64.
__global__ __launch_bounds__(256) void proj_gemm_mfma(
    const __bf16* __restrict__ xb, const __bf16* __restrict__ wcat,
    const float* __restrict__ kb, const float* __restrict__ qb, const float* __restrict__ vb,
    float* __restrict__ k0, float* __restrict__ q0, float* __restrict__ v0)
{
    const int arr = blockIdx.y;
    const float* __restrict__ bia = arr == 0 ? kb : (arr == 1 ? qb : vb);
    float* __restrict__ out       = arr == 0 ? k0 : (arr == 1 ? q0 : v0);
    const __bf16* __restrict__ w  = wcat + (size_t)arr * DD * 2048;

    __shared__ __bf16 As[2][64 * 64];     // 8 KB each
    __shared__ __bf16 Bs[2][128 * 64];    // 16 KB each

    const int t = threadIdx.x;
    const int wave = t >> 6, lane = t & 63;
    const int wm = wave & 1, wn = wave >> 1;
    const int m = lane & 15, quad = lane >> 4;
    const int row0 = blockIdx.x * 64;

    floatx4 acc[2][4] = {};

    // prologue: stage k-tile 0 into buf 0
    #pragma unroll
    for (int c = 0; c < 2; c++) {
        int f = t + c * 256;
        gload_lds16(&xb[(size_t)(row0 + (f >> 3)) * 2048 + (f & 7) * 8], &As[0][f * 8]);
    }
    #pragma unroll
    for (int c = 0; c < 4; c++) {
        int f = t + c * 256;
        gload_lds16(&w[(size_t)(f >> 3) * 2048 + (f & 7) * 8], &Bs[0][f * 8]);
    }
    __syncthreads();   // drains vmcnt(0) before barrier (compiler-enforced)

    for (int kt = 0; kt < 32; kt++) {
        const int cur = kt & 1, nxt = cur ^ 1;
        if (kt + 1 < 32) {
            const int k0i = (kt + 1) * 64;
            #pragma unroll
            for (int c = 0; c < 2; c++) {
                int f = t + c * 256;
                gload_lds16(&xb[(size_t)(row0 + (f >> 3)) * 2048 + k0i + (f & 7) * 8], &As[nxt][f * 8]);
            }
            #pragma unroll
            for (int c = 0; c < 4; c++) {
                int f = t + c * 256;
                gload_lds16(&w[(size_t)(f >> 3) * 2048 + k0i + (f & 7) * 8], &Bs[nxt][f * 8]);
            }
        }
        #pragma unroll
        for (int ks = 0; ks < 2; ks++) {
            bf16x8 af[2], bfr[4];
            #pragma unroll
            for (int i = 0; i < 2; i++)
                af[i] = *(const bf16x8*)&As[cur][(wm * 32 + i * 16 + m) * 64 + ks * 32 + quad * 8];
            #pragma unroll
            for (int j = 0; j < 4; j++)
                bfr[j] = *(const bf16x8*)&Bs[cur][(wn * 64 + j * 16 + m) * 64 + ks * 32 + quad * 8];
            #pragma unroll
            for (int i = 0; i < 2; i++)
                #pragma unroll
                for (int j = 0; j < 4; j++)
                    acc[i][j] = __builtin_amdgcn_mfma_f32_16x16x32_bf16(af[i], bfr[j], acc[i][j], 0, 0, 0);
        }
        __syncthreads();
    }
    #pragma unroll
    for (int i = 0; i < 2; i++)
        #pragma unroll
        for (int j = 0; j < 4; j++) {
            int col = wn * 64 + j * 16 + m;
            float bv = bia[col];
            #pragma unroll
            for (int r = 0; r < 4; r++)
                out[(size_t)(row0 + wm * 32 + i * 16 + quad * 4 + r) * 128 + col] = acc[i][j][r] + bv;
        }
}

// ================= out GEMM: out(8192x2048) = nmb(8192x128 bf16) @ owb^T + ob ============
// K=128 staged whole (no K-loop), global_load_lds, 128x128 tile.
__global__ __launch_bounds__(256) void out_gemm_mfma(
    const __bf16* __restrict__ A, const __bf16* __restrict__ wb,
    const float* __restrict__ bias, float* __restrict__ out)
{
    __shared__ __bf16 As[128 * 128];
    __shared__ __bf16 Bs[128 * 128];

    const int t = threadIdx.x;
    const int wave = t >> 6, lane = t & 63;
    const int wm = wave & 1, wn = wave >> 1;
    const int m = lane & 15, quad = lane >> 4;
    const int row0 = blockIdx.x * 128;
    const int col0 = blockIdx.y * 128;

    #pragma unroll
    for (int c = 0; c < 8; c++) {
        int f = t + c * 256;
        gload_lds16(&A[(size_t)(row0 + (f >> 4)) * 128 + (f & 15) * 8], &As[f * 8]);
        gload_lds16(&wb[(size_t)(col0 + (f >> 4)) * 128 + (f & 15) * 8], &Bs[f * 8]);
    }
    __syncthreads();

    floatx4 acc[4][4] = {};
    #pragma unroll
    for (int ks = 0; ks < 4; ks++) {
        bf16x8 af[4], bfr[4];
        #pragma unroll
        for (int i = 0; i < 4; i++)
            af[i] = *(const bf16x8*)&As[(wm * 64 + i * 16 + m) * 128 + ks * 32 + quad * 8];
        #pragma unroll
        for (int j = 0; j < 4; j++)
            bfr[j] = *(const bf16x8*)&Bs[(wn * 64 + j * 16 + m) * 128 + ks * 32 + quad * 8];
        #pragma unroll
        for (int i = 0; i < 4; i++)
            #pragma unroll
            for (int j = 0; j < 4; j++)
                acc[i][j] = __builtin_amdgcn_mfma_f32_16x16x32_bf16(af[i], bfr[j], acc[i][j], 0, 0, 0);
    }
    #pragma unroll
    for (int i = 0; i < 4; i++) {
        int grow = row0 + wm * 64 + i * 16 + quad * 4;
        #pragma unroll
        for (int j = 0; j < 4; j++) {
            int col = col0 + wn * 64 + j * 16 + m;
            float bv = bias[col];
            #pragma unroll
            for (int r = 0; r < 4; r++)
                out[(size_t)(grow + r) * 2048 + col] = acc[i][j][r] + bv;
        }
    }
}

// ================= beta = sigmoid(x @ beta_w^T + beta_b); also emit xb = bf16(x) =========
__global__ __launch_bounds__(256) void beta_kernel(
    const float* __restrict__ x, const float* __restrict__ bw,
    const float* __restrict__ bb, float* __restrict__ beta, __bf16* __restrict__ xb)
{
    const int row = blockIdx.x;
    const float* xr = x + (size_t)row * 2048;
    __bf16* xbr = xb + (size_t)row * 2048;
    const int t = threadIdx.x;
    float s = 0.f;
    #pragma unroll
    for (int jj = 0; jj < 2; jj++) {
        int j = (t + jj * 256) * 4;
        float4 f = *(const float4*)&xr[j];
        float4 wv = *(const float4*)&bw[j];
        s = fmaf(f.x, wv.x, s); s = fmaf(f.y, wv.y, s);
        s = fmaf(f.z, wv.z, s); s = fmaf(f.w, wv.w, s);
        bf16x4 v; v[0] = (__bf16)f.x; v[1] = (__bf16)f.y; v[2] = (__bf16)f.z; v[3] = (__bf16)f.w;
        *(bf16x4*)&xbr[j] = v;
    }
    #pragma unroll
    for (int m = 1; m < 64; m <<= 1) s += __shfl_xor(s, m, 64);
    __shared__ float red[4];
    if ((t & 63) == 0) red[t >> 6] = s;
    __syncthreads();
    if (t == 0) {
        float tot = red[0] + red[1] + red[2] + red[3] + bb[0];
        beta[row] = 1.f / (1.f + expf(-tot));
    }
}

// ================= pack weights to bf16: conv wpk, proj wcat, out owb; zero sumsq =========
__global__ __launch_bounds__(256) void wpack_zero(
    const float* __restrict__ kw, const float* __restrict__ qw, const float* __restrict__ vw,
    const float* __restrict__ kpw, const float* __restrict__ qpw, const float* __restrict__ vpw,
    const float* __restrict__ ow,
    __bf16* __restrict__ wpk, __bf16* __restrict__ wcat, __bf16* __restrict__ owb,
    float* __restrict__ sumsq)
{
    const int t = threadIdx.x;
    const int bx = blockIdx.x;
    if (bx == 0) {
        #pragma unroll
        for (int e = 0; e < 4; e++) sumsq[t * 4 + e] = 0.f;
    }
    if (bx < 144) {
        int base = (bx * 256 + t) * 4;                    // over 3*3*128*128 = 147456
        int arr = base / 49152, rem = base % 49152;
        const float* __restrict__ w = arr == 0 ? kw : arr == 1 ? qw : vw;
        int dt = rem / 16384, rem2 = rem % 16384;
        int o = rem2 >> 7, i0 = rem2 & 127;
        #pragma unroll
        for (int e = 0; e < 4; e++) {
            int i = i0 + e;
            wpk[base + e] = (__bf16)w[(size_t)((o * 128 + i) * 3 + dt) * 3 + 1];
        }
    } else if (bx < 912) {
        int e = (bx - 144) * 1024 + t * 4;                // over 3*128*2048 = 786432
        int arr = e >> 18, rem = e & 262143;
        const float* __restrict__ w = arr == 0 ? kpw : arr == 1 ? qpw : vpw;
        float4 f = *(const float4*)&w[rem];
        bf16x4 v; v[0] = (__bf16)f.x; v[1] = (__bf16)f.y; v[2] = (__bf16)f.z; v[3] = (__bf16)f.w;
        *(bf16x4*)&wcat[(size_t)arr * 262144 + rem] = v;
    } else {
        int e = (bx - 912) * 1024 + t * 4;                // over 2048*128 = 262144
        float4 f = *(const float4*)&ow[e];
        bf16x4 v; v[0] = (__bf16)f.x; v[1] = (__bf16)f.y; v[2] = (__bf16)f.z; v[3] = (__bf16)f.w;
        *(bf16x4*)&owb[e] = v;
    }
}

// ================= conv as MFMA GEMM + bias + SiLU + fused l2norm partials ================
__global__ __launch_bounds__(256) void conv_mfma(
    const float* __restrict__ k0, const float* __restrict__ q0, const float* __restrict__ v0,
    const __bf16* __restrict__ wpk,
    const float* __restrict__ kb, const float* __restrict__ qb, const float* __restrict__ vb,
    float* __restrict__ kcT, float* __restrict__ qcT, float* __restrict__ vcT,
    float* __restrict__ sumsq)
{
    const int sb  = blockIdx.x;
    const int arr = blockIdx.y >> 2;
    const int b   = blockIdx.y & 3;
    const float* __restrict__ in = (arr == 0 ? k0 : arr == 1 ? q0 : v0) + (size_t)b * DD * LL;
    const float* __restrict__ bi = arr == 0 ? kb : arr == 1 ? qb : vb;
    float* __restrict__ out      = (arr == 0 ? kcT : arr == 1 ? qcT : vcT) + (size_t)b * LL * DD;
    const __bf16* __restrict__ wp = wpk + (size_t)arr * 3 * DD * DD;

    __shared__ __bf16 Xs[66 * 136];
    __shared__ float colsum[128];

    const int t = threadIdx.x;
    const int s0 = sb * 64;
    if (t < 128) colsum[t] = 0.f;

    #pragma unroll
    for (int p = 0; p < 32; p++) {
        int idx = t + p * 256;
        int sr = idx & 63, i = idx >> 6;
        float v = in[(size_t)i * LL + s0 + sr];
        int row = sr + 1;
        Xs[row * 136 + (i ^ ((row & 7) << 4))] = (__bf16)v;
    }
    {
        int e = t >> 7, i = t & 127;
        int row = e * 65;
        int s = s0 - 1 + e * 65;
        float v = (s >= 0 && s < LL) ? in[(size_t)i * LL + s] : 0.f;
        Xs[row * 136 + (i ^ ((row & 7) << 4))] = (__bf16)v;
    }
    __syncthreads();

    const int wave = t >> 6, lane = t & 63;
    const int wm = wave & 1, wn = wave >> 1;
    const int m = lane & 15, quad = lane >> 4;

    floatx4 acc[2][4] = {};
    #pragma unroll
    for (int dt = 0; dt < 3; dt++) {
        bf16x8 bfr[4][4];
        #pragma unroll
        for (int ks = 0; ks < 4; ks++)
            #pragma unroll
            for (int j = 0; j < 4; j++)
                bfr[ks][j] = *(const bf16x8*)&wp[(size_t)(dt * DD + wn * 64 + j * 16 + m) * DD + ks * 32 + quad * 8];
        #pragma unroll
        for (int ks = 0; ks < 4; ks++) {
            bf16x8 af[2];
            #pragma unroll
            for (int ii = 0; ii < 2; ii++) {
                int row = wm * 32 + ii * 16 + m + dt;
                af[ii] = *(const bf16x8*)&Xs[row * 136 + ((ks * 32 + quad * 8) ^ ((row & 7) << 4))];
            }
            #pragma unroll
            for (int ii = 0; ii < 2; ii++)
                #pragma unroll
                for (int j = 0; j < 4; j++)
                    acc[ii][j] = __builtin_amdgcn_mfma_f32_16x16x32_bf16(af[ii], bfr[ks][j], acc[ii][j], 0, 0, 0);
        }
    }

    float part[4] = {0.f, 0.f, 0.f, 0.f};
    #pragma unroll
    for (int ii = 0; ii < 2; ii++)
        #pragma unroll
        for (int j = 0; j < 4; j++) {
            int col = wn * 64 + j * 16 + m;
            float bv = bi[col];
            #pragma unroll
            for (int r = 0; r < 4; r++) {
                int srow = s0 + wm * 32 + ii * 16 + quad * 4 + r;
                float v = acc[ii][j][r] + bv;
                float y = v / (1.f + expf(-v));
                out[(size_t)srow * DD + col] = y;
                part[j] = fmaf(y, y, part[j]);
            }
        }
    if (arr < 2) {
        #pragma unroll
        for (int j = 0; j < 4; j++)
            atomicAdd(&colsum[wn * 64 + j * 16 + m], part[j]);
        __syncthreads();
        if (t < 128) atomicAdd(&sumsq[arr * 512 + b * 128 + t], colsum[t]);
    }
}

// ============================================================================
// Chunked delta rule (WY / UT transform), C = 64 — see R0 derivation.
// ============================================================================

// --------- PRE1 (parallel over 128 (b,c)): A, L, and triangular solve -> W, U0
__global__ __launch_bounds__(256) void chunk_pre1(
    const float* __restrict__ kTg, const float* __restrict__ qTg, const float* __restrict__ vTg,
    const float* __restrict__ beta, const float* __restrict__ sumsq,
    __bf16* __restrict__ Lb, __bf16* __restrict__ Wb, __bf16* __restrict__ Ub)
{
    const int c = blockIdx.x, b = blockIdx.y;
    const int gc = b * NCHUNK + c;
    const int t0 = c * CK;
    const float* kbase = kTg + ((size_t)b * LL + t0) * DD;
    const float* qbase = qTg + ((size_t)b * LL + t0) * DD;
    const float* vbase = vTg + ((size_t)b * LL + t0) * DD;

    __shared__ __bf16 Ks[CK][136];
    __shared__ __bf16 Qs[CK][136];
    __shared__ float  Af[CK][65];
    __shared__ float  WU[CK][257];
    __shared__ float  betas[CK];

    const int t = threadIdx.x;
    #pragma unroll
    for (int p = 0; p < 8; p++) {
        int idx = t + p * 256;
        int r = idx >> 5, c4 = idx & 31;
        float4 sk = *(const float4*)&sumsq[b * 128 + c4 * 4];
        float4 sq = *(const float4*)&sumsq[512 + b * 128 + c4 * 4];
        float ik0 = rsqrtf(fmaxf(sk.x, 1e-24f)), ik1 = rsqrtf(fmaxf(sk.y, 1e-24f));
        float ik2 = rsqrtf(fmaxf(sk.z, 1e-24f)), ik3 = rsqrtf(fmaxf(sk.w, 1e-24f));
        float iq0 = rsqrtf(fmaxf(sq.x, 1e-24f)), iq1 = rsqrtf(fmaxf(sq.y, 1e-24f));
        float iq2 = rsqrtf(fmaxf(sq.z, 1e-24f)), iq3 = rsqrtf(fmaxf(sq.w, 1e-24f));
        float4 f = *(const float4*)&kbase[(size_t)r * DD + c4 * 4];
        bf16x4 v; v[0] = (__bf16)(f.x * ik0); v[1] = (__bf16)(f.y * ik1);
        v[2] = (__bf16)(f.z * ik2); v[3] = (__bf16)(f.w * ik3);
        *(bf16x4*)&Ks[r][c4 * 4] = v;
        float4 g = *(const float4*)&qbase[(size_t)r * DD + c4 * 4];
        bf16x4 u; u[0] = (__bf16)(g.x * iq0); u[1] = (__bf16)(g.y * iq1);
        u[2] = (__bf16)(g.z * iq2); u[3] = (__bf16)(g.w * iq3);
        *(bf16x4*)&Qs[r][c4 * 4] = u;
    }
    if (t < CK) betas[t] = beta[(size_t)b * LL + t0 + t];
    __syncthreads();

    const int wave = t >> 6, lane = t & 63;
    const int wm = wave & 1, wn = wave >> 1;
    const int m = lane & 15, quad = lane >> 4;

    floatx4 accM[2][2] = {}, accL[2][2] = {};
    #pragma unroll
    for (int ks = 0; ks < 4; ks++) {
        bf16x8 ak[2], aq[2], bk[2];
        #pragma unroll
        for (int i = 0; i < 2; i++) {
            ak[i] = *(const bf16x8*)&Ks[wm * 32 + i * 16 + m][ks * 32 + quad * 8];
            aq[i] = *(const bf16x8*)&Qs[wm * 32 + i * 16 + m][ks * 32 + quad * 8];
            bk[i] = *(const bf16x8*)&Ks[wn * 32 + i * 16 + m][ks * 32 + quad * 8];
        }
        #pragma unroll
        for (int i = 0; i < 2; i++)
            #pragma unroll
            for (int j = 0; j < 2; j++) {
                accM[i][j] = __builtin_amdgcn_mfma_f32_16x16x32_bf16(ak[i], bk[j], accM[i][j], 0, 0, 0);
                accL[i][j] = __builtin_amdgcn_mfma_f32_16x16x32_bf16(aq[i], bk[j], accL[i][j], 0, 0, 0);
            }
    }
    #pragma unroll
    for (int i = 0; i < 2; i++)
        #pragma unroll
        for (int j = 0; j < 2; j++)
            #pragma unroll
            for (int r = 0; r < 4; r++) {
                int row = wm * 32 + i * 16 + quad * 4 + r;
                int col = wn * 32 + j * 16 + m;
                Af[row][col] = (col < row) ? betas[row] * accM[i][j][r] : 0.f;
                Lb[((size_t)gc * CK + row) * CK + col] =
                    (col <= row) ? (__bf16)accL[i][j][r] : (__bf16)0.f;
            }
    __syncthreads();

    const int col = t;
    const float* rbase = (col < DD) ? kbase : vbase;
    const int cm = col & (DD - 1);
    const float scale = (col < DD) ? rsqrtf(fmaxf(sumsq[b * 128 + cm], 1e-24f)) : 1.f;
    float cur = rbase[cm] * scale;
    for (int tt = 0; tt < CK; tt++) {
        float nxt = (tt < CK - 1) ? rbase[(size_t)(tt + 1) * DD + cm] * scale : 0.f;
        float acc = betas[tt] * cur;
        for (int s = 0; s < tt; s++)
            acc -= Af[tt][s] * WU[s][col];
        WU[tt][col] = acc;
        __bf16 bv = (__bf16)acc;
        if (col < DD) Wb[((size_t)gc * CK + tt) * DD + col] = bv;
        else          Ub[((size_t)gc * CK + tt) * DD + cm]  = bv;
        cur = nxt;
    }
}

// --------- PRE2 (parallel): H, G, P, Y from W, U0, L, K, Q
__global__ __launch_bounds__(256) void chunk_pre2(
    const float* __restrict__ kTg, const float* __restrict__ qTg,
    const float* __restrict__ sumsq,
    const __bf16* __restrict__ Lb, const __bf16* __restrict__ Wb, const __bf16* __restrict__ Ub,
    __bf16* __restrict__ HTb, __bf16* __restrict__ Gb,
    __bf16* __restrict__ Pb, __bf16* __restrict__ Yb)
{
    const int c = blockIdx.x, b = blockIdx.y;
    const int gc = b * NCHUNK + c;
    const int t0 = c * CK;

    __shared__ __bf16 Kt[DD][72];
    __shared__ __bf16 Wt[DD][72];
    __shared__ __bf16 Ut[DD][72];
    __shared__ __bf16 Ls[CK][72];

    const int t = threadIdx.x;
    #pragma unroll
    for (int p = 0; p < 8; p++) {
        int idx = t + p * 256;
        int tt = idx >> 5, j4 = idx & 31;
        float4 sk = *(const float4*)&sumsq[b * 128 + j4 * 4];
        float4 f = *(const float4*)&kTg[((size_t)b * LL + t0 + tt) * DD + j4 * 4];
        Kt[j4 * 4 + 0][tt] = (__bf16)(f.x * rsqrtf(fmaxf(sk.x, 1e-24f)));
        Kt[j4 * 4 + 1][tt] = (__bf16)(f.y * rsqrtf(fmaxf(sk.y, 1e-24f)));
        Kt[j4 * 4 + 2][tt] = (__bf16)(f.z * rsqrtf(fmaxf(sk.z, 1e-24f)));
        Kt[j4 * 4 + 3][tt] = (__bf16)(f.w * rsqrtf(fmaxf(sk.w, 1e-24f)));
        bf16x4 w = *(const bf16x4*)&Wb[((size_t)gc * CK + tt) * DD + j4 * 4];
        bf16x4 u = *(const bf16x4*)&Ub[((size_t)gc * CK + tt) * DD + j4 * 4];
        #pragma unroll
        for (int e = 0; e < 4; e++) { Wt[j4 * 4 + e][tt] = w[e]; Ut[j4 * 4 + e][tt] = u[e]; }
    }
    #pragma unroll
    for (int p = 0; p < 4; p++) {
        int idx = t + p * 256;
        int tt = idx >> 4, s4 = idx & 15;
        *(bf16x4*)&Ls[tt][s4 * 4] = *(const bf16x4*)&Lb[((size_t)gc * CK + tt) * CK + s4 * 4];
    }
    __syncthreads();

    const int wave = t >> 6, lane = t & 63;
    const int wm = wave & 1, wn = wave >> 1;
    const int m = lane & 15, quad = lane >> 4;

    // H^T (negated): C[j][i] = -sum_t Kt[j][t] Wt[i][t]
    {
        floatx4 acc[4][4] = {};
        #pragma unroll
        for (int ks = 0; ks < 2; ks++) {
            bf16x8 a[4], bb[4];
            #pragma unroll
            for (int i = 0; i < 4; i++) {
                a[i]  = *(const bf16x8*)&Kt[wm * 64 + i * 16 + m][ks * 32 + quad * 8];
                bb[i] = *(const bf16x8*)&Wt[wn * 64 + i * 16 + m][ks * 32 + quad * 8];
            }
            #pragma unroll
            for (int i = 0; i < 4; i++)
                #pragma unroll
                for (int j = 0; j < 4; j++)
                    acc[i][j] = __builtin_amdgcn_mfma_f32_16x16x32_bf16(a[i], bb[j], acc[i][j], 0, 0, 0);
        }
        #pragma unroll
        for (int i = 0; i < 4; i++)
            #pragma unroll
            for (int j = 0; j < 4; j++)
                #pragma unroll
                for (int r = 0; r < 4; r++) {
                    int row = wm * 64 + i * 16 + quad * 4 + r;
                    int cx  = wn * 64 + j * 16 + m;
                    HTb[((size_t)gc * DD + row) * DD + cx] = (__bf16)(-acc[i][j][r]);
                }
    }
    // G: C[i][j] = sum_t Ut[i][t] Kt[j][t]
    {
        floatx4 acc[4][4] = {};
        #pragma unroll
        for (int ks = 0; ks < 2; ks++) {
            bf16x8 a[4], bb[4];
            #pragma unroll
            for (int i = 0; i < 4; i++) {
                a[i]  = *(const bf16x8*)&Ut[wm * 64 + i * 16 + m][ks * 32 + quad * 8];
                bb[i] = *(const bf16x8*)&Kt[wn * 64 + i * 16 + m][ks * 32 + quad * 8];
            }
            #pragma unroll
            for (int i = 0; i < 4; i++)
                #pragma unroll
                for (int j = 0; j < 4; j++)
                    acc[i][j] = __builtin_amdgcn_mfma_f32_16x16x32_bf16(a[i], bb[j], acc[i][j], 0, 0, 0);
        }
        #pragma unroll
        for (int i = 0; i < 4; i++)
            #pragma unroll
            for (int j = 0; j < 4; j++)
                #pragma unroll
                for (int r = 0; r < 4; r++) {
                    int row = wm * 64 + i * 16 + quad * 4 + r;
                    int cx  = wn * 64 + j * 16 + m;
                    Gb[((size_t)gc * DD + row) * DD + cx] = (__bf16)acc[i][j][r];
                }
    }
    // P = Q - L W
    {
        floatx4 acc[2][4] = {};
        #pragma unroll
        for (int ks = 0; ks < 2; ks++) {
            bf16x8 a[2], bb[4];
            #pragma unroll
            for (int i = 0; i < 2; i++)
                a[i] = *(const bf16x8*)&Ls[wm * 32 + i * 16 + m][ks * 32 + quad * 8];
            #pragma unroll
            for (int j = 0; j < 4; j++)
                bb[j] = *(const bf16x8*)&Wt[wn * 64 + j * 16 + m][ks * 32 + quad * 8];
            #pragma unroll
            for (int i = 0; i < 2; i++)
                #pragma unroll
                for (int j = 0; j < 4; j++)
                    acc[i][j] = __builtin_amdgcn_mfma_f32_16x16x32_bf16(a[i], bb[j], acc[i][j], 0, 0, 0);
        }
        #pragma unroll
        for (int i = 0; i < 2; i++)
            #pragma unroll
            for (int j = 0; j < 4; j++)
                #pragma unroll
                for (int r = 0; r < 4; r++) {
                    int row = wm * 32 + i * 16 + quad * 4 + r;
                    int cx  = wn * 64 + j * 16 + m;
                    float iq = rsqrtf(fmaxf(sumsq[512 + b * 128 + cx], 1e-24f));
                    float qv = qTg[((size_t)b * LL + t0 + row) * DD + cx] * iq;
                    Pb[((size_t)gc * CK + row) * DD + cx] = (__bf16)(qv - acc[i][j][r]);
                }
    }
    // Y = L U0
    {
        floatx4 acc[2][4] = {};
        #pragma unroll
        for (int ks = 0; ks < 2; ks++) {
            bf16x8 a[2], bb[4];
            #pragma unroll
            for (int i = 0; i < 2; i++)
                a[i] = *(const bf16x8*)&Ls[wm * 32 + i * 16 + m][ks * 32 + quad * 8];
            #pragma unroll
            for (int j = 0; j < 4; j++)
                bb[j] = *(const bf16x8*)&Ut[wn * 64 + j * 16 + m][ks * 32 + quad * 8];
            #pragma unroll
            for (int i = 0; i < 2; i++)
                #pragma unroll
                for (int j = 0; j < 4; j++)
                    acc[i][j] = __builtin_amdgcn_mfma_f32_16x16x32_bf16(a[i], bb[j], acc[i][j], 0, 0, 0);
        }
        #pragma unroll
        for (int i = 0; i < 2; i++)
            #pragma unroll
            for (int j = 0; j < 4; j++)
                #pragma unroll
                for (int r = 0; r < 4; r++) {
                    int row = wm * 32 + i * 16 + quad * 4 + r;
                    int cx  = wn * 64 + j * 16 + m;
                    Yb[((size_t)gc * CK + row) * DD + cx] = (__bf16)acc[i][j][r];
                }
    }
}

// --------- serial chain: S <- S (I - H) + G; 16 blocks (4b x 4 rowgroups of 32 rows)
__global__ __launch_bounds__(256) void delta_serial(
    const __bf16* __restrict__ HTb, const __bf16* __restrict__ Gb, __bf16* __restrict__ S0b)
{
    const int b  = blockIdx.x >> 2;
    const int rg = blockIdx.x & 3;
    __shared__ __bf16 Ss[32][136];
    const int t = threadIdx.x;
    const int wj = t >> 6;
    const int lane = t & 63;
    const int m = lane & 15, quad = lane >> 4;

    floatx4 acc[2][2] = {};
    bf16x8 hA[8], hB[8];
    __bf16 gpre[16];

    {
        const size_t g0 = (size_t)(b * NCHUNK) * DD * DD;
        #pragma unroll
        for (int ks = 0; ks < 4; ks++)
            #pragma unroll
            for (int j = 0; j < 2; j++) {
                int hr = wj * 32 + j * 16 + m;
                hA[ks * 2 + j] = *(const bf16x8*)&HTb[g0 + (size_t)hr * DD + ks * 32 + quad * 8];
            }
        #pragma unroll
        for (int i = 0; i < 2; i++)
            #pragma unroll
            for (int j = 0; j < 2; j++)
                #pragma unroll
                for (int r = 0; r < 4; r++) {
                    int row = rg * 32 + i * 16 + quad * 4 + r;
                    int cx  = wj * 32 + j * 16 + m;
                    gpre[(i * 2 + j) * 4 + r] = Gb[g0 + (size_t)row * DD + cx];
                }
    }

    for (int c = 0; c < NCHUNK; c++) {
        const size_t gco = (size_t)(b * NCHUNK + c) * DD * DD;
        const size_t gcn = gco + (size_t)DD * DD;
        const bool even = (c & 1) == 0;
        if (c + 1 < NCHUNK) {
            #pragma unroll
            for (int ks = 0; ks < 4; ks++)
                #pragma unroll
                for (int j = 0; j < 2; j++) {
                    int hr = wj * 32 + j * 16 + m;
                    bf16x8 v = *(const bf16x8*)&HTb[gcn + (size_t)hr * DD + ks * 32 + quad * 8];
                    if (even) hB[ks * 2 + j] = v; else hA[ks * 2 + j] = v;
                }
        }
        #pragma unroll
        for (int i = 0; i < 2; i++)
            #pragma unroll
            for (int j = 0; j < 2; j++) {
                int row = i * 16 + quad * 4;
                int cx  = wj * 32 + j * 16 + m;
                #pragma unroll
                for (int r = 0; r < 4; r++)
                    Ss[row + r][cx] = (__bf16)acc[i][j][r];
            }
        __syncthreads();
        #pragma unroll
        for (int p = 0; p < 4; p++) {
            int idx = t + p * 256;
            int row = idx >> 5, c4 = idx & 31;
            *(bf16x4*)&S0b[gco + (size_t)(rg * 32 + row) * DD + c4 * 4] =
                *(const bf16x4*)&Ss[row][c4 * 4];
        }
        #pragma unroll
        for (int i = 0; i < 2; i++)
            #pragma unroll
            for (int j = 0; j < 2; j++)
                #pragma unroll
                for (int r = 0; r < 4; r++)
                    acc[i][j][r] += (float)gpre[(i * 2 + j) * 4 + r];
        if (c + 1 < NCHUNK) {
            #pragma unroll
            for (int i = 0; i < 2; i++)
                #pragma unroll
                for (int j = 0; j < 2; j++)
                    #pragma unroll
                    for (int r = 0; r < 4; r++) {
                        int row = rg * 32 + i * 16 + quad * 4 + r;
                        int cx  = wj * 32 + j * 16 + m;
                        gpre[(i * 2 + j) * 4 + r] = Gb[gcn + (size_t)row * DD + cx];
                    }
        }
        #pragma unroll
        for (int ks = 0; ks < 4; ks++) {
            bf16x8 a[2];
            #pragma unroll
            for (int i = 0; i < 2; i++)
                a[i] = *(const bf16x8*)&Ss[i * 16 + m][ks * 32 + quad * 8];
            #pragma unroll
            for (int i = 0; i < 2; i++)
                #pragma unroll
                for (int j = 0; j < 2; j++) {
                    bf16x8 hb = even ? hA[ks * 2 + j] : hB[ks * 2 + j];
                    acc[i][j] = __builtin_amdgcn_mfma_f32_16x16x32_bf16(a[i], hb, acc[i][j], 0, 0, 0);
                }
        }
        __syncthreads();
    }
}

// --------- O = P S0^T + Y, fused RMSNorm over D -> nmb (bf16, (B,L,D))
__global__ __launch_bounds__(256) void chunk_out(
    const __bf16* __restrict__ Pb, const __bf16* __restrict__ Yb, const __bf16* __restrict__ S0b,
    const float* __restrict__ rms_w, __bf16* __restrict__ nmb)
{
    const int c = blockIdx.x, b = blockIdx.y;
    const int gc = b * NCHUNK + c;
    const int t0 = c * CK;
    __shared__ __bf16 Ps[CK][136];
    __shared__ __bf16 Sb[DD][136];
    __shared__ float red[2][2][2][4][4];
    const int t = threadIdx.x;
    #pragma unroll
    for (int p = 0; p < 8; p++) {
        int idx = t + p * 256;
        int row = idx >> 5, c4 = idx & 31;
        *(bf16x4*)&Ps[row][c4 * 4] = *(const bf16x4*)&Pb[((size_t)gc * CK + row) * DD + c4 * 4];
    }
    #pragma unroll
    for (int p = 0; p < 16; p++) {
        int idx = t + p * 256;
        int row = idx >> 5, c4 = idx & 31;
        *(bf16x4*)&Sb[row][c4 * 4] = *(const bf16x4*)&S0b[((size_t)gc * DD + row) * DD + c4 * 4];
    }
    __syncthreads();

    const int wave = t >> 6, lane = t & 63;
    const int wm = wave & 1, wn = wave >> 1;
    const int m = lane & 15, quad = lane >> 4;

    floatx4 acc[2][4] = {};
    #pragma unroll
    for (int ks = 0; ks < 4; ks++) {
        bf16x8 a[2], bb[4];
        #pragma unroll
        for (int i = 0; i < 2; i++)
            a[i] = *(const bf16x8*)&Ps[wm * 32 + i * 16 + m][ks * 32 + quad * 8];
        #pragma unroll
        for (int j = 0; j < 4; j++)
            bb[j] = *(const bf16x8*)&Sb[wn * 64 + j * 16 + m][ks * 32 + quad * 8];
        #pragma unroll
        for (int i = 0; i < 2; i++)
            #pragma unroll
            for (int j = 0; j < 4; j++)
                acc[i][j] = __builtin_amdgcn_mfma_f32_16x16x32_bf16(a[i], bb[j], acc[i][j], 0, 0, 0);
    }

    float v[2][4][4];
    float ss[2][4] = {};
    #pragma unroll
    for (int i = 0; i < 2; i++)
        #pragma unroll
        for (int j = 0; j < 4; j++)
            #pragma unroll
            for (int r = 0; r < 4; r++) {
                int row = wm * 32 + i * 16 + quad * 4 + r;
                int cx  = wn * 64 + j * 16 + m;
                float y = (float)Yb[((size_t)gc * CK + row) * DD + cx];
                float vv = acc[i][j][r] + y;
                v[i][j][r] = vv;
                ss[i][r] = fmaf(vv, vv, ss[i][r]);
            }
    #pragma unroll
    for (int mask = 1; mask < 16; mask <<= 1)
        #pragma unroll
        for (int i = 0; i < 2; i++)
            #pragma unroll
            for (int r = 0; r < 4; r++)
                ss[i][r] += __shfl_xor(ss[i][r], mask, 64);
    if (m == 0)
        #pragma unroll
        for (int i = 0; i < 2; i++)
            #pragma unroll
            for (int r = 0; r < 4; r++)
                red[wn][wm][i][quad][r] = ss[i][r];
    __syncthreads();
    #pragma unroll
    for (int i = 0; i < 2; i++)
        #pragma unroll
        for (int r = 0; r < 4; r++) {
            float tot = red[0][wm][i][quad][r] + red[1][wm][i][quad][r];
            float inv = rsqrtf(tot * (1.f / 128.f) + 1.1920928955078125e-07f);
            int row = wm * 32 + i * 16 + quad * 4 + r;
            #pragma unroll
            for (int j = 0; j < 4; j++) {
                int cx = wn * 64 + j * 16 + m;
                nmb[((size_t)b * LL + t0 + row) * DD + cx] = (__bf16)(v[i][j][r] * inv * rms_w[cx]);
            }
        }
}

extern "C" void kernel_launch(void* const* d_in, const int* in_sizes, int n_in,
                              void* d_out, int out_size, void* d_ws, size_t ws_size,
                              hipStream_t stream) {
    const float* x    = (const float*)d_in[0];
    const float* kpw  = (const float*)d_in[1];
    const float* kpb  = (const float*)d_in[2];
    const float* qpw  = (const float*)d_in[3];
    const float* qpb  = (const float*)d_in[4];
    const float* vpw  = (const float*)d_in[5];
    const float* vpb  = (const float*)d_in[6];
    const float* kcw  = (const float*)d_in[7];
    const float* kcb  = (const float*)d_in[8];
    const float* qcw  = (const float*)d_in[9];
    const float* qcb  = (const float*)d_in[10];
    const float* vcw  = (const float*)d_in[11];
    const float* vcb  = (const float*)d_in[12];
    const float* bw   = (const float*)d_in[13];
    const float* bb   = (const float*)d_in[14];
    const float* rw   = (const float*)d_in[15];
    const float* ow   = (const float*)d_in[16];
    const float* obi  = (const float*)d_in[17];
    float* out = (float*)d_out;

    float* ws = (float*)d_ws;
    const size_t NB1 = (size_t)BB * DD * LL;   // 1,048,576 floats = 4 MB
    // slot map:
    //  0: k0 -> Lb+Wb(bf16) -> S0b(bf16)   1: q0 -> Ub(bf16)   2: v0 -> HTb(bf16)
    //  3: kcT   4: qcT   5: vcT -> Gb(bf16)
    //  6: nmb (bf16)   7: Pb+Yb(bf16)
    //  8: beta + sumsq + wpk + wcat + owb
    // xb (bf16, 32 MB) lives in d_out (64 MB) — dead before out_gemm overwrites it.
    float* k0  = ws;
    float* q0  = ws + NB1;
    float* v0  = ws + 2 * NB1;
    float* kcT = ws + 3 * NB1;
    float* qcT = ws + 4 * NB1;
    float* vcT = ws + 5 * NB1;
    float* beta  = ws + 8 * NB1;
    float* sumsq = beta + (size_t)BB * LL;
    __bf16* wpk  = (__bf16*)(sumsq + 1024);                 // 147456 bf16
    __bf16* wcat = wpk + (size_t)147456;                    // 786432 bf16 (1.5 MB)
    __bf16* owb  = wcat + (size_t)786432;                   // 262144 bf16 (0.5 MB)

    __bf16* Lb  = (__bf16*)k0;
    __bf16* Wb  = Lb + (size_t)128 * 64 * 64;
    __bf16* Ub  = (__bf16*)q0;
    __bf16* HTb = (__bf16*)v0;
    __bf16* Gb  = (__bf16*)vcT;
    __bf16* Pb  = (__bf16*)(ws + 7 * NB1);
    __bf16* Yb  = Pb + (size_t)128 * 64 * 128;
    __bf16* S0b = (__bf16*)k0;
    __bf16* nmb = (__bf16*)(ws + 6 * NB1);
    __bf16* xb  = (__bf16*)d_out;

    wpack_zero<<<dim3(1168), 256, 0, stream>>>(kcw, qcw, vcw, kpw, qpw, vpw, ow, wpk, wcat, owb, sumsq);
    beta_kernel<<<dim3(BB * LL), 256, 0, stream>>>(x, bw, bb, beta, xb);
    proj_gemm_mfma<<<dim3(128, 3), 256, 0, stream>>>(xb, wcat, kpb, qpb, vpb, k0, q0, v0);
    conv_mfma<<<dim3(32, 12), 256, 0, stream>>>(k0, q0, v0, wpk, kcb, qcb, vcb, kcT, qcT, vcT, sumsq);
    chunk_pre1<<<dim3(NCHUNK, BB), 256, 0, stream>>>(kcT, qcT, vcT, beta, sumsq, Lb, Wb, Ub);
    chunk_pre2<<<dim3(NCHUNK, BB), 256, 0, stream>>>(kcT, qcT, sumsq, Lb, Wb, Ub, HTb, Gb, Pb, Yb);
    delta_serial<<<dim3(BB * 4), 256, 0, stream>>>(HTb, Gb, S0b);
    chunk_out<<<dim3(NCHUNK, BB), 256, 0, stream>>>(Pb, Yb, S0b, rw, nmb);
    out_gemm_mfma<<<dim3(64, 16), 256, 0, stream>>>(nmb, owb, obi, out);
}

// Round 6
// 346.897 us; speedup vs baseline: 1.9225x; 1.0083x over previous
//
#include <hip/hip_runtime.h>
#include <math.h>

#define LL 2048
#define DD 128
#define BB 4
#define CK 64
#define NCHUNK 32

typedef __bf16 bf16x8 __attribute__((ext_vector_type(8)));
typedef __bf16 bf16x4 __attribute__((ext_vector_type(4)));
typedef float floatx4 __attribute__((ext_vector_type(4)));

// async global->LDS, 16B per lane. LDS dest must be wave-uniform base + lane*16.
__device__ __forceinline__ void gload_lds16(const void* g, void* l) {
    __builtin_amdgcn_global_load_lds(
        (const __attribute__((address_space(1))) unsigned int*)g,
        (__attribute__((address_space(3))) unsigned int*)l, 16, 0, 0);
}

// ================= proj GEMM (bf16 MFMA, global_load_lds, dbuf) =================
// C(8192x128 x3) = xb(8192x2048 bf16) @ wcat[arr]^T + b.  Tile 64x128, K-step 64.
__global__ __launch_bounds__(256) void proj_gemm_mfma(
    const __bf16* __restrict__ xb, const __bf16* __restrict__ wcat,
    const float* __restrict__ kb, const float* __restrict__ qb, const float* __restrict__ vb,
    float* __restrict__ k0, float* __restrict__ q0, float* __restrict__ v0)
{
    const int arr = blockIdx.y;
    const float* __restrict__ bia = arr == 0 ? kb : (arr == 1 ? qb : vb);
    float* __restrict__ out       = arr == 0 ? k0 : (arr == 1 ? q0 : v0);
    const __bf16* __restrict__ w  = wcat + (size_t)arr * DD * 2048;

    __shared__ __bf16 As[2][64 * 64];     // 8 KB each
    __shared__ __bf16 Bs[2][128 * 64];    // 16 KB each

    const int t = threadIdx.x;
    const int wave = t >> 6, lane = t & 63;
    const int wm = wave & 1, wn = wave >> 1;
    const int m = lane & 15, quad = lane >> 4;
    const int row0 = blockIdx.x * 64;

    floatx4 acc[2][4] = {};

    #pragma unroll
    for (int c = 0; c < 2; c++) {
        int f = t + c * 256;
        gload_lds16(&xb[(size_t)(row0 + (f >> 3)) * 2048 + (f & 7) * 8], &As[0][f * 8]);
    }
    #pragma unroll
    for (int c = 0; c < 4; c++) {
        int f = t + c * 256;
        gload_lds16(&w[(size_t)(f >> 3) * 2048 + (f & 7) * 8], &Bs[0][f * 8]);
    }
    __syncthreads();

    for (int kt = 0; kt < 32; kt++) {
        const int cur = kt & 1, nxt = cur ^ 1;
        if (kt + 1 < 32) {
            const int k0i = (kt + 1) * 64;
            #pragma unroll
            for (int c = 0; c < 2; c++) {
                int f = t + c * 256;
                gload_lds16(&xb[(size_t)(row0 + (f >> 3)) * 2048 + k0i + (f & 7) * 8], &As[nxt][f * 8]);
            }
            #pragma unroll
            for (int c = 0; c < 4; c++) {
                int f = t + c * 256;
                gload_lds16(&w[(size_t)(f >> 3) * 2048 + k0i + (f & 7) * 8], &Bs[nxt][f * 8]);
            }
        }
        #pragma unroll
        for (int ks = 0; ks < 2; ks++) {
            bf16x8 af[2], bfr[4];
            #pragma unroll
            for (int i = 0; i < 2; i++)
                af[i] = *(const bf16x8*)&As[cur][(wm * 32 + i * 16 + m) * 64 + ks * 32 + quad * 8];
            #pragma unroll
            for (int j = 0; j < 4; j++)
                bfr[j] = *(const bf16x8*)&Bs[cur][(wn * 64 + j * 16 + m) * 64 + ks * 32 + quad * 8];
            #pragma unroll
            for (int i = 0; i < 2; i++)
                #pragma unroll
                for (int j = 0; j < 4; j++)
                    acc[i][j] = __builtin_amdgcn_mfma_f32_16x16x32_bf16(af[i], bfr[j], acc[i][j], 0, 0, 0);
        }
        __syncthreads();
    }
    #pragma unroll
    for (int i = 0; i < 2; i++)
        #pragma unroll
        for (int j = 0; j < 4; j++) {
            int col = wn * 64 + j * 16 + m;
            float bv = bia[col];
            #pragma unroll
            for (int r = 0; r < 4; r++)
                out[(size_t)(row0 + wm * 32 + i * 16 + quad * 4 + r) * 128 + col] = acc[i][j][r] + bv;
        }
}

// ================= out GEMM: out(8192x2048) = nmb(8192x128 bf16) @ owb^T + ob ============
__global__ __launch_bounds__(256) void out_gemm_mfma(
    const __bf16* __restrict__ A, const __bf16* __restrict__ wb,
    const float* __restrict__ bias, float* __restrict__ out)
{
    __shared__ __bf16 As[128 * 128];
    __shared__ __bf16 Bs[128 * 128];

    const int t = threadIdx.x;
    const int wave = t >> 6, lane = t & 63;
    const int wm = wave & 1, wn = wave >> 1;
    const int m = lane & 15, quad = lane >> 4;
    const int row0 = blockIdx.x * 128;
    const int col0 = blockIdx.y * 128;

    #pragma unroll
    for (int c = 0; c < 8; c++) {
        int f = t + c * 256;
        gload_lds16(&A[(size_t)(row0 + (f >> 4)) * 128 + (f & 15) * 8], &As[f * 8]);
        gload_lds16(&wb[(size_t)(col0 + (f >> 4)) * 128 + (f & 15) * 8], &Bs[f * 8]);
    }
    __syncthreads();

    floatx4 acc[4][4] = {};
    #pragma unroll
    for (int ks = 0; ks < 4; ks++) {
        bf16x8 af[4], bfr[4];
        #pragma unroll
        for (int i = 0; i < 4; i++)
            af[i] = *(const bf16x8*)&As[(wm * 64 + i * 16 + m) * 128 + ks * 32 + quad * 8];
        #pragma unroll
        for (int j = 0; j < 4; j++)
            bfr[j] = *(const bf16x8*)&Bs[(wn * 64 + j * 16 + m) * 128 + ks * 32 + quad * 8];
        #pragma unroll
        for (int i = 0; i < 4; i++)
            #pragma unroll
            for (int j = 0; j < 4; j++)
                acc[i][j] = __builtin_amdgcn_mfma_f32_16x16x32_bf16(af[i], bfr[j], acc[i][j], 0, 0, 0);
    }
    #pragma unroll
    for (int i = 0; i < 4; i++) {
        int grow = row0 + wm * 64 + i * 16 + quad * 4;
        #pragma unroll
        for (int j = 0; j < 4; j++) {
            int col = col0 + wn * 64 + j * 16 + m;
            float bv = bias[col];
            #pragma unroll
            for (int r = 0; r < 4; r++)
                out[(size_t)(grow + r) * 2048 + col] = acc[i][j][r] + bv;
        }
    }
}

// ================= beta = sigmoid(x @ beta_w^T + beta_b); also emit xb = bf16(x) =========
__global__ __launch_bounds__(256) void beta_kernel(
    const float* __restrict__ x, const float* __restrict__ bw,
    const float* __restrict__ bb, float* __restrict__ beta, __bf16* __restrict__ xb)
{
    const int row = blockIdx.x;
    const float* xr = x + (size_t)row * 2048;
    __bf16* xbr = xb + (size_t)row * 2048;
    const int t = threadIdx.x;
    float s = 0.f;
    #pragma unroll
    for (int jj = 0; jj < 2; jj++) {
        int j = (t + jj * 256) * 4;
        float4 f = *(const float4*)&xr[j];
        float4 wv = *(const float4*)&bw[j];
        s = fmaf(f.x, wv.x, s); s = fmaf(f.y, wv.y, s);
        s = fmaf(f.z, wv.z, s); s = fmaf(f.w, wv.w, s);
        bf16x4 v; v[0] = (__bf16)f.x; v[1] = (__bf16)f.y; v[2] = (__bf16)f.z; v[3] = (__bf16)f.w;
        *(bf16x4*)&xbr[j] = v;
    }
    #pragma unroll
    for (int m = 1; m < 64; m <<= 1) s += __shfl_xor(s, m, 64);
    __shared__ float red[4];
    if ((t & 63) == 0) red[t >> 6] = s;
    __syncthreads();
    if (t == 0) {
        float tot = red[0] + red[1] + red[2] + red[3] + bb[0];
        beta[row] = 1.f / (1.f + expf(-tot));
    }
}

// ================= pack weights to bf16: conv wpk, proj wcat, out owb; zero sumsq =========
__global__ __launch_bounds__(256) void wpack_zero(
    const float* __restrict__ kw, const float* __restrict__ qw, const float* __restrict__ vw,
    const float* __restrict__ kpw, const float* __restrict__ qpw, const float* __restrict__ vpw,
    const float* __restrict__ ow,
    __bf16* __restrict__ wpk, __bf16* __restrict__ wcat, __bf16* __restrict__ owb,
    float* __restrict__ sumsq)
{
    const int t = threadIdx.x;
    const int bx = blockIdx.x;
    if (bx == 0) {
        #pragma unroll
        for (int e = 0; e < 4; e++) sumsq[t * 4 + e] = 0.f;
    }
    if (bx < 144) {
        int base = (bx * 256 + t) * 4;                    // over 3*3*128*128 = 147456
        int arr = base / 49152, rem = base % 49152;
        const float* __restrict__ w = arr == 0 ? kw : arr == 1 ? qw : vw;
        int dt = rem / 16384, rem2 = rem % 16384;
        int o = rem2 >> 7, i0 = rem2 & 127;
        #pragma unroll
        for (int e = 0; e < 4; e++) {
            int i = i0 + e;
            wpk[base + e] = (__bf16)w[(size_t)((o * 128 + i) * 3 + dt) * 3 + 1];
        }
    } else if (bx < 912) {
        int e = (bx - 144) * 1024 + t * 4;                // over 3*128*2048 = 786432
        int arr = e >> 18, rem = e & 262143;
        const float* __restrict__ w = arr == 0 ? kpw : arr == 1 ? qpw : vpw;
        float4 f = *(const float4*)&w[rem];
        bf16x4 v; v[0] = (__bf16)f.x; v[1] = (__bf16)f.y; v[2] = (__bf16)f.z; v[3] = (__bf16)f.w;
        *(bf16x4*)&wcat[(size_t)arr * 262144 + rem] = v;
    } else {
        int e = (bx - 912) * 1024 + t * 4;                // over 2048*128 = 262144
        float4 f = *(const float4*)&ow[e];
        bf16x4 v; v[0] = (__bf16)f.x; v[1] = (__bf16)f.y; v[2] = (__bf16)f.z; v[3] = (__bf16)f.w;
        *(bf16x4*)&owb[e] = v;
    }
}

// ================= conv as MFMA GEMM + bias + SiLU + fused l2norm partials ================
__global__ __launch_bounds__(256) void conv_mfma(
    const float* __restrict__ k0, const float* __restrict__ q0, const float* __restrict__ v0,
    const __bf16* __restrict__ wpk,
    const float* __restrict__ kb, const float* __restrict__ qb, const float* __restrict__ vb,
    float* __restrict__ kcT, float* __restrict__ qcT, float* __restrict__ vcT,
    float* __restrict__ sumsq)
{
    const int sb  = blockIdx.x;
    const int arr = blockIdx.y >> 2;
    const int b   = blockIdx.y & 3;
    const float* __restrict__ in = (arr == 0 ? k0 : arr == 1 ? q0 : v0) + (size_t)b * DD * LL;
    const float* __restrict__ bi = arr == 0 ? kb : arr == 1 ? qb : vb;
    float* __restrict__ out      = (arr == 0 ? kcT : arr == 1 ? qcT : vcT) + (size_t)b * LL * DD;
    const __bf16* __restrict__ wp = wpk + (size_t)arr * 3 * DD * DD;

    __shared__ __bf16 Xs[66 * 136];
    __shared__ float colsum[128];

    const int t = threadIdx.x;
    const int s0 = sb * 64;
    if (t < 128) colsum[t] = 0.f;

    #pragma unroll
    for (int p = 0; p < 32; p++) {
        int idx = t + p * 256;
        int sr = idx & 63, i = idx >> 6;
        float v = in[(size_t)i * LL + s0 + sr];
        int row = sr + 1;
        Xs[row * 136 + (i ^ ((row & 7) << 4))] = (__bf16)v;
    }
    {
        int e = t >> 7, i = t & 127;
        int row = e * 65;
        int s = s0 - 1 + e * 65;
        float v = (s >= 0 && s < LL) ? in[(size_t)i * LL + s] : 0.f;
        Xs[row * 136 + (i ^ ((row & 7) << 4))] = (__bf16)v;
    }
    __syncthreads();

    const int wave = t >> 6, lane = t & 63;
    const int wm = wave & 1, wn = wave >> 1;
    const int m = lane & 15, quad = lane >> 4;

    floatx4 acc[2][4] = {};
    #pragma unroll
    for (int dt = 0; dt < 3; dt++) {
        bf16x8 bfr[4][4];
        #pragma unroll
        for (int ks = 0; ks < 4; ks++)
            #pragma unroll
            for (int j = 0; j < 4; j++)
                bfr[ks][j] = *(const bf16x8*)&wp[(size_t)(dt * DD + wn * 64 + j * 16 + m) * DD + ks * 32 + quad * 8];
        #pragma unroll
        for (int ks = 0; ks < 4; ks++) {
            bf16x8 af[2];
            #pragma unroll
            for (int ii = 0; ii < 2; ii++) {
                int row = wm * 32 + ii * 16 + m + dt;
                af[ii] = *(const bf16x8*)&Xs[row * 136 + ((ks * 32 + quad * 8) ^ ((row & 7) << 4))];
            }
            #pragma unroll
            for (int ii = 0; ii < 2; ii++)
                #pragma unroll
                for (int j = 0; j < 4; j++)
                    acc[ii][j] = __builtin_amdgcn_mfma_f32_16x16x32_bf16(af[ii], bfr[ks][j], acc[ii][j], 0, 0, 0);
        }
    }

    float part[4] = {0.f, 0.f, 0.f, 0.f};
    #pragma unroll
    for (int ii = 0; ii < 2; ii++)
        #pragma unroll
        for (int j = 0; j < 4; j++) {
            int col = wn * 64 + j * 16 + m;
            float bv = bi[col];
            #pragma unroll
            for (int r = 0; r < 4; r++) {
                int srow = s0 + wm * 32 + ii * 16 + quad * 4 + r;
                float v = acc[ii][j][r] + bv;
                float y = v / (1.f + expf(-v));
                out[(size_t)srow * DD + col] = y;
                part[j] = fmaf(y, y, part[j]);
            }
        }
    if (arr < 2) {
        #pragma unroll
        for (int j = 0; j < 4; j++)
            atomicAdd(&colsum[wn * 64 + j * 16 + m], part[j]);
        __syncthreads();
        if (t < 128) atomicAdd(&sumsq[arr * 512 + b * 128 + t], colsum[t]);
    }
}

// ============================================================================
// Chunked delta rule (WY / UT transform), C = 64 — see R0 derivation.
// ============================================================================

// --------- PRE1: A, L, and triangular solve -> W, U0.
// Latency fix: forward substitution batched 8-wide (8 independent ds_reads/step);
// Af stores -beta*KK^T off-diagonal, beta on the diagonal (betas array deleted);
// WU aliases the dead Ks/Qs buffers -> LDS exactly 80 KB -> 2 blocks/CU.
__global__ __launch_bounds__(256) void chunk_pre1(
    const float* __restrict__ kTg, const float* __restrict__ qTg, const float* __restrict__ vTg,
    const float* __restrict__ beta, const float* __restrict__ sumsq,
    __bf16* __restrict__ Lb, __bf16* __restrict__ Wb, __bf16* __restrict__ Ub)
{
    const int c = blockIdx.x, b = blockIdx.y;
    const int gc = b * NCHUNK + c;
    const int t0 = c * CK;
    const float* kbase = kTg + ((size_t)b * LL + t0) * DD;
    const float* qbase = qTg + ((size_t)b * LL + t0) * DD;
    const float* vbase = vTg + ((size_t)b * LL + t0) * DD;

    __shared__ float pool[16384];      // 64 KB: phase1 = Ks+Qs (34.8 KB), phase2 = WU[64][256]
    __shared__ float Af[CK][64];       // 16 KB; Af[i][j<i] = -beta_i*(KK^T)_ij, Af[i][i] = beta_i
    __bf16 (*Ks)[136] = (__bf16(*)[136])pool;
    __bf16 (*Qs)[136] = (__bf16(*)[136])((char*)pool + CK * 136 * 2);
    float (*WU)[256]  = (float(*)[256])pool;

    const int t = threadIdx.x;
    #pragma unroll
    for (int p = 0; p < 8; p++) {
        int idx = t + p * 256;          // 2048 float4 chunks = 64 x 128
        int r = idx >> 5, c4 = idx & 31;
        float4 sk = *(const float4*)&sumsq[b * 128 + c4 * 4];
        float4 sq = *(const float4*)&sumsq[512 + b * 128 + c4 * 4];
        float ik0 = rsqrtf(fmaxf(sk.x, 1e-24f)), ik1 = rsqrtf(fmaxf(sk.y, 1e-24f));
        float ik2 = rsqrtf(fmaxf(sk.z, 1e-24f)), ik3 = rsqrtf(fmaxf(sk.w, 1e-24f));
        float iq0 = rsqrtf(fmaxf(sq.x, 1e-24f)), iq1 = rsqrtf(fmaxf(sq.y, 1e-24f));
        float iq2 = rsqrtf(fmaxf(sq.z, 1e-24f)), iq3 = rsqrtf(fmaxf(sq.w, 1e-24f));
        float4 f = *(const float4*)&kbase[(size_t)r * DD + c4 * 4];
        bf16x4 v; v[0] = (__bf16)(f.x * ik0); v[1] = (__bf16)(f.y * ik1);
        v[2] = (__bf16)(f.z * ik2); v[3] = (__bf16)(f.w * ik3);
        *(bf16x4*)&Ks[r][c4 * 4] = v;
        float4 g = *(const float4*)&qbase[(size_t)r * DD + c4 * 4];
        bf16x4 u; u[0] = (__bf16)(g.x * iq0); u[1] = (__bf16)(g.y * iq1);
        u[2] = (__bf16)(g.z * iq2); u[3] = (__bf16)(g.w * iq3);
        *(bf16x4*)&Qs[r][c4 * 4] = u;
    }
    __syncthreads();

    const int wave = t >> 6, lane = t & 63;
    const int wm = wave & 1, wn = wave >> 1;
    const int m = lane & 15, quad = lane >> 4;

    floatx4 accM[2][2] = {}, accL[2][2] = {};
    #pragma unroll
    for (int ks = 0; ks < 4; ks++) {
        bf16x8 ak[2], aq[2], bk[2];
        #pragma unroll
        for (int i = 0; i < 2; i++) {
            ak[i] = *(const bf16x8*)&Ks[wm * 32 + i * 16 + m][ks * 32 + quad * 8];
            aq[i] = *(const bf16x8*)&Qs[wm * 32 + i * 16 + m][ks * 32 + quad * 8];
            bk[i] = *(const bf16x8*)&Ks[wn * 32 + i * 16 + m][ks * 32 + quad * 8];
        }
        #pragma unroll
        for (int i = 0; i < 2; i++)
            #pragma unroll
            for (int j = 0; j < 2; j++) {
                accM[i][j] = __builtin_amdgcn_mfma_f32_16x16x32_bf16(ak[i], bk[j], accM[i][j], 0, 0, 0);
                accL[i][j] = __builtin_amdgcn_mfma_f32_16x16x32_bf16(aq[i], bk[j], accL[i][j], 0, 0, 0);
            }
    }
    #pragma unroll
    for (int i = 0; i < 2; i++) {
        #pragma unroll
        for (int r = 0; r < 4; r++) {
            int row = wm * 32 + i * 16 + quad * 4 + r;
            float bval = beta[(size_t)b * LL + t0 + row];
            #pragma unroll
            for (int j = 0; j < 2; j++) {
                int col = wn * 32 + j * 16 + m;
                Af[row][col] = (col < row) ? -bval * accM[i][j][r] : (col == row ? bval : 0.f);
                Lb[((size_t)gc * CK + row) * CK + col] =
                    (col <= row) ? (__bf16)accL[i][j][r] : (__bf16)0.f;
            }
        }
    }
    __syncthreads();   // Ks/Qs dead beyond this point; pool becomes WU

    // forward substitution: (I+A)[W|U0] = beta [K_norm|V]; thread t owns column t.
    // batched 8-wide: 8 independent WU reads per step amortize ds_read latency.
    const int col = t;
    const float* rbase = (col < DD) ? kbase : vbase;
    const int cm = col & (DD - 1);
    const float scale = (col < DD) ? rsqrtf(fmaxf(sumsq[b * 128 + cm], 1e-24f)) : 1.f;
    float cur = rbase[cm] * scale;
    for (int tt = 0; tt < CK; tt++) {
        float nxt = (tt < CK - 1) ? rbase[(size_t)(tt + 1) * DD + cm] * scale : 0.f;
        float p0 = 0.f, p1 = 0.f, p2 = 0.f, p3 = 0.f;
        int s = 0;
        for (; s + 8 <= tt; s += 8) {
            float a0 = Af[tt][s + 0], a1 = Af[tt][s + 1], a2 = Af[tt][s + 2], a3 = Af[tt][s + 3];
            float a4 = Af[tt][s + 4], a5 = Af[tt][s + 5], a6 = Af[tt][s + 6], a7 = Af[tt][s + 7];
            float w0 = WU[s + 0][col], w1 = WU[s + 1][col], w2 = WU[s + 2][col], w3 = WU[s + 3][col];
            float w4 = WU[s + 4][col], w5 = WU[s + 5][col], w6 = WU[s + 6][col], w7 = WU[s + 7][col];
            p0 = fmaf(a0, w0, p0); p1 = fmaf(a1, w1, p1);
            p2 = fmaf(a2, w2, p2); p3 = fmaf(a3, w3, p3);
            p0 = fmaf(a4, w4, p0); p1 = fmaf(a5, w5, p1);
            p2 = fmaf(a6, w6, p2); p3 = fmaf(a7, w7, p3);
        }
        for (; s < tt; s++) p0 = fmaf(Af[tt][s], WU[s][col], p0);
        float acc = fmaf(Af[tt][tt], cur, (p0 + p1) + (p2 + p3));
        WU[tt][col] = acc;
        __bf16 bv = (__bf16)acc;
        if (col < DD) Wb[((size_t)gc * CK + tt) * DD + col] = bv;
        else          Ub[((size_t)gc * CK + tt) * DD + cm]  = bv;
        cur = nxt;
    }
}

// --------- PRE2 (parallel): H, G, P, Y from W, U0, L, K, Q
__global__ __launch_bounds__(256) void chunk_pre2(
    const float* __restrict__ kTg, const float* __restrict__ qTg,
    const float* __restrict__ sumsq,
    const __bf16* __restrict__ Lb, const __bf16* __restrict__ Wb, const __bf16* __restrict__ Ub,
    __bf16* __restrict__ HTb, __bf16* __restrict__ Gb,
    __bf16* __restrict__ Pb, __bf16* __restrict__ Yb)
{
    const int c = blockIdx.x, b = blockIdx.y;
    const int gc = b * NCHUNK + c;
    const int t0 = c * CK;

    __shared__ __bf16 Kt[DD][72];
    __shared__ __bf16 Wt[DD][72];
    __shared__ __bf16 Ut[DD][72];
    __shared__ __bf16 Ls[CK][72];

    const int t = threadIdx.x;
    #pragma unroll
    for (int p = 0; p < 8; p++) {
        int idx = t + p * 256;
        int tt = idx >> 5, j4 = idx & 31;
        float4 sk = *(const float4*)&sumsq[b * 128 + j4 * 4];
        float4 f = *(const float4*)&kTg[((size_t)b * LL + t0 + tt) * DD + j4 * 4];
        Kt[j4 * 4 + 0][tt] = (__bf16)(f.x * rsqrtf(fmaxf(sk.x, 1e-24f)));
        Kt[j4 * 4 + 1][tt] = (__bf16)(f.y * rsqrtf(fmaxf(sk.y, 1e-24f)));
        Kt[j4 * 4 + 2][tt] = (__bf16)(f.z * rsqrtf(fmaxf(sk.z, 1e-24f)));
        Kt[j4 * 4 + 3][tt] = (__bf16)(f.w * rsqrtf(fmaxf(sk.w, 1e-24f)));
        bf16x4 w = *(const bf16x4*)&Wb[((size_t)gc * CK + tt) * DD + j4 * 4];
        bf16x4 u = *(const bf16x4*)&Ub[((size_t)gc * CK + tt) * DD + j4 * 4];
        #pragma unroll
        for (int e = 0; e < 4; e++) { Wt[j4 * 4 + e][tt] = w[e]; Ut[j4 * 4 + e][tt] = u[e]; }
    }
    #pragma unroll
    for (int p = 0; p < 4; p++) {
        int idx = t + p * 256;
        int tt = idx >> 4, s4 = idx & 15;
        *(bf16x4*)&Ls[tt][s4 * 4] = *(const bf16x4*)&Lb[((size_t)gc * CK + tt) * CK + s4 * 4];
    }
    __syncthreads();

    const int wave = t >> 6, lane = t & 63;
    const int wm = wave & 1, wn = wave >> 1;
    const int m = lane & 15, quad = lane >> 4;

    // H^T (negated): C[j][i] = -sum_t Kt[j][t] Wt[i][t]
    {
        floatx4 acc[4][4] = {};
        #pragma unroll
        for (int ks = 0; ks < 2; ks++) {
            bf16x8 a[4], bb[4];
            #pragma unroll
            for (int i = 0; i < 4; i++) {
                a[i]  = *(const bf16x8*)&Kt[wm * 64 + i * 16 + m][ks * 32 + quad * 8];
                bb[i] = *(const bf16x8*)&Wt[wn * 64 + i * 16 + m][ks * 32 + quad * 8];
            }
            #pragma unroll
            for (int i = 0; i < 4; i++)
                #pragma unroll
                for (int j = 0; j < 4; j++)
                    acc[i][j] = __builtin_amdgcn_mfma_f32_16x16x32_bf16(a[i], bb[j], acc[i][j], 0, 0, 0);
        }
        #pragma unroll
        for (int i = 0; i < 4; i++)
            #pragma unroll
            for (int j = 0; j < 4; j++)
                #pragma unroll
                for (int r = 0; r < 4; r++) {
                    int row = wm * 64 + i * 16 + quad * 4 + r;
                    int cx  = wn * 64 + j * 16 + m;
                    HTb[((size_t)gc * DD + row) * DD + cx] = (__bf16)(-acc[i][j][r]);
                }
    }
    // G: C[i][j] = sum_t Ut[i][t] Kt[j][t]
    {
        floatx4 acc[4][4] = {};
        #pragma unroll
        for (int ks = 0; ks < 2; ks++) {
            bf16x8 a[4], bb[4];
            #pragma unroll
            for (int i = 0; i < 4; i++) {
                a[i]  = *(const bf16x8*)&Ut[wm * 64 + i * 16 + m][ks * 32 + quad * 8];
                bb[i] = *(const bf16x8*)&Kt[wn * 64 + i * 16 + m][ks * 32 + quad * 8];
            }
            #pragma unroll
            for (int i = 0; i < 4; i++)
                #pragma unroll
                for (int j = 0; j < 4; j++)
                    acc[i][j] = __builtin_amdgcn_mfma_f32_16x16x32_bf16(a[i], bb[j], acc[i][j], 0, 0, 0);
        }
        #pragma unroll
        for (int i = 0; i < 4; i++)
            #pragma unroll
            for (int j = 0; j < 4; j++)
                #pragma unroll
                for (int r = 0; r < 4; r++) {
                    int row = wm * 64 + i * 16 + quad * 4 + r;
                    int cx  = wn * 64 + j * 16 + m;
                    Gb[((size_t)gc * DD + row) * DD + cx] = (__bf16)acc[i][j][r];
                }
    }
    // P = Q - L W
    {
        floatx4 acc[2][4] = {};
        #pragma unroll
        for (int ks = 0; ks < 2; ks++) {
            bf16x8 a[2], bb[4];
            #pragma unroll
            for (int i = 0; i < 2; i++)
                a[i] = *(const bf16x8*)&Ls[wm * 32 + i * 16 + m][ks * 32 + quad * 8];
            #pragma unroll
            for (int j = 0; j < 4; j++)
                bb[j] = *(const bf16x8*)&Wt[wn * 64 + j * 16 + m][ks * 32 + quad * 8];
            #pragma unroll
            for (int i = 0; i < 2; i++)
                #pragma unroll
                for (int j = 0; j < 4; j++)
                    acc[i][j] = __builtin_amdgcn_mfma_f32_16x16x32_bf16(a[i], bb[j], acc[i][j], 0, 0, 0);
        }
        #pragma unroll
        for (int i = 0; i < 2; i++)
            #pragma unroll
            for (int j = 0; j < 4; j++)
                #pragma unroll
                for (int r = 0; r < 4; r++) {
                    int row = wm * 32 + i * 16 + quad * 4 + r;
                    int cx  = wn * 64 + j * 16 + m;
                    float iq = rsqrtf(fmaxf(sumsq[512 + b * 128 + cx], 1e-24f));
                    float qv = qTg[((size_t)b * LL + t0 + row) * DD + cx] * iq;
                    Pb[((size_t)gc * CK + row) * DD + cx] = (__bf16)(qv - acc[i][j][r]);
                }
    }
    // Y = L U0
    {
        floatx4 acc[2][4] = {};
        #pragma unroll
        for (int ks = 0; ks < 2; ks++) {
            bf16x8 a[2], bb[4];
            #pragma unroll
            for (int i = 0; i < 2; i++)
                a[i] = *(const bf16x8*)&Ls[wm * 32 + i * 16 + m][ks * 32 + quad * 8];
            #pragma unroll
            for (int j = 0; j < 4; j++)
                bb[j] = *(const bf16x8*)&Ut[wn * 64 + j * 16 + m][ks * 32 + quad * 8];
            #pragma unroll
            for (int i = 0; i < 2; i++)
                #pragma unroll
                for (int j = 0; j < 4; j++)
                    acc[i][j] = __builtin_amdgcn_mfma_f32_16x16x32_bf16(a[i], bb[j], acc[i][j], 0, 0, 0);
        }
        #pragma unroll
        for (int i = 0; i < 2; i++)
            #pragma unroll
            for (int j = 0; j < 4; j++)
                #pragma unroll
                for (int r = 0; r < 4; r++) {
                    int row = wm * 32 + i * 16 + quad * 4 + r;
                    int cx  = wn * 64 + j * 16 + m;
                    Yb[((size_t)gc * CK + row) * DD + cx] = (__bf16)acc[i][j][r];
                }
    }
}

// --------- serial chain: S <- S (I - H) + G; 16 blocks (4b x 4 rowgroups of 32 rows)
__global__ __launch_bounds__(256) void delta_serial(
    const __bf16* __restrict__ HTb, const __bf16* __restrict__ Gb, __bf16* __restrict__ S0b)
{
    const int b  = blockIdx.x >> 2;
    const int rg = blockIdx.x & 3;
    __shared__ __bf16 Ss[32][136];
    const int t = threadIdx.x;
    const int wj = t >> 6;
    const int lane = t & 63;
    const int m = lane & 15, quad = lane >> 4;

    floatx4 acc[2][2] = {};
    bf16x8 hA[8], hB[8];
    __bf16 gpre[16];

    {
        const size_t g0 = (size_t)(b * NCHUNK) * DD * DD;
        #pragma unroll
        for (int ks = 0; ks < 4; ks++)
            #pragma unroll
            for (int j = 0; j < 2; j++) {
                int hr = wj * 32 + j * 16 + m;
                hA[ks * 2 + j] = *(const bf16x8*)&HTb[g0 + (size_t)hr * DD + ks * 32 + quad * 8];
            }
        #pragma unroll
        for (int i = 0; i < 2; i++)
            #pragma unroll
            for (int j = 0; j < 2; j++)
                #pragma unroll
                for (int r = 0; r < 4; r++) {
                    int row = rg * 32 + i * 16 + quad * 4 + r;
                    int cx  = wj * 32 + j * 16 + m;
                    gpre[(i * 2 + j) * 4 + r] = Gb[g0 + (size_t)row * DD + cx];
                }
    }

    for (int c = 0; c < NCHUNK; c++) {
        const size_t gco = (size_t)(b * NCHUNK + c) * DD * DD;
        const size_t gcn = gco + (size_t)DD * DD;
        const bool even = (c & 1) == 0;
        if (c + 1 < NCHUNK) {
            #pragma unroll
            for (int ks = 0; ks < 4; ks++)
                #pragma unroll
                for (int j = 0; j < 2; j++) {
                    int hr = wj * 32 + j * 16 + m;
                    bf16x8 v = *(const bf16x8*)&HTb[gcn + (size_t)hr * DD + ks * 32 + quad * 8];
                    if (even) hB[ks * 2 + j] = v; else hA[ks * 2 + j] = v;
                }
        }
        #pragma unroll
        for (int i = 0; i < 2; i++)
            #pragma unroll
            for (int j = 0; j < 2; j++) {
                int row = i * 16 + quad * 4;
                int cx  = wj * 32 + j * 16 + m;
                #pragma unroll
                for (int r = 0; r < 4; r++)
                    Ss[row + r][cx] = (__bf16)acc[i][j][r];
            }
        __syncthreads();
        #pragma unroll
        for (int p = 0; p < 4; p++) {
            int idx = t + p * 256;
            int row = idx >> 5, c4 = idx & 31;
            *(bf16x4*)&S0b[gco + (size_t)(rg * 32 + row) * DD + c4 * 4] =
                *(const bf16x4*)&Ss[row][c4 * 4];
        }
        #pragma unroll
        for (int i = 0; i < 2; i++)
            #pragma unroll
            for (int j = 0; j < 2; j++)
                #pragma unroll
                for (int r = 0; r < 4; r++)
                    acc[i][j][r] += (float)gpre[(i * 2 + j) * 4 + r];
        if (c + 1 < NCHUNK) {
            #pragma unroll
            for (int i = 0; i < 2; i++)
                #pragma unroll
                for (int j = 0; j < 2; j++)
                    #pragma unroll
                    for (int r = 0; r < 4; r++) {
                        int row = rg * 32 + i * 16 + quad * 4 + r;
                        int cx  = wj * 32 + j * 16 + m;
                        gpre[(i * 2 + j) * 4 + r] = Gb[gcn + (size_t)row * DD + cx];
                    }
        }
        #pragma unroll
        for (int ks = 0; ks < 4; ks++) {
            bf16x8 a[2];
            #pragma unroll
            for (int i = 0; i < 2; i++)
                a[i] = *(const bf16x8*)&Ss[i * 16 + m][ks * 32 + quad * 8];
            #pragma unroll
            for (int i = 0; i < 2; i++)
                #pragma unroll
                for (int j = 0; j < 2; j++) {
                    bf16x8 hb = even ? hA[ks * 2 + j] : hB[ks * 2 + j];
                    acc[i][j] = __builtin_amdgcn_mfma_f32_16x16x32_bf16(a[i], hb, acc[i][j], 0, 0, 0);
                }
        }
        __syncthreads();
    }
}

// --------- O = P S0^T + Y, fused RMSNorm over D -> nmb (bf16, (B,L,D))
__global__ __launch_bounds__(256) void chunk_out(
    const __bf16* __restrict__ Pb, const __bf16* __restrict__ Yb, const __bf16* __restrict__ S0b,
    const float* __restrict__ rms_w, __bf16* __restrict__ nmb)
{
    const int c = blockIdx.x, b = blockIdx.y;
    const int gc = b * NCHUNK + c;
    const int t0 = c * CK;
    __shared__ __bf16 Ps[CK][136];
    __shared__ __bf16 Sb[DD][136];
    __shared__ float red[2][2][2][4][4];
    const int t = threadIdx.x;
    #pragma unroll
    for (int p = 0; p < 8; p++) {
        int idx = t + p * 256;
        int row = idx >> 5, c4 = idx & 31;
        *(bf16x4*)&Ps[row][c4 * 4] = *(const bf16x4*)&Pb[((size_t)gc * CK + row) * DD + c4 * 4];
    }
    #pragma unroll
    for (int p = 0; p < 16; p++) {
        int idx = t + p * 256;
        int row = idx >> 5, c4 = idx & 31;
        *(bf16x4*)&Sb[row][c4 * 4] = *(const bf16x4*)&S0b[((size_t)gc * DD + row) * DD + c4 * 4];
    }
    __syncthreads();

    const int wave = t >> 6, lane = t & 63;
    const int wm = wave & 1, wn = wave >> 1;
    const int m = lane & 15, quad = lane >> 4;

    floatx4 acc[2][4] = {};
    #pragma unroll
    for (int ks = 0; ks < 4; ks++) {
        bf16x8 a[2], bb[4];
        #pragma unroll
        for (int i = 0; i < 2; i++)
            a[i] = *(const bf16x8*)&Ps[wm * 32 + i * 16 + m][ks * 32 + quad * 8];
        #pragma unroll
        for (int j = 0; j < 4; j++)
            bb[j] = *(const bf16x8*)&Sb[wn * 64 + j * 16 + m][ks * 32 + quad * 8];
        #pragma unroll
        for (int i = 0; i < 2; i++)
            #pragma unroll
            for (int j = 0; j < 4; j++)
                acc[i][j] = __builtin_amdgcn_mfma_f32_16x16x32_bf16(a[i], bb[j], acc[i][j], 0, 0, 0);
    }

    float v[2][4][4];
    float ss[2][4] = {};
    #pragma unroll
    for (int i = 0; i < 2; i++)
        #pragma unroll
        for (int j = 0; j < 4; j++)
            #pragma unroll
            for (int r = 0; r < 4; r++) {
                int row = wm * 32 + i * 16 + quad * 4 + r;
                int cx  = wn * 64 + j * 16 + m;
                float y = (float)Yb[((size_t)gc * CK + row) * DD + cx];
                float vv = acc[i][j][r] + y;
                v[i][j][r] = vv;
                ss[i][r] = fmaf(vv, vv, ss[i][r]);
            }
    #pragma unroll
    for (int mask = 1; mask < 16; mask <<= 1)
        #pragma unroll
        for (int i = 0; i < 2; i++)
            #pragma unroll
            for (int r = 0; r < 4; r++)
                ss[i][r] += __shfl_xor(ss[i][r], mask, 64);
    if (m == 0)
        #pragma unroll
        for (int i = 0; i < 2; i++)
            #pragma unroll
            for (int r = 0; r < 4; r++)
                red[wn][wm][i][quad][r] = ss[i][r];
    __syncthreads();
    #pragma unroll
    for (int i = 0; i < 2; i++)
        #pragma unroll
        for (int r = 0; r < 4; r++) {
            float tot = red[0][wm][i][quad][r] + red[1][wm][i][quad][r];
            float inv = rsqrtf(tot * (1.f / 128.f) + 1.1920928955078125e-07f);
            int row = wm * 32 + i * 16 + quad * 4 + r;
            #pragma unroll
            for (int j = 0; j < 4; j++) {
                int cx = wn * 64 + j * 16 + m;
                nmb[((size_t)b * LL + t0 + row) * DD + cx] = (__bf16)(v[i][j][r] * inv * rms_w[cx]);
            }
        }
}

extern "C" void kernel_launch(void* const* d_in, const int* in_sizes, int n_in,
                              void* d_out, int out_size, void* d_ws, size_t ws_size,
                              hipStream_t stream) {
    const float* x    = (const float*)d_in[0];
    const float* kpw  = (const float*)d_in[1];
    const float* kpb  = (const float*)d_in[2];
    const float* qpw  = (const float*)d_in[3];
    const float* qpb  = (const float*)d_in[4];
    const float* vpw  = (const float*)d_in[5];
    const float* vpb  = (const float*)d_in[6];
    const float* kcw  = (const float*)d_in[7];
    const float* kcb  = (const float*)d_in[8];
    const float* qcw  = (const float*)d_in[9];
    const float* qcb  = (const float*)d_in[10];
    const float* vcw  = (const float*)d_in[11];
    const float* vcb  = (const float*)d_in[12];
    const float* bw   = (const float*)d_in[13];
    const float* bb   = (const float*)d_in[14];
    const float* rw   = (const float*)d_in[15];
    const float* ow   = (const float*)d_in[16];
    const float* obi  = (const float*)d_in[17];
    float* out = (float*)d_out;

    float* ws = (float*)d_ws;
    const size_t NB1 = (size_t)BB * DD * LL;   // 1,048,576 floats = 4 MB
    float* k0  = ws;
    float* q0  = ws + NB1;
    float* v0  = ws + 2 * NB1;
    float* kcT = ws + 3 * NB1;
    float* qcT = ws + 4 * NB1;
    float* vcT = ws + 5 * NB1;
    float* beta  = ws + 8 * NB1;
    float* sumsq = beta + (size_t)BB * LL;
    __bf16* wpk  = (__bf16*)(sumsq + 1024);                 // 147456 bf16
    __bf16* wcat = wpk + (size_t)147456;                    // 786432 bf16 (1.5 MB)
    __bf16* owb  = wcat + (size_t)786432;                   // 262144 bf16 (0.5 MB)

    __bf16* Lb  = (__bf16*)k0;
    __bf16* Wb  = Lb + (size_t)128 * 64 * 64;
    __bf16* Ub  = (__bf16*)q0;
    __bf16* HTb = (__bf16*)v0;
    __bf16* Gb  = (__bf16*)vcT;
    __bf16* Pb  = (__bf16*)(ws + 7 * NB1);
    __bf16* Yb  = Pb + (size_t)128 * 64 * 128;
    __bf16* S0b = (__bf16*)k0;
    __bf16* nmb = (__bf16*)(ws + 6 * NB1);
    __bf16* xb  = (__bf16*)d_out;

    wpack_zero<<<dim3(1168), 256, 0, stream>>>(kcw, qcw, vcw, kpw, qpw, vpw, ow, wpk, wcat, owb, sumsq);
    beta_kernel<<<dim3(BB * LL), 256, 0, stream>>>(x, bw, bb, beta, xb);
    proj_gemm_mfma<<<dim3(128, 3), 256, 0, stream>>>(xb, wcat, kpb, qpb, vpb, k0, q0, v0);
    conv_mfma<<<dim3(32, 12), 256, 0, stream>>>(k0, q0, v0, wpk, kcb, qcb, vcb, kcT, qcT, vcT, sumsq);
    chunk_pre1<<<dim3(NCHUNK, BB), 256, 0, stream>>>(kcT, qcT, vcT, beta, sumsq, Lb, Wb, Ub);
    chunk_pre2<<<dim3(NCHUNK, BB), 256, 0, stream>>>(kcT, qcT, sumsq, Lb, Wb, Ub, HTb, Gb, Pb, Yb);
    delta_serial<<<dim3(BB * 4), 256, 0, stream>>>(HTb, Gb, S0b);
    chunk_out<<<dim3(NCHUNK, BB), 256, 0, stream>>>(Pb, Yb, S0b, rw, nmb);
    out_gemm_mfma<<<dim3(64, 16), 256, 0, stream>>>(nmb, owb, obi, out);
}

// Round 7
// 307.779 us; speedup vs baseline: 2.1669x; 1.1271x over previous
//
#include <hip/hip_runtime.h>
#include <math.h>

#define LL 2048
#define DD 128
#define BB 4
#define CK 64
#define NCHUNK 32

typedef __bf16 bf16x8 __attribute__((ext_vector_type(8)));
typedef __bf16 bf16x4 __attribute__((ext_vector_type(4)));
typedef float floatx4 __attribute__((ext_vector_type(4)));

// async global->LDS, 16B per lane. LDS dest must be wave-uniform base + lane*16.
__device__ __forceinline__ void gload_lds16(const void* g, void* l) {
    __builtin_amdgcn_global_load_lds(
        (const __attribute__((address_space(1))) unsigned int*)g,
        (__attribute__((address_space(3))) unsigned int*)l, 16, 0, 0);
}

// ================= proj GEMM (bf16 MFMA, global_load_lds, dbuf) =================
// C(8192x128 x3) = xb(8192x2048 bf16) @ wcat[arr]^T + b.  Tile 64x128, K-step 64.
__global__ __launch_bounds__(256) void proj_gemm_mfma(
    const __bf16* __restrict__ xb, const __bf16* __restrict__ wcat,
    const float* __restrict__ kb, const float* __restrict__ qb, const float* __restrict__ vb,
    float* __restrict__ k0, float* __restrict__ q0, float* __restrict__ v0)
{
    const int arr = blockIdx.y;
    const float* __restrict__ bia = arr == 0 ? kb : (arr == 1 ? qb : vb);
    float* __restrict__ out       = arr == 0 ? k0 : (arr == 1 ? q0 : v0);
    const __bf16* __restrict__ w  = wcat + (size_t)arr * DD * 2048;

    __shared__ __bf16 As[2][64 * 64];     // 8 KB each
    __shared__ __bf16 Bs[2][128 * 64];    // 16 KB each

    const int t = threadIdx.x;
    const int wave = t >> 6, lane = t & 63;
    const int wm = wave & 1, wn = wave >> 1;
    const int m = lane & 15, quad = lane >> 4;
    const int row0 = blockIdx.x * 64;

    floatx4 acc[2][4] = {};

    #pragma unroll
    for (int c = 0; c < 2; c++) {
        int f = t + c * 256;
        gload_lds16(&xb[(size_t)(row0 + (f >> 3)) * 2048 + (f & 7) * 8], &As[0][f * 8]);
    }
    #pragma unroll
    for (int c = 0; c < 4; c++) {
        int f = t + c * 256;
        gload_lds16(&w[(size_t)(f >> 3) * 2048 + (f & 7) * 8], &Bs[0][f * 8]);
    }
    __syncthreads();

    for (int kt = 0; kt < 32; kt++) {
        const int cur = kt & 1, nxt = cur ^ 1;
        if (kt + 1 < 32) {
            const int k0i = (kt + 1) * 64;
            #pragma unroll
            for (int c = 0; c < 2; c++) {
                int f = t + c * 256;
                gload_lds16(&xb[(size_t)(row0 + (f >> 3)) * 2048 + k0i + (f & 7) * 8], &As[nxt][f * 8]);
            }
            #pragma unroll
            for (int c = 0; c < 4; c++) {
                int f = t + c * 256;
                gload_lds16(&w[(size_t)(f >> 3) * 2048 + k0i + (f & 7) * 8], &Bs[nxt][f * 8]);
            }
        }
        #pragma unroll
        for (int ks = 0; ks < 2; ks++) {
            bf16x8 af[2], bfr[4];
            #pragma unroll
            for (int i = 0; i < 2; i++)
                af[i] = *(const bf16x8*)&As[cur][(wm * 32 + i * 16 + m) * 64 + ks * 32 + quad * 8];
            #pragma unroll
            for (int j = 0; j < 4; j++)
                bfr[j] = *(const bf16x8*)&Bs[cur][(wn * 64 + j * 16 + m) * 64 + ks * 32 + quad * 8];
            #pragma unroll
            for (int i = 0; i < 2; i++)
                #pragma unroll
                for (int j = 0; j < 4; j++)
                    acc[i][j] = __builtin_amdgcn_mfma_f32_16x16x32_bf16(af[i], bfr[j], acc[i][j], 0, 0, 0);
        }
        __syncthreads();
    }
    #pragma unroll
    for (int i = 0; i < 2; i++)
        #pragma unroll
        for (int j = 0; j < 4; j++) {
            int col = wn * 64 + j * 16 + m;
            float bv = bia[col];
            #pragma unroll
            for (int r = 0; r < 4; r++)
                out[(size_t)(row0 + wm * 32 + i * 16 + quad * 4 + r) * 128 + col] = acc[i][j][r] + bv;
        }
}

// ================= out GEMM: out(8192x2048) = nmb(8192x128 bf16) @ owb^T + ob ============
__global__ __launch_bounds__(256) void out_gemm_mfma(
    const __bf16* __restrict__ A, const __bf16* __restrict__ wb,
    const float* __restrict__ bias, float* __restrict__ out)
{
    __shared__ __bf16 As[128 * 128];
    __shared__ __bf16 Bs[128 * 128];

    const int t = threadIdx.x;
    const int wave = t >> 6, lane = t & 63;
    const int wm = wave & 1, wn = wave >> 1;
    const int m = lane & 15, quad = lane >> 4;
    const int row0 = blockIdx.x * 128;
    const int col0 = blockIdx.y * 128;

    #pragma unroll
    for (int c = 0; c < 8; c++) {
        int f = t + c * 256;
        gload_lds16(&A[(size_t)(row0 + (f >> 4)) * 128 + (f & 15) * 8], &As[f * 8]);
        gload_lds16(&wb[(size_t)(col0 + (f >> 4)) * 128 + (f & 15) * 8], &Bs[f * 8]);
    }
    __syncthreads();

    floatx4 acc[4][4] = {};
    #pragma unroll
    for (int ks = 0; ks < 4; ks++) {
        bf16x8 af[4], bfr[4];
        #pragma unroll
        for (int i = 0; i < 4; i++)
            af[i] = *(const bf16x8*)&As[(wm * 64 + i * 16 + m) * 128 + ks * 32 + quad * 8];
        #pragma unroll
        for (int j = 0; j < 4; j++)
            bfr[j] = *(const bf16x8*)&Bs[(wn * 64 + j * 16 + m) * 128 + ks * 32 + quad * 8];
        #pragma unroll
        for (int i = 0; i < 4; i++)
            #pragma unroll
            for (int j = 0; j < 4; j++)
                acc[i][j] = __builtin_amdgcn_mfma_f32_16x16x32_bf16(af[i], bfr[j], acc[i][j], 0, 0, 0);
    }
    #pragma unroll
    for (int i = 0; i < 4; i++) {
        int grow = row0 + wm * 64 + i * 16 + quad * 4;
        #pragma unroll
        for (int j = 0; j < 4; j++) {
            int col = col0 + wn * 64 + j * 16 + m;
            float bv = bias[col];
            #pragma unroll
            for (int r = 0; r < 4; r++)
                out[(size_t)(grow + r) * 2048 + col] = acc[i][j][r] + bv;
        }
    }
}

// ================= beta = sigmoid(x @ beta_w^T + beta_b); also emit xb = bf16(x) =========
__global__ __launch_bounds__(256) void beta_kernel(
    const float* __restrict__ x, const float* __restrict__ bw,
    const float* __restrict__ bb, float* __restrict__ beta, __bf16* __restrict__ xb)
{
    const int row = blockIdx.x;
    const float* xr = x + (size_t)row * 2048;
    __bf16* xbr = xb + (size_t)row * 2048;
    const int t = threadIdx.x;
    float s = 0.f;
    #pragma unroll
    for (int jj = 0; jj < 2; jj++) {
        int j = (t + jj * 256) * 4;
        float4 f = *(const float4*)&xr[j];
        float4 wv = *(const float4*)&bw[j];
        s = fmaf(f.x, wv.x, s); s = fmaf(f.y, wv.y, s);
        s = fmaf(f.z, wv.z, s); s = fmaf(f.w, wv.w, s);
        bf16x4 v; v[0] = (__bf16)f.x; v[1] = (__bf16)f.y; v[2] = (__bf16)f.z; v[3] = (__bf16)f.w;
        *(bf16x4*)&xbr[j] = v;
    }
    #pragma unroll
    for (int m = 1; m < 64; m <<= 1) s += __shfl_xor(s, m, 64);
    __shared__ float red[4];
    if ((t & 63) == 0) red[t >> 6] = s;
    __syncthreads();
    if (t == 0) {
        float tot = red[0] + red[1] + red[2] + red[3] + bb[0];
        beta[row] = 1.f / (1.f + expf(-tot));
    }
}

// ================= pack weights to bf16: conv wpk, proj wcat, out owb; zero sumsq =========
__global__ __launch_bounds__(256) void wpack_zero(
    const float* __restrict__ kw, const float* __restrict__ qw, const float* __restrict__ vw,
    const float* __restrict__ kpw, const float* __restrict__ qpw, const float* __restrict__ vpw,
    const float* __restrict__ ow,
    __bf16* __restrict__ wpk, __bf16* __restrict__ wcat, __bf16* __restrict__ owb,
    float* __restrict__ sumsq)
{
    const int t = threadIdx.x;
    const int bx = blockIdx.x;
    if (bx == 0) {
        #pragma unroll
        for (int e = 0; e < 4; e++) sumsq[t * 4 + e] = 0.f;
    }
    if (bx < 144) {
        int base = (bx * 256 + t) * 4;                    // over 3*3*128*128 = 147456
        int arr = base / 49152, rem = base % 49152;
        const float* __restrict__ w = arr == 0 ? kw : arr == 1 ? qw : vw;
        int dt = rem / 16384, rem2 = rem % 16384;
        int o = rem2 >> 7, i0 = rem2 & 127;
        #pragma unroll
        for (int e = 0; e < 4; e++) {
            int i = i0 + e;
            wpk[base + e] = (__bf16)w[(size_t)((o * 128 + i) * 3 + dt) * 3 + 1];
        }
    } else if (bx < 912) {
        int e = (bx - 144) * 1024 + t * 4;                // over 3*128*2048 = 786432
        int arr = e >> 18, rem = e & 262143;
        const float* __restrict__ w = arr == 0 ? kpw : arr == 1 ? qpw : vpw;
        float4 f = *(const float4*)&w[rem];
        bf16x4 v; v[0] = (__bf16)f.x; v[1] = (__bf16)f.y; v[2] = (__bf16)f.z; v[3] = (__bf16)f.w;
        *(bf16x4*)&wcat[(size_t)arr * 262144 + rem] = v;
    } else {
        int e = (bx - 912) * 1024 + t * 4;                // over 2048*128 = 262144
        float4 f = *(const float4*)&ow[e];
        bf16x4 v; v[0] = (__bf16)f.x; v[1] = (__bf16)f.y; v[2] = (__bf16)f.z; v[3] = (__bf16)f.w;
        *(bf16x4*)&owb[e] = v;
    }
}

// ================= conv as MFMA GEMM + bias + SiLU + fused l2norm partials ================
__global__ __launch_bounds__(256) void conv_mfma(
    const float* __restrict__ k0, const float* __restrict__ q0, const float* __restrict__ v0,
    const __bf16* __restrict__ wpk,
    const float* __restrict__ kb, const float* __restrict__ qb, const float* __restrict__ vb,
    float* __restrict__ kcT, float* __restrict__ qcT, float* __restrict__ vcT,
    float* __restrict__ sumsq)
{
    const int sb  = blockIdx.x;
    const int arr = blockIdx.y >> 2;
    const int b   = blockIdx.y & 3;
    const float* __restrict__ in = (arr == 0 ? k0 : arr == 1 ? q0 : v0) + (size_t)b * DD * LL;
    const float* __restrict__ bi = arr == 0 ? kb : arr == 1 ? qb : vb;
    float* __restrict__ out      = (arr == 0 ? kcT : arr == 1 ? qcT : vcT) + (size_t)b * LL * DD;
    const __bf16* __restrict__ wp = wpk + (size_t)arr * 3 * DD * DD;

    __shared__ __bf16 Xs[66 * 136];
    __shared__ float colsum[128];

    const int t = threadIdx.x;
    const int s0 = sb * 64;
    if (t < 128) colsum[t] = 0.f;

    #pragma unroll
    for (int p = 0; p < 32; p++) {
        int idx = t + p * 256;
        int sr = idx & 63, i = idx >> 6;
        float v = in[(size_t)i * LL + s0 + sr];
        int row = sr + 1;
        Xs[row * 136 + (i ^ ((row & 7) << 4))] = (__bf16)v;
    }
    {
        int e = t >> 7, i = t & 127;
        int row = e * 65;
        int s = s0 - 1 + e * 65;
        float v = (s >= 0 && s < LL) ? in[(size_t)i * LL + s] : 0.f;
        Xs[row * 136 + (i ^ ((row & 7) << 4))] = (__bf16)v;
    }
    __syncthreads();

    const int wave = t >> 6, lane = t & 63;
    const int wm = wave & 1, wn = wave >> 1;
    const int m = lane & 15, quad = lane >> 4;

    floatx4 acc[2][4] = {};
    #pragma unroll
    for (int dt = 0; dt < 3; dt++) {
        bf16x8 bfr[4][4];
        #pragma unroll
        for (int ks = 0; ks < 4; ks++)
            #pragma unroll
            for (int j = 0; j < 4; j++)
                bfr[ks][j] = *(const bf16x8*)&wp[(size_t)(dt * DD + wn * 64 + j * 16 + m) * DD + ks * 32 + quad * 8];
        #pragma unroll
        for (int ks = 0; ks < 4; ks++) {
            bf16x8 af[2];
            #pragma unroll
            for (int ii = 0; ii < 2; ii++) {
                int row = wm * 32 + ii * 16 + m + dt;
                af[ii] = *(const bf16x8*)&Xs[row * 136 + ((ks * 32 + quad * 8) ^ ((row & 7) << 4))];
            }
            #pragma unroll
            for (int ii = 0; ii < 2; ii++)
                #pragma unroll
                for (int j = 0; j < 4; j++)
                    acc[ii][j] = __builtin_amdgcn_mfma_f32_16x16x32_bf16(af[ii], bfr[ks][j], acc[ii][j], 0, 0, 0);
        }
    }

    float part[4] = {0.f, 0.f, 0.f, 0.f};
    #pragma unroll
    for (int ii = 0; ii < 2; ii++)
        #pragma unroll
        for (int j = 0; j < 4; j++) {
            int col = wn * 64 + j * 16 + m;
            float bv = bi[col];
            #pragma unroll
            for (int r = 0; r < 4; r++) {
                int srow = s0 + wm * 32 + ii * 16 + quad * 4 + r;
                float v = acc[ii][j][r] + bv;
                float y = v / (1.f + expf(-v));
                out[(size_t)srow * DD + col] = y;
                part[j] = fmaf(y, y, part[j]);
            }
        }
    if (arr < 2) {
        #pragma unroll
        for (int j = 0; j < 4; j++)
            atomicAdd(&colsum[wn * 64 + j * 16 + m], part[j]);
        __syncthreads();
        if (t < 128) atomicAdd(&sumsq[arr * 512 + b * 128 + t], colsum[t]);
    }
}

// ============================================================================
// Chunked delta rule (WY / UT transform), C = 64 — see R0 derivation.
// ============================================================================

// --------- PRE1: A, L, and triangular solve -> W, U0.
// The solve is COLUMN-LOCAL: thread t owns column t; all WU[s][col] it reads were
// computed by itself -> keep them in registers w[64] (fully unrolled, static idx).
// Af[tt][s] is a wave-uniform LDS broadcast (conflict-free, b128-mergeable).
__global__ __launch_bounds__(256) void chunk_pre1(
    const float* __restrict__ kTg, const float* __restrict__ qTg, const float* __restrict__ vTg,
    const float* __restrict__ beta, const float* __restrict__ sumsq,
    __bf16* __restrict__ Lb, __bf16* __restrict__ Wb, __bf16* __restrict__ Ub)
{
    const int c = blockIdx.x, b = blockIdx.y;
    const int gc = b * NCHUNK + c;
    const int t0 = c * CK;
    const float* kbase = kTg + ((size_t)b * LL + t0) * DD;
    const float* qbase = qTg + ((size_t)b * LL + t0) * DD;
    const float* vbase = vTg + ((size_t)b * LL + t0) * DD;

    __shared__ __bf16 Ks[CK][136];
    __shared__ __bf16 Qs[CK][136];
    __shared__ float  Af[CK][64];   // Af[i][j<i] = -beta_i*(KK^T)_ij, Af[i][i] = beta_i

    const int t = threadIdx.x;
    #pragma unroll
    for (int p = 0; p < 8; p++) {
        int idx = t + p * 256;          // 2048 float4 chunks = 64 x 128
        int r = idx >> 5, c4 = idx & 31;
        float4 sk = *(const float4*)&sumsq[b * 128 + c4 * 4];
        float4 sq = *(const float4*)&sumsq[512 + b * 128 + c4 * 4];
        float ik0 = rsqrtf(fmaxf(sk.x, 1e-24f)), ik1 = rsqrtf(fmaxf(sk.y, 1e-24f));
        float ik2 = rsqrtf(fmaxf(sk.z, 1e-24f)), ik3 = rsqrtf(fmaxf(sk.w, 1e-24f));
        float iq0 = rsqrtf(fmaxf(sq.x, 1e-24f)), iq1 = rsqrtf(fmaxf(sq.y, 1e-24f));
        float iq2 = rsqrtf(fmaxf(sq.z, 1e-24f)), iq3 = rsqrtf(fmaxf(sq.w, 1e-24f));
        float4 f = *(const float4*)&kbase[(size_t)r * DD + c4 * 4];
        bf16x4 v; v[0] = (__bf16)(f.x * ik0); v[1] = (__bf16)(f.y * ik1);
        v[2] = (__bf16)(f.z * ik2); v[3] = (__bf16)(f.w * ik3);
        *(bf16x4*)&Ks[r][c4 * 4] = v;
        float4 g = *(const float4*)&qbase[(size_t)r * DD + c4 * 4];
        bf16x4 u; u[0] = (__bf16)(g.x * iq0); u[1] = (__bf16)(g.y * iq1);
        u[2] = (__bf16)(g.z * iq2); u[3] = (__bf16)(g.w * iq3);
        *(bf16x4*)&Qs[r][c4 * 4] = u;
    }
    __syncthreads();

    const int wave = t >> 6, lane = t & 63;
    const int wm = wave & 1, wn = wave >> 1;
    const int m = lane & 15, quad = lane >> 4;

    floatx4 accM[2][2] = {}, accL[2][2] = {};
    #pragma unroll
    for (int ks = 0; ks < 4; ks++) {
        bf16x8 ak[2], aq[2], bk[2];
        #pragma unroll
        for (int i = 0; i < 2; i++) {
            ak[i] = *(const bf16x8*)&Ks[wm * 32 + i * 16 + m][ks * 32 + quad * 8];
            aq[i] = *(const bf16x8*)&Qs[wm * 32 + i * 16 + m][ks * 32 + quad * 8];
            bk[i] = *(const bf16x8*)&Ks[wn * 32 + i * 16 + m][ks * 32 + quad * 8];
        }
        #pragma unroll
        for (int i = 0; i < 2; i++)
            #pragma unroll
            for (int j = 0; j < 2; j++) {
                accM[i][j] = __builtin_amdgcn_mfma_f32_16x16x32_bf16(ak[i], bk[j], accM[i][j], 0, 0, 0);
                accL[i][j] = __builtin_amdgcn_mfma_f32_16x16x32_bf16(aq[i], bk[j], accL[i][j], 0, 0, 0);
            }
    }
    #pragma unroll
    for (int i = 0; i < 2; i++) {
        #pragma unroll
        for (int r = 0; r < 4; r++) {
            int row = wm * 32 + i * 16 + quad * 4 + r;
            float bval = beta[(size_t)b * LL + t0 + row];
            #pragma unroll
            for (int j = 0; j < 2; j++) {
                int col = wn * 32 + j * 16 + m;
                Af[row][col] = (col < row) ? -bval * accM[i][j][r] : (col == row ? bval : 0.f);
                Lb[((size_t)gc * CK + row) * CK + col] =
                    (col <= row) ? (__bf16)accL[i][j][r] : (__bf16)0.f;
            }
        }
    }
    __syncthreads();

    // forward substitution, column-local in registers:
    // w[tt] = Af[tt][tt]*rhs[tt] + sum_{s<tt} Af[tt][s]*w[s]
    const int col = t;
    const float* rbase = (col < DD) ? kbase : vbase;
    const int cm = col & (DD - 1);
    const float scale = (col < DD) ? rsqrtf(fmaxf(sumsq[b * 128 + cm], 1e-24f)) : 1.f;
    float w[CK];
    float cur = rbase[cm] * scale;
    #pragma unroll
    for (int tt = 0; tt < CK; tt++) {
        float nxt = (tt < CK - 1) ? rbase[(size_t)(tt + 1) * DD + cm] * scale : 0.f;
        float p0 = 0.f, p1 = 0.f, p2 = 0.f, p3 = 0.f;
        #pragma unroll
        for (int s = 0; s + 4 <= tt; s += 4) {
            p0 = fmaf(Af[tt][s + 0], w[s + 0], p0);
            p1 = fmaf(Af[tt][s + 1], w[s + 1], p1);
            p2 = fmaf(Af[tt][s + 2], w[s + 2], p2);
            p3 = fmaf(Af[tt][s + 3], w[s + 3], p3);
        }
        #pragma unroll
        for (int s = tt & ~3; s < tt; s++)
            p0 = fmaf(Af[tt][s], w[s], p0);
        float acc = fmaf(Af[tt][tt], cur, (p0 + p1) + (p2 + p3));
        w[tt] = acc;
        __bf16 bv = (__bf16)acc;
        if (col < DD) Wb[((size_t)gc * CK + tt) * DD + col] = bv;
        else          Ub[((size_t)gc * CK + tt) * DD + cm]  = bv;
        cur = nxt;
    }
}

// --------- PRE2 (parallel): H, G, P, Y from W, U0, L, K, Q
__global__ __launch_bounds__(256) void chunk_pre2(
    const float* __restrict__ kTg, const float* __restrict__ qTg,
    const float* __restrict__ sumsq,
    const __bf16* __restrict__ Lb, const __bf16* __restrict__ Wb, const __bf16* __restrict__ Ub,
    __bf16* __restrict__ HTb, __bf16* __restrict__ Gb,
    __bf16* __restrict__ Pb, __bf16* __restrict__ Yb)
{
    const int c = blockIdx.x, b = blockIdx.y;
    const int gc = b * NCHUNK + c;
    const int t0 = c * CK;

    __shared__ __bf16 Kt[DD][72];
    __shared__ __bf16 Wt[DD][72];
    __shared__ __bf16 Ut[DD][72];
    __shared__ __bf16 Ls[CK][72];

    const int t = threadIdx.x;
    #pragma unroll
    for (int p = 0; p < 8; p++) {
        int idx = t + p * 256;
        int tt = idx >> 5, j4 = idx & 31;
        float4 sk = *(const float4*)&sumsq[b * 128 + j4 * 4];
        float4 f = *(const float4*)&kTg[((size_t)b * LL + t0 + tt) * DD + j4 * 4];
        Kt[j4 * 4 + 0][tt] = (__bf16)(f.x * rsqrtf(fmaxf(sk.x, 1e-24f)));
        Kt[j4 * 4 + 1][tt] = (__bf16)(f.y * rsqrtf(fmaxf(sk.y, 1e-24f)));
        Kt[j4 * 4 + 2][tt] = (__bf16)(f.z * rsqrtf(fmaxf(sk.z, 1e-24f)));
        Kt[j4 * 4 + 3][tt] = (__bf16)(f.w * rsqrtf(fmaxf(sk.w, 1e-24f)));
        bf16x4 w = *(const bf16x4*)&Wb[((size_t)gc * CK + tt) * DD + j4 * 4];
        bf16x4 u = *(const bf16x4*)&Ub[((size_t)gc * CK + tt) * DD + j4 * 4];
        #pragma unroll
        for (int e = 0; e < 4; e++) { Wt[j4 * 4 + e][tt] = w[e]; Ut[j4 * 4 + e][tt] = u[e]; }
    }
    #pragma unroll
    for (int p = 0; p < 4; p++) {
        int idx = t + p * 256;
        int tt = idx >> 4, s4 = idx & 15;
        *(bf16x4*)&Ls[tt][s4 * 4] = *(const bf16x4*)&Lb[((size_t)gc * CK + tt) * CK + s4 * 4];
    }
    __syncthreads();

    const int wave = t >> 6, lane = t & 63;
    const int wm = wave & 1, wn = wave >> 1;
    const int m = lane & 15, quad = lane >> 4;

    // H^T (negated): C[j][i] = -sum_t Kt[j][t] Wt[i][t]
    {
        floatx4 acc[4][4] = {};
        #pragma unroll
        for (int ks = 0; ks < 2; ks++) {
            bf16x8 a[4], bb[4];
            #pragma unroll
            for (int i = 0; i < 4; i++) {
                a[i]  = *(const bf16x8*)&Kt[wm * 64 + i * 16 + m][ks * 32 + quad * 8];
                bb[i] = *(const bf16x8*)&Wt[wn * 64 + i * 16 + m][ks * 32 + quad * 8];
            }
            #pragma unroll
            for (int i = 0; i < 4; i++)
                #pragma unroll
                for (int j = 0; j < 4; j++)
                    acc[i][j] = __builtin_amdgcn_mfma_f32_16x16x32_bf16(a[i], bb[j], acc[i][j], 0, 0, 0);
        }
        #pragma unroll
        for (int i = 0; i < 4; i++)
            #pragma unroll
            for (int j = 0; j < 4; j++)
                #pragma unroll
                for (int r = 0; r < 4; r++) {
                    int row = wm * 64 + i * 16 + quad * 4 + r;
                    int cx  = wn * 64 + j * 16 + m;
                    HTb[((size_t)gc * DD + row) * DD + cx] = (__bf16)(-acc[i][j][r]);
                }
    }
    // G: C[i][j] = sum_t Ut[i][t] Kt[j][t]
    {
        floatx4 acc[4][4] = {};
        #pragma unroll
        for (int ks = 0; ks < 2; ks++) {
            bf16x8 a[4], bb[4];
            #pragma unroll
            for (int i = 0; i < 4; i++) {
                a[i]  = *(const bf16x8*)&Ut[wm * 64 + i * 16 + m][ks * 32 + quad * 8];
                bb[i] = *(const bf16x8*)&Kt[wn * 64 + i * 16 + m][ks * 32 + quad * 8];
            }
            #pragma unroll
            for (int i = 0; i < 4; i++)
                #pragma unroll
                for (int j = 0; j < 4; j++)
                    acc[i][j] = __builtin_amdgcn_mfma_f32_16x16x32_bf16(a[i], bb[j], acc[i][j], 0, 0, 0);
        }
        #pragma unroll
        for (int i = 0; i < 4; i++)
            #pragma unroll
            for (int j = 0; j < 4; j++)
                #pragma unroll
                for (int r = 0; r < 4; r++) {
                    int row = wm * 64 + i * 16 + quad * 4 + r;
                    int cx  = wn * 64 + j * 16 + m;
                    Gb[((size_t)gc * DD + row) * DD + cx] = (__bf16)acc[i][j][r];
                }
    }
    // P = Q - L W
    {
        floatx4 acc[2][4] = {};
        #pragma unroll
        for (int ks = 0; ks < 2; ks++) {
            bf16x8 a[2], bb[4];
            #pragma unroll
            for (int i = 0; i < 2; i++)
                a[i] = *(const bf16x8*)&Ls[wm * 32 + i * 16 + m][ks * 32 + quad * 8];
            #pragma unroll
            for (int j = 0; j < 4; j++)
                bb[j] = *(const bf16x8*)&Wt[wn * 64 + j * 16 + m][ks * 32 + quad * 8];
            #pragma unroll
            for (int i = 0; i < 2; i++)
                #pragma unroll
                for (int j = 0; j < 4; j++)
                    acc[i][j] = __builtin_amdgcn_mfma_f32_16x16x32_bf16(a[i], bb[j], acc[i][j], 0, 0, 0);
        }
        #pragma unroll
        for (int i = 0; i < 2; i++)
            #pragma unroll
            for (int j = 0; j < 4; j++)
                #pragma unroll
                for (int r = 0; r < 4; r++) {
                    int row = wm * 32 + i * 16 + quad * 4 + r;
                    int cx  = wn * 64 + j * 16 + m;
                    float iq = rsqrtf(fmaxf(sumsq[512 + b * 128 + cx], 1e-24f));
                    float qv = qTg[((size_t)b * LL + t0 + row) * DD + cx] * iq;
                    Pb[((size_t)gc * CK + row) * DD + cx] = (__bf16)(qv - acc[i][j][r]);
                }
    }
    // Y = L U0
    {
        floatx4 acc[2][4] = {};
        #pragma unroll
        for (int ks = 0; ks < 2; ks++) {
            bf16x8 a[2], bb[4];
            #pragma unroll
            for (int i = 0; i < 2; i++)
                a[i] = *(const bf16x8*)&Ls[wm * 32 + i * 16 + m][ks * 32 + quad * 8];
            #pragma unroll
            for (int j = 0; j < 4; j++)
                bb[j] = *(const bf16x8*)&Ut[wn * 64 + j * 16 + m][ks * 32 + quad * 8];
            #pragma unroll
            for (int i = 0; i < 2; i++)
                #pragma unroll
                for (int j = 0; j < 4; j++)
                    acc[i][j] = __builtin_amdgcn_mfma_f32_16x16x32_bf16(a[i], bb[j], acc[i][j], 0, 0, 0);
        }
        #pragma unroll
        for (int i = 0; i < 2; i++)
            #pragma unroll
            for (int j = 0; j < 4; j++)
                #pragma unroll
                for (int r = 0; r < 4; r++) {
                    int row = wm * 32 + i * 16 + quad * 4 + r;
                    int cx  = wn * 64 + j * 16 + m;
                    Yb[((size_t)gc * CK + row) * DD + cx] = (__bf16)acc[i][j][r];
                }
    }
}

// --------- serial chain: S <- S (I - H) + G; 16 blocks (4b x 4 rowgroups of 32 rows)
__global__ __launch_bounds__(256) void delta_serial(
    const __bf16* __restrict__ HTb, const __bf16* __restrict__ Gb, __bf16* __restrict__ S0b)
{
    const int b  = blockIdx.x >> 2;
    const int rg = blockIdx.x & 3;
    __shared__ __bf16 Ss[32][136];
    const int t = threadIdx.x;
    const int wj = t >> 6;
    const int lane = t & 63;
    const int m = lane & 15, quad = lane >> 4;

    floatx4 acc[2][2] = {};
    bf16x8 hA[8], hB[8];
    __bf16 gpre[16];

    {
        const size_t g0 = (size_t)(b * NCHUNK) * DD * DD;
        #pragma unroll
        for (int ks = 0; ks < 4; ks++)
            #pragma unroll
            for (int j = 0; j < 2; j++) {
                int hr = wj * 32 + j * 16 + m;
                hA[ks * 2 + j] = *(const bf16x8*)&HTb[g0 + (size_t)hr * DD + ks * 32 + quad * 8];
            }
        #pragma unroll
        for (int i = 0; i < 2; i++)
            #pragma unroll
            for (int j = 0; j < 2; j++)
                #pragma unroll
                for (int r = 0; r < 4; r++) {
                    int row = rg * 32 + i * 16 + quad * 4 + r;
                    int cx  = wj * 32 + j * 16 + m;
                    gpre[(i * 2 + j) * 4 + r] = Gb[g0 + (size_t)row * DD + cx];
                }
    }

    for (int c = 0; c < NCHUNK; c++) {
        const size_t gco = (size_t)(b * NCHUNK + c) * DD * DD;
        const size_t gcn = gco + (size_t)DD * DD;
        const bool even = (c & 1) == 0;
        if (c + 1 < NCHUNK) {
            #pragma unroll
            for (int ks = 0; ks < 4; ks++)
                #pragma unroll
                for (int j = 0; j < 2; j++) {
                    int hr = wj * 32 + j * 16 + m;
                    bf16x8 v = *(const bf16x8*)&HTb[gcn + (size_t)hr * DD + ks * 32 + quad * 8];
                    if (even) hB[ks * 2 + j] = v; else hA[ks * 2 + j] = v;
                }
        }
        #pragma unroll
        for (int i = 0; i < 2; i++)
            #pragma unroll
            for (int j = 0; j < 2; j++) {
                int row = i * 16 + quad * 4;
                int cx  = wj * 32 + j * 16 + m;
                #pragma unroll
                for (int r = 0; r < 4; r++)
                    Ss[row + r][cx] = (__bf16)acc[i][j][r];
            }
        __syncthreads();
        #pragma unroll
        for (int p = 0; p < 4; p++) {
            int idx = t + p * 256;
            int row = idx >> 5, c4 = idx & 31;
            *(bf16x4*)&S0b[gco + (size_t)(rg * 32 + row) * DD + c4 * 4] =
                *(const bf16x4*)&Ss[row][c4 * 4];
        }
        #pragma unroll
        for (int i = 0; i < 2; i++)
            #pragma unroll
            for (int j = 0; j < 2; j++)
                #pragma unroll
                for (int r = 0; r < 4; r++)
                    acc[i][j][r] += (float)gpre[(i * 2 + j) * 4 + r];
        if (c + 1 < NCHUNK) {
            #pragma unroll
            for (int i = 0; i < 2; i++)
                #pragma unroll
                for (int j = 0; j < 2; j++)
                    #pragma unroll
                    for (int r = 0; r < 4; r++) {
                        int row = rg * 32 + i * 16 + quad * 4 + r;
                        int cx  = wj * 32 + j * 16 + m;
                        gpre[(i * 2 + j) * 4 + r] = Gb[gcn + (size_t)row * DD + cx];
                    }
        }
        #pragma unroll
        for (int ks = 0; ks < 4; ks++) {
            bf16x8 a[2];
            #pragma unroll
            for (int i = 0; i < 2; i++)
                a[i] = *(const bf16x8*)&Ss[i * 16 + m][ks * 32 + quad * 8];
            #pragma unroll
            for (int i = 0; i < 2; i++)
                #pragma unroll
                for (int j = 0; j < 2; j++) {
                    bf16x8 hb = even ? hA[ks * 2 + j] : hB[ks * 2 + j];
                    acc[i][j] = __builtin_amdgcn_mfma_f32_16x16x32_bf16(a[i], hb, acc[i][j], 0, 0, 0);
                }
        }
        __syncthreads();
    }
}

// --------- O = P S0^T + Y, fused RMSNorm over D -> nmb (bf16, (B,L,D))
__global__ __launch_bounds__(256) void chunk_out(
    const __bf16* __restrict__ Pb, const __bf16* __restrict__ Yb, const __bf16* __restrict__ S0b,
    const float* __restrict__ rms_w, __bf16* __restrict__ nmb)
{
    const int c = blockIdx.x, b = blockIdx.y;
    const int gc = b * NCHUNK + c;
    const int t0 = c * CK;
    __shared__ __bf16 Ps[CK][136];
    __shared__ __bf16 Sb[DD][136];
    __shared__ float red[2][2][2][4][4];
    const int t = threadIdx.x;
    #pragma unroll
    for (int p = 0; p < 8; p++) {
        int idx = t + p * 256;
        int row = idx >> 5, c4 = idx & 31;
        *(bf16x4*)&Ps[row][c4 * 4] = *(const bf16x4*)&Pb[((size_t)gc * CK + row) * DD + c4 * 4];
    }
    #pragma unroll
    for (int p = 0; p < 16; p++) {
        int idx = t + p * 256;
        int row = idx >> 5, c4 = idx & 31;
        *(bf16x4*)&Sb[row][c4 * 4] = *(const bf16x4*)&S0b[((size_t)gc * DD + row) * DD + c4 * 4];
    }
    __syncthreads();

    const int wave = t >> 6, lane = t & 63;
    const int wm = wave & 1, wn = wave >> 1;
    const int m = lane & 15, quad = lane >> 4;

    floatx4 acc[2][4] = {};
    #pragma unroll
    for (int ks = 0; ks < 4; ks++) {
        bf16x8 a[2], bb[4];
        #pragma unroll
        for (int i = 0; i < 2; i++)
            a[i] = *(const bf16x8*)&Ps[wm * 32 + i * 16 + m][ks * 32 + quad * 8];
        #pragma unroll
        for (int j = 0; j < 4; j++)
            bb[j] = *(const bf16x8*)&Sb[wn * 64 + j * 16 + m][ks * 32 + quad * 8];
        #pragma unroll
        for (int i = 0; i < 2; i++)
            #pragma unroll
            for (int j = 0; j < 4; j++)
                acc[i][j] = __builtin_amdgcn_mfma_f32_16x16x32_bf16(a[i], bb[j], acc[i][j], 0, 0, 0);
    }

    float v[2][4][4];
    float ss[2][4] = {};
    #pragma unroll
    for (int i = 0; i < 2; i++)
        #pragma unroll
        for (int j = 0; j < 4; j++)
            #pragma unroll
            for (int r = 0; r < 4; r++) {
                int row = wm * 32 + i * 16 + quad * 4 + r;
                int cx  = wn * 64 + j * 16 + m;
                float y = (float)Yb[((size_t)gc * CK + row) * DD + cx];
                float vv = acc[i][j][r] + y;
                v[i][j][r] = vv;
                ss[i][r] = fmaf(vv, vv, ss[i][r]);
            }
    #pragma unroll
    for (int mask = 1; mask < 16; mask <<= 1)
        #pragma unroll
        for (int i = 0; i < 2; i++)
            #pragma unroll
            for (int r = 0; r < 4; r++)
                ss[i][r] += __shfl_xor(ss[i][r], mask, 64);
    if (m == 0)
        #pragma unroll
        for (int i = 0; i < 2; i++)
            #pragma unroll
            for (int r = 0; r < 4; r++)
                red[wn][wm][i][quad][r] = ss[i][r];
    __syncthreads();
    #pragma unroll
    for (int i = 0; i < 2; i++)
        #pragma unroll
        for (int r = 0; r < 4; r++) {
            float tot = red[0][wm][i][quad][r] + red[1][wm][i][quad][r];
            float inv = rsqrtf(tot * (1.f / 128.f) + 1.1920928955078125e-07f);
            int row = wm * 32 + i * 16 + quad * 4 + r;
            #pragma unroll
            for (int j = 0; j < 4; j++) {
                int cx = wn * 64 + j * 16 + m;
                nmb[((size_t)b * LL + t0 + row) * DD + cx] = (__bf16)(v[i][j][r] * inv * rms_w[cx]);
            }
        }
}

extern "C" void kernel_launch(void* const* d_in, const int* in_sizes, int n_in,
                              void* d_out, int out_size, void* d_ws, size_t ws_size,
                              hipStream_t stream) {
    const float* x    = (const float*)d_in[0];
    const float* kpw  = (const float*)d_in[1];
    const float* kpb  = (const float*)d_in[2];
    const float* qpw  = (const float*)d_in[3];
    const float* qpb  = (const float*)d_in[4];
    const float* vpw  = (const float*)d_in[5];
    const float* vpb  = (const float*)d_in[6];
    const float* kcw  = (const float*)d_in[7];
    const float* kcb  = (const float*)d_in[8];
    const float* qcw  = (const float*)d_in[9];
    const float* qcb  = (const float*)d_in[10];
    const float* vcw  = (const float*)d_in[11];
    const float* vcb  = (const float*)d_in[12];
    const float* bw   = (const float*)d_in[13];
    const float* bb   = (const float*)d_in[14];
    const float* rw   = (const float*)d_in[15];
    const float* ow   = (const float*)d_in[16];
    const float* obi  = (const float*)d_in[17];
    float* out = (float*)d_out;

    float* ws = (float*)d_ws;
    const size_t NB1 = (size_t)BB * DD * LL;   // 1,048,576 floats = 4 MB
    float* k0  = ws;
    float* q0  = ws + NB1;
    float* v0  = ws + 2 * NB1;
    float* kcT = ws + 3 * NB1;
    float* qcT = ws + 4 * NB1;
    float* vcT = ws + 5 * NB1;
    float* beta  = ws + 8 * NB1;
    float* sumsq = beta + (size_t)BB * LL;
    __bf16* wpk  = (__bf16*)(sumsq + 1024);                 // 147456 bf16
    __bf16* wcat = wpk + (size_t)147456;                    // 786432 bf16 (1.5 MB)
    __bf16* owb  = wcat + (size_t)786432;                   // 262144 bf16 (0.5 MB)

    __bf16* Lb  = (__bf16*)k0;
    __bf16* Wb  = Lb + (size_t)128 * 64 * 64;
    __bf16* Ub  = (__bf16*)q0;
    __bf16* HTb = (__bf16*)v0;
    __bf16* Gb  = (__bf16*)vcT;
    __bf16* Pb  = (__bf16*)(ws + 7 * NB1);
    __bf16* Yb  = Pb + (size_t)128 * 64 * 128;
    __bf16* S0b = (__bf16*)k0;
    __bf16* nmb = (__bf16*)(ws + 6 * NB1);
    __bf16* xb  = (__bf16*)d_out;

    wpack_zero<<<dim3(1168), 256, 0, stream>>>(kcw, qcw, vcw, kpw, qpw, vpw, ow, wpk, wcat, owb, sumsq);
    beta_kernel<<<dim3(BB * LL), 256, 0, stream>>>(x, bw, bb, beta, xb);
    proj_gemm_mfma<<<dim3(128, 3), 256, 0, stream>>>(xb, wcat, kpb, qpb, vpb, k0, q0, v0);
    conv_mfma<<<dim3(32, 12), 256, 0, stream>>>(k0, q0, v0, wpk, kcb, qcb, vcb, kcT, qcT, vcT, sumsq);
    chunk_pre1<<<dim3(NCHUNK, BB), 256, 0, stream>>>(kcT, qcT, vcT, beta, sumsq, Lb, Wb, Ub);
    chunk_pre2<<<dim3(NCHUNK, BB), 256, 0, stream>>>(kcT, qcT, sumsq, Lb, Wb, Ub, HTb, Gb, Pb, Yb);
    delta_serial<<<dim3(BB * 4), 256, 0, stream>>>(HTb, Gb, S0b);
    chunk_out<<<dim3(NCHUNK, BB), 256, 0, stream>>>(Pb, Yb, S0b, rw, nmb);
    out_gemm_mfma<<<dim3(64, 16), 256, 0, stream>>>(nmb, owb, obi, out);
}